// Round 1
// baseline (2726.487 us; speedup 1.0000x reference)
//
#include <hip/hip_runtime.h>
#include <math.h>

constexpr int NB   = 128;      // capsule batch = G*G*B
constexpr int NCAP = 512;
constexpr int NCLS = 43;
constexpr int NO   = 21;
constexpr int KO   = NCLS * NO; // 903

// ---- workspace layout (float offsets) ----
constexpr size_t F_H1   = 0;         // 16,777,216 floats
constexpr size_t F_H2   = 16777216;  // 33,554,432
constexpr size_t F_H3   = 0;         //  2,097,152 (h1 dead by conv3)
constexpr size_t F_H4   = 2097152;   //  1,048,576
constexpr size_t F_H5   = 3145728;   //    524,288
constexpr size_t F_PRI  = 0;         // 59,179,008 (h1..h5 dead by priors)
constexpr size_t F_CAPS = 59179008;  //    524,288
constexpr size_t F_LOG  = 59703296;  //  2,818,048
constexpr size_t F_PRB  = 62521344;  //  2,818,048
constexpr size_t F_S    = 65339392;  //    115,584
constexpr size_t F_OUTS = 65454976;  //    115,584
constexpr size_t F_STAT = 65570560;  //      1,024
// total: 65,571,584 floats = 262,286,336 bytes (< 256 MiB)

// ---------------- generic tiled direct conv (fp32), pad=1 -----------------
// block: 256 threads -> tile 16(w) x 8(h) pixels x 32 out-channels
// per-thread: 4 oc x 4 px register tile
template<int KS, int STRIDE, int ICC, int IHT, int IWT>
__global__ __launch_bounds__(256) void conv_k(
    const float* __restrict__ in, const float* __restrict__ w,
    const float* __restrict__ bias, float* __restrict__ out,
    int IC, int OC, int IH, int IW, int OH, int OW)
{
  constexpr int BOC = 32;
  const int noc = OC >> 5;
  const int bz  = blockIdx.z;
  const int ocb = bz % noc;
  const int b   = bz / noc;
  const int tx0 = blockIdx.x * 16;
  const int ty0 = blockIdx.y * 8;
  const int oc0 = ocb * BOC;

  __shared__ float lin[ICC][IHT][IWT];
  __shared__ float lw[ICC][KS * KS][BOC];

  const int t  = threadIdx.x;
  const int pq = t & 3;         // pixel quad (x)
  const int ty = (t >> 2) & 7;  // row in tile
  const int oq = t >> 5;        // oc quad

  float acc[4][4];
#pragma unroll
  for (int m = 0; m < 4; ++m) {
    float bv = bias[oc0 + oq * 4 + m];
#pragma unroll
    for (int j = 0; j < 4; ++j) acc[m][j] = bv;
  }

  const int gx0 = tx0 * STRIDE - 1;  // pad = 1
  const int gy0 = ty0 * STRIDE - 1;
  const int nch = IC / ICC;

  for (int ch = 0; ch < nch; ++ch) {
    const int ic0 = ch * ICC;
    __syncthreads();
    // stage input patch
    for (int e = t; e < ICC * IHT * IWT; e += 256) {
      int ic = e / (IHT * IWT);
      int rr = e % (IHT * IWT);
      int ey = rr / IWT, ex = rr % IWT;
      int gy = gy0 + ey, gx = gx0 + ex;
      float v = 0.f;
      if ((unsigned)gy < (unsigned)IH && (unsigned)gx < (unsigned)IW)
        v = in[((size_t)(b * IC + ic0 + ic) * IH + gy) * IW + gx];
      lin[ic][ey][ex] = v;
    }
    // stage weights as [ic][k][oc] so the oc read is an aligned float4
    for (int e = t; e < ICC * KS * KS * BOC; e += 256) {
      int ocl = e & (BOC - 1);
      int rr  = e >> 5;
      int kk  = rr % (KS * KS);
      int ic  = rr / (KS * KS);
      lw[ic][kk][ocl] = w[((size_t)(oc0 + ocl) * IC + ic0 + ic) * (KS * KS) + kk];
    }
    __syncthreads();

    for (int ic = 0; ic < ICC; ++ic) {
#pragma unroll
      for (int ky = 0; ky < KS; ++ky) {
#pragma unroll
        for (int kx = 0; kx < KS; ++kx) {
          float xv[4];
#pragma unroll
          for (int j = 0; j < 4; ++j)
            xv[j] = lin[ic][ty * STRIDE + ky][(pq * 4 + j) * STRIDE + kx];
          const float4 w4 = *(const float4*)&lw[ic][ky * KS + kx][oq * 4];
#pragma unroll
          for (int j = 0; j < 4; ++j) {
            acc[0][j] = fmaf(w4.x, xv[j], acc[0][j]);
            acc[1][j] = fmaf(w4.y, xv[j], acc[1][j]);
            acc[2][j] = fmaf(w4.z, xv[j], acc[2][j]);
            acc[3][j] = fmaf(w4.w, xv[j], acc[3][j]);
          }
        }
      }
    }
  }

  const int oy = ty0 + ty;
#pragma unroll
  for (int m = 0; m < 4; ++m) {
    int oc = oc0 + oq * 4 + m;
    float* op = out + ((size_t)(b * OC + oc) * OH + oy) * OW + tx0 + pq * 4;
#pragma unroll
    for (int j = 0; j < 4; ++j) op[j] = acc[m][j];
  }
}

// ---------------- batch norm ----------------
__global__ __launch_bounds__(256) void bn_stats_k(
    const float* __restrict__ x, float* __restrict__ stats,
    int C, int sh, int split, int nelem)
{
  const int c = blockIdx.x / split;
  const int s = blockIdx.x % split;
  const int HW = 1 << sh;
  float sum = 0.f, sq = 0.f;
  for (int i = s * 256 + threadIdx.x; i < nelem; i += split * 256) {
    int b = i >> sh, r = i & (HW - 1);
    float v = x[((size_t)(b * C + c) << sh) + r];
    sum += v; sq += v * v;
  }
#pragma unroll
  for (int off = 32; off > 0; off >>= 1) {
    sum += __shfl_down(sum, off);
    sq  += __shfl_down(sq, off);
  }
  __shared__ float ls[4], lq[4];
  int wid = threadIdx.x >> 6, lane = threadIdx.x & 63;
  if (lane == 0) { ls[wid] = sum; lq[wid] = sq; }
  __syncthreads();
  if (threadIdx.x == 0) {
    float S = ls[0] + ls[1] + ls[2] + ls[3];
    float Q = lq[0] + lq[1] + lq[2] + lq[3];
    atomicAdd(&stats[c], S);
    atomicAdd(&stats[C + c], Q);
  }
}

__global__ void bn_fin_k(float* __restrict__ stats, const float* __restrict__ g,
                         const float* __restrict__ bt, int C, float inv_n)
{
  int c = threadIdx.x;
  if (c < C) {
    float m  = stats[c] * inv_n;
    float v  = stats[C + c] * inv_n - m * m;
    float rs = rsqrtf(v + 1e-5f);
    float sc = g[c] * rs;
    stats[2 * C + c] = sc;
    stats[3 * C + c] = bt[c] - m * sc;
  }
}

__global__ __launch_bounds__(256) void bn_apply_k(
    float* __restrict__ x, const float* __restrict__ stats,
    int C, int sh, int total4)
{
  const int stride = gridDim.x * 256;
  for (int i = blockIdx.x * 256 + threadIdx.x; i < total4; i += stride) {
    int c = (i >> (sh - 2)) & (C - 1);
    float sc = stats[2 * C + c], sf = stats[3 * C + c];
    float4 v = ((const float4*)x)[i];
    float t;
    t = fmaf(v.x, sc, sf); v.x = fmaxf(t, 0.1f * t);
    t = fmaf(v.y, sc, sf); v.y = fmaxf(t, 0.1f * t);
    t = fmaf(v.z, sc, sf); v.z = fmaxf(t, 0.1f * t);
    t = fmaf(v.w, sc, sf); v.w = fmaxf(t, 0.1f * t);
    ((float4*)x)[i] = v;
  }
}

// ---------------- capsule rearrange ----------------
__global__ void caps_k(const float* __restrict__ h5, float* __restrict__ caps)
{
  int e = blockIdx.x * 256 + threadIdx.x;
  if (e >= NB * NCAP * 8) return;
  int ii = e & 7;
  int n  = (e >> 3) & 511;
  int jb = e >> 12;
  int j = jb >> 3, b = jb & 7;
  int i = n >> 7, k = (n >> 5) & 3, ch = ((n & 31) << 3) | ii;
  int hh = (i << 2) | (j >> 2);
  int ww = ((j & 3) << 2) | k;
  caps[e] = h5[((size_t)(b * 256 + ch) * 16 + hh) * 16 + ww];
}

// ---------------- priors: block per n, loop over b ----------------
__global__ __launch_bounds__(256) void priors_k(
    const float* __restrict__ caps, const float* __restrict__ rw,
    float* __restrict__ priors)
{
  const int n = blockIdx.x;  // 0..511
  __shared__ float lrw[NCLS * 8 * NO]; // 7224 floats
  __shared__ float lc[NB * 8];         // 1024 floats
  const int t = threadIdx.x;
  for (int e = t; e < NCLS * 8 * NO; e += 256)
    lrw[e] = rw[(size_t)n * NCLS * 8 * NO + e];
  for (int e = t; e < NB * 8; e += 256) {
    int b = e >> 3, ii = e & 7;
    lc[e] = caps[((size_t)b * NCAP + n) * 8 + ii];
  }
  __syncthreads();

  int p[4], kk[4], oo[4];
#pragma unroll
  for (int q = 0; q < 4; ++q) {
    p[q]  = t + q * 256;
    kk[q] = (p[q] < KO) ? p[q] / NO : 0;
    oo[q] = (p[q] < KO) ? p[q] % NO : 0;
  }
  for (int b = 0; b < NB; ++b) {
    const float* cb = &lc[b * 8];
    float c0 = cb[0], c1 = cb[1], c2 = cb[2], c3 = cb[3];
    float c4 = cb[4], c5 = cb[5], c6 = cb[6], c7 = cb[7];
    float* pout = priors + ((size_t)b * NCAP + n) * KO;
#pragma unroll
    for (int q = 0; q < 4; ++q) {
      if (p[q] < KO) {
        const float* wv = &lrw[kk[q] * (8 * NO) + oo[q]];
        float a = c0 * wv[0];
        a = fmaf(c1, wv[21],  a);
        a = fmaf(c2, wv[42],  a);
        a = fmaf(c3, wv[63],  a);
        a = fmaf(c4, wv[84],  a);
        a = fmaf(c5, wv[105], a);
        a = fmaf(c6, wv[126], a);
        a = fmaf(c7, wv[147], a);
        pout[p[q]] = a;
      }
    }
  }
}

// ---------------- routing ----------------
// s partial: grid = NB * 8 blocks, each handles 64 n's, atomics into s
__global__ __launch_bounds__(256) void route_s_partial(
    const float* __restrict__ priors, const float* __restrict__ probs,
    float* __restrict__ s, int uniform)
{
  const int b  = blockIdx.x >> 3;
  const int ns = blockIdx.x & 7;
  const int t  = threadIdx.x;
  const int p0 = t, p1 = t + 256, p2 = t + 512, p3 = t + 768;
  const int k0 = p0 / NO, k1 = p1 / NO, k2 = p2 / NO;
  const int k3 = (p3 < KO) ? p3 / NO : 0;
  float a0 = 0.f, a1 = 0.f, a2 = 0.f, a3 = 0.f;
  const float* pb  = priors + ((size_t)b * NCAP + ns * 64) * KO;
  const float* prb = probs + ((size_t)b * NCAP + ns * 64) * NCLS;
#pragma unroll 2
  for (int n = 0; n < 64; ++n) {
    const float* pn = pb + (size_t)n * KO;
    if (uniform) {
      a0 += pn[p0]; a1 += pn[p1]; a2 += pn[p2];
      if (p3 < KO) a3 += pn[p3];
    } else {
      const float* pr = prb + n * NCLS;
      a0 = fmaf(pr[k0], pn[p0], a0);
      a1 = fmaf(pr[k1], pn[p1], a1);
      a2 = fmaf(pr[k2], pn[p2], a2);
      if (p3 < KO) a3 = fmaf(pr[k3], pn[p3], a3);
    }
  }
  const float sc = uniform ? (1.f / 43.f) : 1.f;
  atomicAdd(&s[b * KO + p0], a0 * sc);
  atomicAdd(&s[b * KO + p1], a1 * sc);
  atomicAdd(&s[b * KO + p2], a2 * sc);
  if (p3 < KO) atomicAdd(&s[b * KO + p3], a3 * sc);
}

__global__ void squash_k(const float* __restrict__ s, float* __restrict__ souts)
{
  int i = blockIdx.x * 256 + threadIdx.x;
  if (i >= NB * NCLS) return;
  int b = i / NCLS, k = i % NCLS;
  const float* sv = s + b * KO + k * NO;
  float sn = 0.f;
#pragma unroll
  for (int o = 0; o < NO; ++o) sn += sv[o] * sv[o];
  float f = sqrtf(sn) / (1.f + sn);
  float* ov = souts + b * KO + k * NO;
#pragma unroll
  for (int o = 0; o < NO; ++o) ov[o] = sv[o] * f;
}

__global__ __launch_bounds__(256) void logits_k(
    const float* __restrict__ priors, const float* __restrict__ souts,
    float* __restrict__ logits, int accum)
{
  int i = blockIdx.x * 256 + threadIdx.x;
  if (i >= NB * NCAP * NCLS) return;
  int k  = i % NCLS;
  int bn = i / NCLS;
  int b  = bn >> 9;
  const float* pv = priors + (size_t)bn * KO + k * NO;
  const float* ov = souts + b * KO + k * NO;
  float d = 0.f;
#pragma unroll
  for (int o = 0; o < NO; ++o) d = fmaf(pv[o], ov[o], d);
  logits[i] = (accum ? logits[i] : 0.f) + d;
}

__global__ __launch_bounds__(256) void probs_k(
    const float* __restrict__ logits, float* __restrict__ probs)
{
  int bn = blockIdx.x * 256 + threadIdx.x;
  if (bn >= NB * NCAP) return;
  const float* lg = logits + (size_t)bn * NCLS;
  float e[NCLS];
  float mx = -1e30f;
#pragma unroll
  for (int k = 0; k < NCLS; ++k) { e[k] = lg[k]; mx = fmaxf(mx, e[k]); }
  float sm = 0.f;
#pragma unroll
  for (int k = 0; k < NCLS; ++k) { e[k] = expf(e[k] - mx); sm += e[k]; }
  float inv = 1.f / sm;
  float* pb = probs + (size_t)bn * NCLS;
#pragma unroll
  for (int k = 0; k < NCLS; ++k) pb[k] = e[k] * inv;
}

__global__ void out_k(const float* __restrict__ souts, float* __restrict__ out)
{
  int i = blockIdx.x * 256 + threadIdx.x;
  if (i >= 8 * 16 * NCLS * NO) return;
  int o = i % NO;
  int r = i / NO;
  int k = r % NCLS; r /= NCLS;
  int g1 = r & 3; r >>= 2;
  int g0 = r & 3;
  int b  = r >> 2;
  int j  = g0 * 4 + g1;
  int jb = j * 8 + b;
  out[i] = souts[jb * KO + k * NO + o];
}

// ---------------- launcher ----------------
extern "C" void kernel_launch(void* const* d_in, const int* in_sizes, int n_in,
                              void* d_out, int out_size, void* d_ws, size_t ws_size,
                              hipStream_t stream)
{
  const float* x   = (const float*)d_in[0];
  const float* c1w = (const float*)d_in[1];  const float* c1b = (const float*)d_in[2];
  const float* g1  = (const float*)d_in[3];  const float* b1  = (const float*)d_in[4];
  const float* c2w = (const float*)d_in[5];  const float* c2b = (const float*)d_in[6];
  const float* g2  = (const float*)d_in[7];  const float* b2  = (const float*)d_in[8];
  const float* c3w = (const float*)d_in[9];  const float* c3b = (const float*)d_in[10];
  const float* g3  = (const float*)d_in[11]; const float* b3  = (const float*)d_in[12];
  const float* c4w = (const float*)d_in[13]; const float* c4b = (const float*)d_in[14];
  const float* g4  = (const float*)d_in[15]; const float* b4  = (const float*)d_in[16];
  const float* c5w = (const float*)d_in[17]; const float* c5b = (const float*)d_in[18];
  const float* g5  = (const float*)d_in[19]; const float* b5  = (const float*)d_in[20];
  const float* rw  = (const float*)d_in[21];

  float* ws  = (float*)d_ws;
  float* out = (float*)d_out;

  float* h1     = ws + F_H1;
  float* h2     = ws + F_H2;
  float* h3     = ws + F_H3;
  float* h4     = ws + F_H4;
  float* h5     = ws + F_H5;
  float* priors = ws + F_PRI;
  float* caps   = ws + F_CAPS;
  float* logits = ws + F_LOG;
  float* probs  = ws + F_PRB;
  float* sbuf   = ws + F_S;
  float* souts  = ws + F_OUTS;
  float* stats  = ws + F_STAT;

  // ---- conv1: 3->128, 3x3 s1 p1, 128x128 ----
  conv_k<3, 1, 3, 10, 18><<<dim3(8, 16, 8 * 4), 256, 0, stream>>>(
      x, c1w, c1b, h1, 3, 128, 128, 128, 128, 128);
  hipMemsetAsync(stats, 0, 2 * 128 * sizeof(float), stream);
  bn_stats_k<<<128 * 16, 256, 0, stream>>>(h1, stats, 128, 14, 16, 131072);
  bn_fin_k<<<1, 256, 0, stream>>>(stats, g1, b1, 128, 1.f / 131072.f);
  bn_apply_k<<<2048, 256, 0, stream>>>(h1, stats, 128, 14, 4194304);

  // ---- conv2: 128->256, 3x3 s1 p1 ----
  conv_k<3, 1, 16, 10, 18><<<dim3(8, 16, 8 * 8), 256, 0, stream>>>(
      h1, c2w, c2b, h2, 128, 256, 128, 128, 128, 128);
  hipMemsetAsync(stats, 0, 2 * 256 * sizeof(float), stream);
  bn_stats_k<<<256 * 8, 256, 0, stream>>>(h2, stats, 256, 14, 8, 131072);
  bn_fin_k<<<1, 256, 0, stream>>>(stats, g2, b2, 256, 1.f / 131072.f);
  bn_apply_k<<<2048, 256, 0, stream>>>(h2, stats, 256, 14, 8388608);

  // ---- conv3: 256->64, 4x4 s2 p1, 128->64 ----
  conv_k<4, 2, 8, 18, 35><<<dim3(4, 8, 8 * 2), 256, 0, stream>>>(
      h2, c3w, c3b, h3, 256, 64, 128, 128, 64, 64);
  hipMemsetAsync(stats, 0, 2 * 64 * sizeof(float), stream);
  bn_stats_k<<<64 * 16, 256, 0, stream>>>(h3, stats, 64, 12, 16, 32768);
  bn_fin_k<<<1, 256, 0, stream>>>(stats, g3, b3, 64, 1.f / 32768.f);
  bn_apply_k<<<2048, 256, 0, stream>>>(h3, stats, 64, 12, 524288);

  // ---- conv4: 64->128, 4x4 s2 p1, 64->32 ----
  conv_k<4, 2, 8, 18, 35><<<dim3(2, 4, 8 * 4), 256, 0, stream>>>(
      h3, c4w, c4b, h4, 64, 128, 64, 64, 32, 32);
  hipMemsetAsync(stats, 0, 2 * 128 * sizeof(float), stream);
  bn_stats_k<<<128 * 8, 256, 0, stream>>>(h4, stats, 128, 10, 8, 8192);
  bn_fin_k<<<1, 256, 0, stream>>>(stats, g4, b4, 128, 1.f / 8192.f);
  bn_apply_k<<<1024, 256, 0, stream>>>(h4, stats, 128, 10, 262144);

  // ---- conv5: 128->256, 4x4 s2 p1, 32->16 ----
  conv_k<4, 2, 8, 18, 35><<<dim3(1, 2, 8 * 8), 256, 0, stream>>>(
      h4, c5w, c5b, h5, 128, 256, 32, 32, 16, 16);
  hipMemsetAsync(stats, 0, 2 * 256 * sizeof(float), stream);
  bn_stats_k<<<256 * 4, 256, 0, stream>>>(h5, stats, 256, 8, 4, 2048);
  bn_fin_k<<<1, 256, 0, stream>>>(stats, g5, b5, 256, 1.f / 2048.f);
  bn_apply_k<<<512, 256, 0, stream>>>(h5, stats, 256, 8, 131072);

  // ---- capsules ----
  caps_k<<<2048, 256, 0, stream>>>(h5, caps);
  priors_k<<<512, 256, 0, stream>>>(caps, rw, priors);

  // ---- routing: 3 iterations ----
  // iter 0 (uniform probs)
  hipMemsetAsync(sbuf, 0, NB * KO * sizeof(float), stream);
  route_s_partial<<<NB * 8, 256, 0, stream>>>(priors, probs, sbuf, 1);
  squash_k<<<(NB * NCLS + 255) / 256, 256, 0, stream>>>(sbuf, souts);
  logits_k<<<(NB * NCAP * NCLS + 255) / 256, 256, 0, stream>>>(priors, souts, logits, 0);
  // iter 1
  probs_k<<<(NB * NCAP + 255) / 256, 256, 0, stream>>>(logits, probs);
  hipMemsetAsync(sbuf, 0, NB * KO * sizeof(float), stream);
  route_s_partial<<<NB * 8, 256, 0, stream>>>(priors, probs, sbuf, 0);
  squash_k<<<(NB * NCLS + 255) / 256, 256, 0, stream>>>(sbuf, souts);
  logits_k<<<(NB * NCAP * NCLS + 255) / 256, 256, 0, stream>>>(priors, souts, logits, 1);
  // iter 2
  probs_k<<<(NB * NCAP + 255) / 256, 256, 0, stream>>>(logits, probs);
  hipMemsetAsync(sbuf, 0, NB * KO * sizeof(float), stream);
  route_s_partial<<<NB * 8, 256, 0, stream>>>(priors, probs, sbuf, 0);
  squash_k<<<(NB * NCLS + 255) / 256, 256, 0, stream>>>(sbuf, souts);

  // ---- final scatter ----
  out_k<<<(8 * 16 * NCLS * NO + 255) / 256, 256, 0, stream>>>(souts, out);
}

// Round 2
// 1565.539 us; speedup vs baseline: 1.7416x; 1.7416x over previous
//
#include <hip/hip_runtime.h>
#include <math.h>

typedef unsigned int  uint;
typedef unsigned short ushort;
using bf16x8 = __attribute__((ext_vector_type(8))) __bf16;
using f32x4  = __attribute__((ext_vector_type(4))) float;

constexpr int NB   = 128;      // capsule batch = G*G*B
constexpr int NCAP = 512;
constexpr int NCLS = 43;
constexpr int NO   = 21;
constexpr int KO   = NCLS * NO; // 903

// ---- workspace layout (float offsets) ----
// conv phase:
constexpr size_t F_XTH  = 0;          // Xt_hi: 16,777,216 bf16 (8,388,608 f32)
constexpr size_t F_XTL  = 8388608;    // Xt_lo
constexpr size_t F_STAT = 16777216;   // 1,024 f32
constexpr size_t F_WPH  = 16778240;   // Wp_hi: 294,912 bf16 (147,456 f32)
constexpr size_t F_WPL  = 16925696;   // Wp_lo
constexpr size_t F_H2   = 17073152;   // 33,554,432 f32, ends 50,627,584
constexpr size_t F_H1   = 48794368;   // h1 raw, 16,777,216 f32, ends 65,571,584
                                      // (overlaps H2 tail: h1raw dead during conv2 - conv2 reads only Xt)
// post-conv phase (Xt/Wp/h1 dead):
constexpr size_t F_H3   = 0;          //  2,097,152
constexpr size_t F_H4   = 2097152;    //  1,048,576
constexpr size_t F_H5   = 3145728;    //    524,288
constexpr size_t F_CAPS = 3670016;    //    524,288
constexpr size_t F_LOG  = 0;          //  2,818,048 (h3 dead)
constexpr size_t F_PRB  = 2818048;    //  2,818,048 (h4/h5/caps dead when first written)
constexpr size_t F_PRI  = 5636096;    // 59,179,008, ends 64,815,104
constexpr size_t F_S    = 64815104;   //    115,584
constexpr size_t F_OUTS = 64930688;   //    115,584
// total footprint: 65,571,584 f32 = 262,286,336 B (same as round 0)

__device__ inline ushort f2bf(float x) {
  uint u = __float_as_uint(x);
  uint r = (u + 0x7fffu + ((u >> 16) & 1u)) >> 16;  // RNE
  return (ushort)r;
}
__device__ inline float bf2f(ushort h) { return __uint_as_float(((uint)h) << 16); }

// ---------------- generic tiled direct conv (fp32), pad=1 -----------------
template<int KS, int STRIDE, int ICC, int IHT, int IWT>
__global__ __launch_bounds__(256) void conv_k(
    const float* __restrict__ in, const float* __restrict__ w,
    const float* __restrict__ bias, float* __restrict__ out,
    int IC, int OC, int IH, int IW, int OH, int OW)
{
  constexpr int BOC = 32;
  const int noc = OC >> 5;
  const int bz  = blockIdx.z;
  const int ocb = bz % noc;
  const int b   = bz / noc;
  const int tx0 = blockIdx.x * 16;
  const int ty0 = blockIdx.y * 8;
  const int oc0 = ocb * BOC;

  __shared__ float lin[ICC][IHT][IWT];
  __shared__ float lw[ICC][KS * KS][BOC];

  const int t  = threadIdx.x;
  const int pq = t & 3;
  const int ty = (t >> 2) & 7;
  const int oq = t >> 5;

  float acc[4][4];
#pragma unroll
  for (int m = 0; m < 4; ++m) {
    float bv = bias[oc0 + oq * 4 + m];
#pragma unroll
    for (int j = 0; j < 4; ++j) acc[m][j] = bv;
  }

  const int gx0 = tx0 * STRIDE - 1;
  const int gy0 = ty0 * STRIDE - 1;
  const int nch = IC / ICC;

  for (int ch = 0; ch < nch; ++ch) {
    const int ic0 = ch * ICC;
    __syncthreads();
    for (int e = t; e < ICC * IHT * IWT; e += 256) {
      int ic = e / (IHT * IWT);
      int rr = e % (IHT * IWT);
      int ey = rr / IWT, ex = rr % IWT;
      int gy = gy0 + ey, gx = gx0 + ex;
      float v = 0.f;
      if ((unsigned)gy < (unsigned)IH && (unsigned)gx < (unsigned)IW)
        v = in[((size_t)(b * IC + ic0 + ic) * IH + gy) * IW + gx];
      lin[ic][ey][ex] = v;
    }
    for (int e = t; e < ICC * KS * KS * BOC; e += 256) {
      int ocl = e & (BOC - 1);
      int rr  = e >> 5;
      int kk  = rr % (KS * KS);
      int ic  = rr / (KS * KS);
      lw[ic][kk][ocl] = w[((size_t)(oc0 + ocl) * IC + ic0 + ic) * (KS * KS) + kk];
    }
    __syncthreads();

    for (int ic = 0; ic < ICC; ++ic) {
#pragma unroll
      for (int ky = 0; ky < KS; ++ky) {
#pragma unroll
        for (int kx = 0; kx < KS; ++kx) {
          float xv[4];
#pragma unroll
          for (int j = 0; j < 4; ++j)
            xv[j] = lin[ic][ty * STRIDE + ky][(pq * 4 + j) * STRIDE + kx];
          const float4 w4 = *(const float4*)&lw[ic][ky * KS + kx][oq * 4];
#pragma unroll
          for (int j = 0; j < 4; ++j) {
            acc[0][j] = fmaf(w4.x, xv[j], acc[0][j]);
            acc[1][j] = fmaf(w4.y, xv[j], acc[1][j]);
            acc[2][j] = fmaf(w4.z, xv[j], acc[2][j]);
            acc[3][j] = fmaf(w4.w, xv[j], acc[3][j]);
          }
        }
      }
    }
  }

  const int oy = ty0 + ty;
#pragma unroll
  for (int m = 0; m < 4; ++m) {
    int oc = oc0 + oq * 4 + m;
    float* op = out + ((size_t)(b * OC + oc) * OH + oy) * OW + tx0 + pq * 4;
#pragma unroll
    for (int j = 0; j < 4; ++j) op[j] = acc[m][j];
  }
}

// ---------------- batch norm ----------------
__global__ __launch_bounds__(256) void bn_stats_k(
    const float* __restrict__ x, float* __restrict__ stats,
    int C, int sh, int split, int nelem)
{
  const int c = blockIdx.x / split;
  const int s = blockIdx.x % split;
  const int HW = 1 << sh;
  float sum = 0.f, sq = 0.f;
  for (int i = s * 256 + threadIdx.x; i < nelem; i += split * 256) {
    int b = i >> sh, r = i & (HW - 1);
    float v = x[((size_t)(b * C + c) << sh) + r];
    sum += v; sq += v * v;
  }
#pragma unroll
  for (int off = 32; off > 0; off >>= 1) {
    sum += __shfl_down(sum, off);
    sq  += __shfl_down(sq, off);
  }
  __shared__ float ls[4], lq[4];
  int wid = threadIdx.x >> 6, lane = threadIdx.x & 63;
  if (lane == 0) { ls[wid] = sum; lq[wid] = sq; }
  __syncthreads();
  if (threadIdx.x == 0) {
    atomicAdd(&stats[c], ls[0] + ls[1] + ls[2] + ls[3]);
    atomicAdd(&stats[C + c], lq[0] + lq[1] + lq[2] + lq[3]);
  }
}

__global__ void bn_fin_k(float* __restrict__ stats, const float* __restrict__ g,
                         const float* __restrict__ bt, int C, float inv_n)
{
  int c = threadIdx.x;
  if (c < C) {
    float m  = stats[c] * inv_n;
    float v  = stats[C + c] * inv_n - m * m;
    float rs = rsqrtf(v + 1e-5f);
    float sc = g[c] * rs;
    stats[2 * C + c] = sc;
    stats[3 * C + c] = bt[c] - m * sc;
  }
}

__global__ __launch_bounds__(256) void bn_apply_k(
    float* __restrict__ x, const float* __restrict__ stats,
    int C, int sh, int total4)
{
  const int stride = gridDim.x * 256;
  for (int i = blockIdx.x * 256 + threadIdx.x; i < total4; i += stride) {
    int c = (i >> (sh - 2)) & (C - 1);
    float sc = stats[2 * C + c], sf = stats[3 * C + c];
    float4 v = ((const float4*)x)[i];
    float t;
    t = fmaf(v.x, sc, sf); v.x = fmaxf(t, 0.1f * t);
    t = fmaf(v.y, sc, sf); v.y = fmaxf(t, 0.1f * t);
    t = fmaf(v.z, sc, sf); v.z = fmaxf(t, 0.1f * t);
    t = fmaf(v.w, sc, sf); v.w = fmaxf(t, 0.1f * t);
    ((float4*)x)[i] = v;
  }
}

// ------- fused BN+LReLU + bf16 hi/lo split + NCHW->NHWC transpose of h1 -------
// grid (4 icb, 128 y, 8 b), block 256
__global__ __launch_bounds__(256) void bn_t_split_k(
    const float* __restrict__ h1, const float* __restrict__ stats,
    ushort* __restrict__ xh, ushort* __restrict__ xl)
{
  const int icb = blockIdx.x, y = blockIdx.y, b = blockIdx.z;
  __shared__ uint tl[128][33];
  const int t = threadIdx.x;
  for (int e = t; e < 4096; e += 256) {
    int ic = e >> 7, x = e & 127;
    int c = icb * 32 + ic;
    float v = h1[(((size_t)b * 128 + c) * 128 + y) * 128 + x];
    float a = fmaf(v, stats[256 + c], stats[384 + c]);
    a = fmaxf(a, 0.1f * a);
    ushort hi = f2bf(a);
    ushort lo = f2bf(a - bf2f(hi));
    tl[x][ic] = (uint)hi | ((uint)lo << 16);
  }
  __syncthreads();
  for (int e = t; e < 4096; e += 256) {
    int x = e >> 5, ic = e & 31;
    uint v = tl[x][ic];
    size_t o = (((size_t)b * 128 + y) * 128 + x) * 128 + icb * 32 + ic;
    xh[o] = (ushort)(v & 0xffffu);
    xl[o] = (ushort)(v >> 16);
  }
}

// ------- weight split/reorder: [oc][ic][3][3] f32 -> [k][oc][ic] bf16 hi/lo -------
__global__ void wsplit_k(const float* __restrict__ w,
                         ushort* __restrict__ wh, ushort* __restrict__ wl)
{
  int i = blockIdx.x * 256 + threadIdx.x;
  if (i >= 256 * 128 * 9) return;
  int k = i % 9; int r = i / 9; int ic = r & 127; int oc = r >> 7;
  float v = w[i];
  ushort hi = f2bf(v);
  ushort lo = f2bf(v - bf2f(hi));
  size_t d = ((size_t)k * 256 + oc) * 128 + ic;
  wh[d] = hi; wl[d] = lo;
}

// ------- conv2 via MFMA implicit GEMM (bf16x3 split, fp32 accum) -------
// grid (2 ocT, 64 row-pairs, 8 b), 256 thr = 4 waves
// block tile: 256 px (2 rows) x 128 oc; wave tile: 64 px x 128 oc
__global__ __launch_bounds__(256, 2) void conv2_mfma_k(
    const ushort* __restrict__ xh, const ushort* __restrict__ xl,
    const ushort* __restrict__ wph, const ushort* __restrict__ wpl,
    float* __restrict__ h2)
{
  const int ocT = blockIdx.x;
  const int y0  = blockIdx.y * 2;
  const int b   = blockIdx.z;

  __shared__ ushort xs[2][2][132][32];   // [hl][row][xi][ic] : 33,792 B
  __shared__ ushort wsm[2][2][128][32];  // [buf][hl][oc][ic] : 32,768 B

  const int t  = threadIdx.x;
  const int w  = t >> 6;
  const int l  = t & 63;
  const int rsel = w >> 1;        // output row within pair
  const int xb   = (w & 1) * 64;  // x base
  const int lr = l & 15;
  const int kg = l >> 4;

  f32x4 acc[8][4];
#pragma unroll
  for (int i = 0; i < 8; ++i)
#pragma unroll
    for (int j = 0; j < 4; ++j) acc[i][j] = (f32x4){0.f, 0.f, 0.f, 0.f};

  for (int ky = 0; ky < 3; ++ky) {
    const int gy0 = y0 + ky - 1;
    for (int ic32 = 0; ic32 < 4; ++ic32) {
      __syncthreads();
      // stage X: 2 rows x 130 xi x 4 icg, hi+lo
      for (int e = t; e < 1040; e += 256) {
        int r   = e / 520;
        int q   = e - r * 520;
        int xi  = q >> 2;
        int icg = q & 3;
        int gy = gy0 + r, gx = xi - 1;
        uint4 vh = {0, 0, 0, 0}, vl = {0, 0, 0, 0};
        if ((unsigned)gy < 128u && (unsigned)gx < 128u) {
          size_t gi = (((size_t)b * 128 + gy) * 128 + gx) * 128 + ic32 * 32 + icg * 8;
          vh = *(const uint4*)(xh + gi);
          vl = *(const uint4*)(xl + gi);
        }
        *(uint4*)&xs[0][r][xi][icg * 8] = vh;
        *(uint4*)&xs[1][r][xi][icg * 8] = vl;
      }
      // stage W for kx=0 into buf 0
      {
        const int kk = ky * 3;
        for (int e = t; e < 512; e += 256) {
          int oc = e >> 2, icg = e & 3;
          size_t gi = (((size_t)kk * 256 + ocT * 128 + oc) * 128) + ic32 * 32 + icg * 8;
          *(uint4*)&wsm[0][0][oc][icg * 8] = *(const uint4*)(wph + gi);
          *(uint4*)&wsm[0][1][oc][icg * 8] = *(const uint4*)(wpl + gi);
        }
      }
      __syncthreads();

      for (int kx = 0; kx < 3; ++kx) {
        if (kx) __syncthreads();
        if (kx < 2) {
          const int kk = ky * 3 + kx + 1;
          const int buf = (kx + 1) & 1;
          for (int e = t; e < 512; e += 256) {
            int oc = e >> 2, icg = e & 3;
            size_t gi = (((size_t)kk * 256 + ocT * 128 + oc) * 128) + ic32 * 32 + icg * 8;
            *(uint4*)&wsm[buf][0][oc][icg * 8] = *(const uint4*)(wph + gi);
            *(uint4*)&wsm[buf][1][oc][icg * 8] = *(const uint4*)(wpl + gi);
          }
        }
        const int buf = kx & 1;
        bf16x8 awh[8], awl[8], xbh[4], xbl[4];
#pragma unroll
        for (int of = 0; of < 8; ++of) {
          awh[of] = *(const bf16x8*)&wsm[buf][0][of * 16 + lr][kg * 8];
          awl[of] = *(const bf16x8*)&wsm[buf][1][of * 16 + lr][kg * 8];
        }
#pragma unroll
        for (int pf = 0; pf < 4; ++pf) {
          int xi = xb + pf * 16 + lr + kx;
          xbh[pf] = *(const bf16x8*)&xs[0][rsel][xi][kg * 8];
          xbl[pf] = *(const bf16x8*)&xs[1][rsel][xi][kg * 8];
        }
#pragma unroll
        for (int of = 0; of < 8; ++of) {
#pragma unroll
          for (int pf = 0; pf < 4; ++pf) {
            acc[of][pf] = __builtin_amdgcn_mfma_f32_16x16x32_bf16(awh[of], xbh[pf], acc[of][pf], 0, 0, 0);
            acc[of][pf] = __builtin_amdgcn_mfma_f32_16x16x32_bf16(awh[of], xbl[pf], acc[of][pf], 0, 0, 0);
            acc[of][pf] = __builtin_amdgcn_mfma_f32_16x16x32_bf16(awl[of], xbh[pf], acc[of][pf], 0, 0, 0);
          }
        }
      }
    }
  }

  // C write: D col = lane&15 (px), row = (lane>>4)*4 + r (oc)
  const int yy = y0 + rsel;
#pragma unroll
  for (int of = 0; of < 8; ++of) {
#pragma unroll
    for (int pf = 0; pf < 4; ++pf) {
      int oc = ocT * 128 + of * 16 + kg * 4;
      int x  = xb + pf * 16 + lr;
      float* p = h2 + (((size_t)b * 256 + oc) * 128 + yy) * 128 + x;
      p[0]         = acc[of][pf][0];
      p[16384]     = acc[of][pf][1];
      p[2 * 16384] = acc[of][pf][2];
      p[3 * 16384] = acc[of][pf][3];
    }
  }
}

// ---------------- capsule rearrange ----------------
__global__ void caps_k(const float* __restrict__ h5, float* __restrict__ caps)
{
  int e = blockIdx.x * 256 + threadIdx.x;
  if (e >= NB * NCAP * 8) return;
  int ii = e & 7;
  int n  = (e >> 3) & 511;
  int jb = e >> 12;
  int j = jb >> 3, b = jb & 7;
  int i = n >> 7, k = (n >> 5) & 3, ch = ((n & 31) << 3) | ii;
  int hh = (i << 2) | (j >> 2);
  int ww = ((j & 3) << 2) | k;
  caps[e] = h5[((size_t)(b * 256 + ch) * 16 + hh) * 16 + ww];
}

// ---------------- priors ----------------
__global__ __launch_bounds__(256) void priors_k(
    const float* __restrict__ caps, const float* __restrict__ rw,
    float* __restrict__ priors)
{
  const int n = blockIdx.x;
  __shared__ float lrw[NCLS * 8 * NO];
  __shared__ float lc[NB * 8];
  const int t = threadIdx.x;
  for (int e = t; e < NCLS * 8 * NO; e += 256)
    lrw[e] = rw[(size_t)n * NCLS * 8 * NO + e];
  for (int e = t; e < NB * 8; e += 256) {
    int b = e >> 3, ii = e & 7;
    lc[e] = caps[((size_t)b * NCAP + n) * 8 + ii];
  }
  __syncthreads();

  int p[4], kk[4], oo[4];
#pragma unroll
  for (int q = 0; q < 4; ++q) {
    p[q]  = t + q * 256;
    kk[q] = (p[q] < KO) ? p[q] / NO : 0;
    oo[q] = (p[q] < KO) ? p[q] % NO : 0;
  }
  for (int b = 0; b < NB; ++b) {
    const float* cb = &lc[b * 8];
    float c0 = cb[0], c1 = cb[1], c2 = cb[2], c3 = cb[3];
    float c4 = cb[4], c5 = cb[5], c6 = cb[6], c7 = cb[7];
    float* pout = priors + ((size_t)b * NCAP + n) * KO;
#pragma unroll
    for (int q = 0; q < 4; ++q) {
      if (p[q] < KO) {
        const float* wv = &lrw[kk[q] * (8 * NO) + oo[q]];
        float a = c0 * wv[0];
        a = fmaf(c1, wv[21],  a);
        a = fmaf(c2, wv[42],  a);
        a = fmaf(c3, wv[63],  a);
        a = fmaf(c4, wv[84],  a);
        a = fmaf(c5, wv[105], a);
        a = fmaf(c6, wv[126], a);
        a = fmaf(c7, wv[147], a);
        pout[p[q]] = a;
      }
    }
  }
}

// ---------------- routing ----------------
__global__ __launch_bounds__(256) void route_s_partial(
    const float* __restrict__ priors, const float* __restrict__ probs,
    float* __restrict__ s, int uniform)
{
  const int b  = blockIdx.x >> 3;
  const int ns = blockIdx.x & 7;
  const int t  = threadIdx.x;
  const int p0 = t, p1 = t + 256, p2 = t + 512, p3 = t + 768;
  const int k0 = p0 / NO, k1 = p1 / NO, k2 = p2 / NO;
  const int k3 = (p3 < KO) ? p3 / NO : 0;
  float a0 = 0.f, a1 = 0.f, a2 = 0.f, a3 = 0.f;
  const float* pb  = priors + ((size_t)b * NCAP + ns * 64) * KO;
  const float* prb = probs + ((size_t)b * NCAP + ns * 64) * NCLS;
#pragma unroll 2
  for (int n = 0; n < 64; ++n) {
    const float* pn = pb + (size_t)n * KO;
    if (uniform) {
      a0 += pn[p0]; a1 += pn[p1]; a2 += pn[p2];
      if (p3 < KO) a3 += pn[p3];
    } else {
      const float* pr = prb + n * NCLS;
      a0 = fmaf(pr[k0], pn[p0], a0);
      a1 = fmaf(pr[k1], pn[p1], a1);
      a2 = fmaf(pr[k2], pn[p2], a2);
      if (p3 < KO) a3 = fmaf(pr[k3], pn[p3], a3);
    }
  }
  const float sc = uniform ? (1.f / 43.f) : 1.f;
  atomicAdd(&s[b * KO + p0], a0 * sc);
  atomicAdd(&s[b * KO + p1], a1 * sc);
  atomicAdd(&s[b * KO + p2], a2 * sc);
  if (p3 < KO) atomicAdd(&s[b * KO + p3], a3 * sc);
}

__global__ void squash_k(const float* __restrict__ s, float* __restrict__ souts)
{
  int i = blockIdx.x * 256 + threadIdx.x;
  if (i >= NB * NCLS) return;
  int b = i / NCLS, k = i % NCLS;
  const float* sv = s + b * KO + k * NO;
  float sn = 0.f;
#pragma unroll
  for (int o = 0; o < NO; ++o) sn += sv[o] * sv[o];
  float f = sqrtf(sn) / (1.f + sn);
  float* ov = souts + b * KO + k * NO;
#pragma unroll
  for (int o = 0; o < NO; ++o) ov[o] = sv[o] * f;
}

__global__ __launch_bounds__(256) void logits_k(
    const float* __restrict__ priors, const float* __restrict__ souts,
    float* __restrict__ logits, int accum)
{
  int i = blockIdx.x * 256 + threadIdx.x;
  if (i >= NB * NCAP * NCLS) return;
  int k  = i % NCLS;
  int bn = i / NCLS;
  int b  = bn >> 9;
  const float* pv = priors + (size_t)bn * KO + k * NO;
  const float* ov = souts + b * KO + k * NO;
  float d = 0.f;
#pragma unroll
  for (int o = 0; o < NO; ++o) d = fmaf(pv[o], ov[o], d);
  logits[i] = (accum ? logits[i] : 0.f) + d;
}

__global__ __launch_bounds__(256) void probs_k(
    const float* __restrict__ logits, float* __restrict__ probs)
{
  int bn = blockIdx.x * 256 + threadIdx.x;
  if (bn >= NB * NCAP) return;
  const float* lg = logits + (size_t)bn * NCLS;
  float e[NCLS];
  float mx = -1e30f;
#pragma unroll
  for (int k = 0; k < NCLS; ++k) { e[k] = lg[k]; mx = fmaxf(mx, e[k]); }
  float sm = 0.f;
#pragma unroll
  for (int k = 0; k < NCLS; ++k) { e[k] = expf(e[k] - mx); sm += e[k]; }
  float inv = 1.f / sm;
  float* pb = probs + (size_t)bn * NCLS;
#pragma unroll
  for (int k = 0; k < NCLS; ++k) pb[k] = e[k] * inv;
}

__global__ void out_k(const float* __restrict__ souts, float* __restrict__ out)
{
  int i = blockIdx.x * 256 + threadIdx.x;
  if (i >= 8 * 16 * NCLS * NO) return;
  int o = i % NO;
  int r = i / NO;
  int k = r % NCLS; r /= NCLS;
  int g1 = r & 3; r >>= 2;
  int g0 = r & 3;
  int b  = r >> 2;
  int j  = g0 * 4 + g1;
  int jb = j * 8 + b;
  out[i] = souts[jb * KO + k * NO + o];
}

// ---------------- launcher ----------------
extern "C" void kernel_launch(void* const* d_in, const int* in_sizes, int n_in,
                              void* d_out, int out_size, void* d_ws, size_t ws_size,
                              hipStream_t stream)
{
  const float* x   = (const float*)d_in[0];
  const float* c1w = (const float*)d_in[1];  const float* c1b = (const float*)d_in[2];
  const float* g1  = (const float*)d_in[3];  const float* b1  = (const float*)d_in[4];
  const float* c2w = (const float*)d_in[5];
  const float* g2  = (const float*)d_in[7];  const float* b2  = (const float*)d_in[8];
  const float* c3w = (const float*)d_in[9];  const float* c3b = (const float*)d_in[10];
  const float* g3  = (const float*)d_in[11]; const float* b3  = (const float*)d_in[12];
  const float* c4w = (const float*)d_in[13]; const float* c4b = (const float*)d_in[14];
  const float* g4  = (const float*)d_in[15]; const float* b4  = (const float*)d_in[16];
  const float* c5w = (const float*)d_in[17]; const float* c5b = (const float*)d_in[18];
  const float* g5  = (const float*)d_in[19]; const float* b5  = (const float*)d_in[20];
  const float* rw  = (const float*)d_in[21];

  float* ws  = (float*)d_ws;
  float* out = (float*)d_out;

  ushort* xth = (ushort*)(ws + F_XTH);
  ushort* xtl = (ushort*)(ws + F_XTL);
  ushort* wph = (ushort*)(ws + F_WPH);
  ushort* wpl = (ushort*)(ws + F_WPL);
  float* h1     = ws + F_H1;
  float* h2     = ws + F_H2;
  float* h3     = ws + F_H3;
  float* h4     = ws + F_H4;
  float* h5     = ws + F_H5;
  float* caps   = ws + F_CAPS;
  float* priors = ws + F_PRI;
  float* logits = ws + F_LOG;
  float* probs  = ws + F_PRB;
  float* sbuf   = ws + F_S;
  float* souts  = ws + F_OUTS;
  float* stats  = ws + F_STAT;

  // ---- weight split for conv2 (independent of conv1) ----
  wsplit_k<<<(256 * 128 * 9 + 255) / 256, 256, 0, stream>>>(c2w, wph, wpl);

  // ---- conv1: 3->128, 3x3 s1 p1 ----
  conv_k<3, 1, 3, 10, 18><<<dim3(8, 16, 8 * 4), 256, 0, stream>>>(
      x, c1w, c1b, h1, 3, 128, 128, 128, 128, 128);
  hipMemsetAsync(stats, 0, 2 * 128 * sizeof(float), stream);
  bn_stats_k<<<128 * 16, 256, 0, stream>>>(h1, stats, 128, 14, 16, 131072);
  bn_fin_k<<<1, 256, 0, stream>>>(stats, g1, b1, 128, 1.f / 131072.f);
  // fused BN+LReLU + split + transpose -> Xt hi/lo
  bn_t_split_k<<<dim3(4, 128, 8), 256, 0, stream>>>(h1, stats, xth, xtl);

  // ---- conv2: MFMA implicit GEMM ----
  conv2_mfma_k<<<dim3(2, 64, 8), 256, 0, stream>>>(xth, xtl, wph, wpl, h2);
  hipMemsetAsync(stats, 0, 2 * 256 * sizeof(float), stream);
  bn_stats_k<<<256 * 8, 256, 0, stream>>>(h2, stats, 256, 14, 8, 131072);
  bn_fin_k<<<1, 256, 0, stream>>>(stats, g2, b2, 256, 1.f / 131072.f);
  bn_apply_k<<<2048, 256, 0, stream>>>(h2, stats, 256, 14, 8388608);

  // ---- conv3: 256->64, 4x4 s2 p1 ----
  conv_k<4, 2, 8, 18, 35><<<dim3(4, 8, 8 * 2), 256, 0, stream>>>(
      h2, c3w, c3b, h3, 256, 64, 128, 128, 64, 64);
  hipMemsetAsync(stats, 0, 2 * 64 * sizeof(float), stream);
  bn_stats_k<<<64 * 16, 256, 0, stream>>>(h3, stats, 64, 12, 16, 32768);
  bn_fin_k<<<1, 256, 0, stream>>>(stats, g3, b3, 64, 1.f / 32768.f);
  bn_apply_k<<<2048, 256, 0, stream>>>(h3, stats, 64, 12, 524288);

  // ---- conv4: 64->128, 4x4 s2 p1 ----
  conv_k<4, 2, 8, 18, 35><<<dim3(2, 4, 8 * 4), 256, 0, stream>>>(
      h3, c4w, c4b, h4, 64, 128, 64, 64, 32, 32);
  hipMemsetAsync(stats, 0, 2 * 128 * sizeof(float), stream);
  bn_stats_k<<<128 * 8, 256, 0, stream>>>(h4, stats, 128, 10, 8, 8192);
  bn_fin_k<<<1, 256, 0, stream>>>(stats, g4, b4, 128, 1.f / 8192.f);
  bn_apply_k<<<1024, 256, 0, stream>>>(h4, stats, 128, 10, 262144);

  // ---- conv5: 128->256, 4x4 s2 p1 ----
  conv_k<4, 2, 8, 18, 35><<<dim3(1, 2, 8 * 8), 256, 0, stream>>>(
      h4, c5w, c5b, h5, 128, 256, 32, 32, 16, 16);
  hipMemsetAsync(stats, 0, 2 * 256 * sizeof(float), stream);
  bn_stats_k<<<256 * 4, 256, 0, stream>>>(h5, stats, 256, 8, 4, 2048);
  bn_fin_k<<<1, 256, 0, stream>>>(stats, g5, b5, 256, 1.f / 2048.f);
  bn_apply_k<<<512, 256, 0, stream>>>(h5, stats, 256, 8, 131072);

  // ---- capsules ----
  caps_k<<<2048, 256, 0, stream>>>(h5, caps);
  priors_k<<<512, 256, 0, stream>>>(caps, rw, priors);

  // ---- routing: 3 iterations ----
  hipMemsetAsync(sbuf, 0, NB * KO * sizeof(float), stream);
  route_s_partial<<<NB * 8, 256, 0, stream>>>(priors, probs, sbuf, 1);
  squash_k<<<(NB * NCLS + 255) / 256, 256, 0, stream>>>(sbuf, souts);
  logits_k<<<(NB * NCAP * NCLS + 255) / 256, 256, 0, stream>>>(priors, souts, logits, 0);
  probs_k<<<(NB * NCAP + 255) / 256, 256, 0, stream>>>(logits, probs);
  hipMemsetAsync(sbuf, 0, NB * KO * sizeof(float), stream);
  route_s_partial<<<NB * 8, 256, 0, stream>>>(priors, probs, sbuf, 0);
  squash_k<<<(NB * NCLS + 255) / 256, 256, 0, stream>>>(sbuf, souts);
  logits_k<<<(NB * NCAP * NCLS + 255) / 256, 256, 0, stream>>>(priors, souts, logits, 1);
  probs_k<<<(NB * NCAP + 255) / 256, 256, 0, stream>>>(logits, probs);
  hipMemsetAsync(sbuf, 0, NB * KO * sizeof(float), stream);
  route_s_partial<<<NB * 8, 256, 0, stream>>>(priors, probs, sbuf, 0);
  squash_k<<<(NB * NCLS + 255) / 256, 256, 0, stream>>>(sbuf, souts);

  // ---- final scatter ----
  out_k<<<(8 * 16 * NCLS * NO + 255) / 256, 256, 0, stream>>>(souts, out);
}

// Round 3
// 1296.756 us; speedup vs baseline: 2.1025x; 1.2073x over previous
//
#include <hip/hip_runtime.h>
#include <math.h>

typedef unsigned int   uint;
typedef unsigned short ushort;
using bf16x8 = __attribute__((ext_vector_type(8))) __bf16;
using f32x4  = __attribute__((ext_vector_type(4))) float;

constexpr int NB   = 128;
constexpr int NCAP = 512;
constexpr int NCLS = 43;
constexpr int NO   = 21;
constexpr int KO   = NCLS * NO; // 903

// ---- workspace layout (float offsets) ----
constexpr size_t F_XTH  = 0;          // h1 split hi (16.8M ushort = 8,388,608 f32)
constexpr size_t F_XTL  = 8388608;    // h1 split lo
constexpr size_t F_STAT = 16777216;   // 1,024
constexpr size_t F_WPH  = 16778240;   // conv2 w hi (147,456)
constexpr size_t F_WPL  = 16925696;
constexpr size_t F_W3H  = 17073152;   // conv3 w hi (131,072)
constexpr size_t F_W3L  = 17204224;
constexpr size_t F_W4H  = 17335296;   // conv4 w hi (65,536)
constexpr size_t F_W4L  = 17400832;
constexpr size_t F_W5H  = 17466368;   // conv5 w hi (262,144)
constexpr size_t F_W5L  = 17728512;
constexpr size_t F_H1   = 17990656;   // h1 raw fp32 NCHW (16,777,216) — dead before conv2 writes X3H here
constexpr size_t F_X3H  = 17990656;   // conv2 out hi, blocked [32][131072][8] bf16 (16,777,216 f32)
constexpr size_t F_X3L  = 34767872;   // ends 51,545,088
constexpr size_t F_H3   = 51545088;   // h3 NHWC fp32 (2,097,152)
constexpr size_t F_X4H  = 53642240;   // (1,048,576)
constexpr size_t F_X4L  = 54690816;
constexpr size_t F_H4   = 55739392;   // (1,048,576)
constexpr size_t F_X5H  = 56787968;   // (524,288)
constexpr size_t F_X5L  = 57312256;
constexpr size_t F_H5   = 57836544;   // h5 NHWC fp32 (524,288)
// routing phase (conv buffers dead except caps):
constexpr size_t F_PRI  = 0;          // 59,179,008
constexpr size_t F_CAPS = 59179008;   // 524,288
constexpr size_t F_LOG  = 59703296;   // 2,818,048
constexpr size_t F_PRB  = 62521344;   // 2,818,048
constexpr size_t F_S    = 65339392;   // 115,584
constexpr size_t F_OUTS = 65454976;   // 115,584 -> ends 65,570,560 (< 65,571,584 budget)

__device__ inline ushort f2bf(float x) {
  uint u = __float_as_uint(x);
  uint r = (u + 0x7fffu + ((u >> 16) & 1u)) >> 16;  // RNE
  return (ushort)r;
}
__device__ inline float bf2f(ushort h) { return __uint_as_float(((uint)h) << 16); }

// ---------------- conv1: fp32 direct (3->128, 3x3, s1, p1) -----------------
template<int KS, int STRIDE, int ICC, int IHT, int IWT>
__global__ __launch_bounds__(256) void conv_k(
    const float* __restrict__ in, const float* __restrict__ w,
    float* __restrict__ out, int IC, int OC, int IH, int IW, int OH, int OW)
{
  constexpr int BOC = 32;
  const int noc = OC >> 5;
  const int bz  = blockIdx.z;
  const int ocb = bz % noc;
  const int b   = bz / noc;
  const int tx0 = blockIdx.x * 16;
  const int ty0 = blockIdx.y * 8;
  const int oc0 = ocb * BOC;

  __shared__ float lin[ICC][IHT][IWT];
  __shared__ float lw[ICC][KS * KS][BOC];

  const int t  = threadIdx.x;
  const int pq = t & 3;
  const int ty = (t >> 2) & 7;
  const int oq = t >> 5;

  float acc[4][4];
#pragma unroll
  for (int m = 0; m < 4; ++m)
#pragma unroll
    for (int j = 0; j < 4; ++j) acc[m][j] = 0.f;

  const int gx0 = tx0 * STRIDE - 1;
  const int gy0 = ty0 * STRIDE - 1;
  const int nch = IC / ICC;

  for (int ch = 0; ch < nch; ++ch) {
    const int ic0 = ch * ICC;
    __syncthreads();
    for (int e = t; e < ICC * IHT * IWT; e += 256) {
      int ic = e / (IHT * IWT);
      int rr = e % (IHT * IWT);
      int ey = rr / IWT, ex = rr % IWT;
      int gy = gy0 + ey, gx = gx0 + ex;
      float v = 0.f;
      if ((unsigned)gy < (unsigned)IH && (unsigned)gx < (unsigned)IW)
        v = in[((size_t)(b * IC + ic0 + ic) * IH + gy) * IW + gx];
      lin[ic][ey][ex] = v;
    }
    for (int e = t; e < ICC * KS * KS * BOC; e += 256) {
      int ocl = e & (BOC - 1);
      int rr  = e >> 5;
      int kk  = rr % (KS * KS);
      int ic  = rr / (KS * KS);
      lw[ic][kk][ocl] = w[((size_t)(oc0 + ocl) * IC + ic0 + ic) * (KS * KS) + kk];
    }
    __syncthreads();

    for (int ic = 0; ic < ICC; ++ic) {
#pragma unroll
      for (int ky = 0; ky < KS; ++ky) {
#pragma unroll
        for (int kx = 0; kx < KS; ++kx) {
          float xv[4];
#pragma unroll
          for (int j = 0; j < 4; ++j)
            xv[j] = lin[ic][ty * STRIDE + ky][(pq * 4 + j) * STRIDE + kx];
          const float4 w4 = *(const float4*)&lw[ic][ky * KS + kx][oq * 4];
#pragma unroll
          for (int j = 0; j < 4; ++j) {
            acc[0][j] = fmaf(w4.x, xv[j], acc[0][j]);
            acc[1][j] = fmaf(w4.y, xv[j], acc[1][j]);
            acc[2][j] = fmaf(w4.z, xv[j], acc[2][j]);
            acc[3][j] = fmaf(w4.w, xv[j], acc[3][j]);
          }
        }
      }
    }
  }

  const int oy = ty0 + ty;
#pragma unroll
  for (int m = 0; m < 4; ++m) {
    int oc = oc0 + oq * 4 + m;
    float* op = out + ((size_t)(b * OC + oc) * OH + oy) * OW + tx0 + pq * 4;
#pragma unroll
    for (int j = 0; j < 4; ++j) op[j] = acc[m][j];
  }
}

// ---------------- BN stats: NCHW (h1 only) ----------------
__global__ __launch_bounds__(256) void bn_stats_k(
    const float* __restrict__ x, float* __restrict__ stats,
    int C, int sh, int split, int nelem)
{
  const int c = blockIdx.x / split;
  const int s = blockIdx.x % split;
  const int HW = 1 << sh;
  float sum = 0.f, sq = 0.f;
  for (int i = s * 256 + threadIdx.x; i < nelem; i += split * 256) {
    int b = i >> sh, r = i & (HW - 1);
    float v = x[((size_t)(b * C + c) << sh) + r];
    sum += v; sq += v * v;
  }
#pragma unroll
  for (int off = 32; off > 0; off >>= 1) {
    sum += __shfl_down(sum, off);
    sq  += __shfl_down(sq, off);
  }
  __shared__ float ls[4], lq[4];
  int wid = threadIdx.x >> 6, lane = threadIdx.x & 63;
  if (lane == 0) { ls[wid] = sum; lq[wid] = sq; }
  __syncthreads();
  if (threadIdx.x == 0) {
    atomicAdd(&stats[c], ls[0] + ls[1] + ls[2] + ls[3]);
    atomicAdd(&stats[C + c], lq[0] + lq[1] + lq[2] + lq[3]);
  }
}

// ---------------- BN stats: NHWC fp32 (h3,h4,h5) ----------------
__global__ __launch_bounds__(256) void bn_stats_nhwc_k(
    const float* __restrict__ x, float* __restrict__ stats,
    int cmask, int lg2c, int totpx)
{
  int g = blockIdx.x * 256 + threadIdx.x;
  int c = g & cmask;
  int p0 = g >> lg2c;
  int stride = (gridDim.x * 256) >> lg2c;
  float s = 0.f, q = 0.f;
  for (int p = p0; p < totpx; p += stride) {
    float v = x[((size_t)p << lg2c) | c];
    s += v; q += v * v;
  }
  atomicAdd(&stats[c], s);
  atomicAdd(&stats[cmask + 1 + c], q);
}

// ---------------- BN stats: blocked bf16 hi/lo (conv2 out) ----------------
__global__ __launch_bounds__(256) void bn_stats_blocked_k(
    const ushort* __restrict__ xh, const ushort* __restrict__ xl,
    float* __restrict__ stats, int nj, int totpx, int slices)
{
  const int j  = blockIdx.x % nj;
  const int sl = blockIdx.x / nj;
  float s[8] = {0,0,0,0,0,0,0,0}, q[8] = {0,0,0,0,0,0,0,0};
  const ushort* ph = xh + (size_t)j * totpx * 8;
  const ushort* pl = xl + (size_t)j * totpx * 8;
  for (int p = sl * 256 + threadIdx.x; p < totpx; p += slices * 256) {
    uint4 vh = *(const uint4*)(ph + (size_t)p * 8);
    uint4 vl = *(const uint4*)(pl + (size_t)p * 8);
    uint hw[4] = {vh.x, vh.y, vh.z, vh.w};
    uint lw[4] = {vl.x, vl.y, vl.z, vl.w};
#pragma unroll
    for (int m = 0; m < 4; ++m) {
      float v0 = __uint_as_float(hw[m] << 16) + __uint_as_float(lw[m] << 16);
      float v1 = __uint_as_float(hw[m] & 0xffff0000u) + __uint_as_float(lw[m] & 0xffff0000u);
      s[2*m] += v0; q[2*m] += v0 * v0;
      s[2*m+1] += v1; q[2*m+1] += v1 * v1;
    }
  }
#pragma unroll
  for (int off = 32; off > 0; off >>= 1)
#pragma unroll
    for (int k = 0; k < 8; ++k) {
      s[k] += __shfl_down(s[k], off);
      q[k] += __shfl_down(q[k], off);
    }
  __shared__ float red[4][16];
  int wid = threadIdx.x >> 6, lane = threadIdx.x & 63;
  if (lane == 0) {
#pragma unroll
    for (int k = 0; k < 8; ++k) { red[wid][k] = s[k]; red[wid][8 + k] = q[k]; }
  }
  __syncthreads();
  if (threadIdx.x < 16) {
    float a = red[0][threadIdx.x] + red[1][threadIdx.x] + red[2][threadIdx.x] + red[3][threadIdx.x];
    int C = nj * 8;
    int c = j * 8 + (threadIdx.x & 7);
    atomicAdd(&stats[(threadIdx.x >> 3) * C + c], a);
  }
}

__global__ void bn_fin_k(float* __restrict__ stats, const float* __restrict__ g,
                         const float* __restrict__ bt, int C, float inv_n)
{
  int c = threadIdx.x;
  if (c < C) {
    float m  = stats[c] * inv_n;
    float v  = stats[C + c] * inv_n - m * m;
    float rs = rsqrtf(v + 1e-5f);
    float sc = g[c] * rs;
    stats[2 * C + c] = sc;
    stats[3 * C + c] = bt[c] - m * sc;
  }
}

// ---- in-place BN+LReLU on blocked bf16 hi/lo (conv2 out -> conv3 in) ----
__global__ __launch_bounds__(256) void bn_apply_blocked_k(
    ushort* __restrict__ xh, ushort* __restrict__ xl,
    const float* __restrict__ stats, int C, int lg2tot, size_t total)
{
  size_t stride = (size_t)gridDim.x * 256;
  for (size_t i = (size_t)blockIdx.x * 256 + threadIdx.x; i < total; i += stride) {
    int j = (int)(i >> lg2tot);
    uint4 vh = *(const uint4*)(xh + i * 8);
    uint4 vl = *(const uint4*)(xl + i * 8);
    int c0 = j * 8;
    float4 sc0 = *(const float4*)&stats[2 * C + c0];
    float4 sc1 = *(const float4*)&stats[2 * C + c0 + 4];
    float4 sf0 = *(const float4*)&stats[3 * C + c0];
    float4 sf1 = *(const float4*)&stats[3 * C + c0 + 4];
    float scv[8] = {sc0.x, sc0.y, sc0.z, sc0.w, sc1.x, sc1.y, sc1.z, sc1.w};
    float sfv[8] = {sf0.x, sf0.y, sf0.z, sf0.w, sf1.x, sf1.y, sf1.z, sf1.w};
    uint hw[4] = {vh.x, vh.y, vh.z, vh.w};
    uint lw[4] = {vl.x, vl.y, vl.z, vl.w};
    uint oh[4], ol[4];
#pragma unroll
    for (int m = 0; m < 4; ++m) {
      float v0 = __uint_as_float(hw[m] << 16) + __uint_as_float(lw[m] << 16);
      float v1 = __uint_as_float(hw[m] & 0xffff0000u) + __uint_as_float(lw[m] & 0xffff0000u);
      float a0 = fmaf(v0, scv[2*m], sfv[2*m]);     a0 = fmaxf(a0, 0.1f * a0);
      float a1 = fmaf(v1, scv[2*m+1], sfv[2*m+1]); a1 = fmaxf(a1, 0.1f * a1);
      ushort h0 = f2bf(a0); ushort l0 = f2bf(a0 - bf2f(h0));
      ushort h1 = f2bf(a1); ushort l1 = f2bf(a1 - bf2f(h1));
      oh[m] = (uint)h0 | ((uint)h1 << 16);
      ol[m] = (uint)l0 | ((uint)l1 << 16);
    }
    uint4 rh = {oh[0], oh[1], oh[2], oh[3]};
    uint4 rl = {ol[0], ol[1], ol[2], ol[3]};
    *(uint4*)(xh + i * 8) = rh;
    *(uint4*)(xl + i * 8) = rl;
  }
}

// ---- BN+LReLU+split fp32 NHWC -> blocked bf16 hi/lo (h3->X4, h4->X5) ----
template<int C>
__global__ __launch_bounds__(256) void split_blocked_k(
    const float* __restrict__ h, const float* __restrict__ stats,
    ushort* __restrict__ oh, ushort* __restrict__ ol, int totpx)
{
  __shared__ ushort lh[16][C + 8], ll[16][C + 8];
  const int px0 = blockIdx.x * 16;
  const int t = threadIdx.x;
  for (int e = t; e < 16 * C / 4; e += 256) {
    int px = e / (C / 4);
    int c0 = (e % (C / 4)) * 4;
    float4 v  = *(const float4*)(h + (size_t)(px0 + px) * C + c0);
    float4 sc = *(const float4*)&stats[2 * C + c0];
    float4 sf = *(const float4*)&stats[3 * C + c0];
    float a0 = fmaf(v.x, sc.x, sf.x); a0 = fmaxf(a0, 0.1f * a0);
    float a1 = fmaf(v.y, sc.y, sf.y); a1 = fmaxf(a1, 0.1f * a1);
    float a2 = fmaf(v.z, sc.z, sf.z); a2 = fmaxf(a2, 0.1f * a2);
    float a3 = fmaf(v.w, sc.w, sf.w); a3 = fmaxf(a3, 0.1f * a3);
    ushort h0 = f2bf(a0), h1 = f2bf(a1), h2v = f2bf(a2), h3v = f2bf(a3);
    lh[px][c0]   = h0;  ll[px][c0]   = f2bf(a0 - bf2f(h0));
    lh[px][c0+1] = h1;  ll[px][c0+1] = f2bf(a1 - bf2f(h1));
    lh[px][c0+2] = h2v; ll[px][c0+2] = f2bf(a2 - bf2f(h2v));
    lh[px][c0+3] = h3v; ll[px][c0+3] = f2bf(a3 - bf2f(h3v));
  }
  __syncthreads();
  for (int e = t; e < 16 * (C / 8); e += 256) {
    int j = e >> 4, px = e & 15;
    *(uint4*)(oh + ((size_t)j * totpx + px0 + px) * 8) = *(const uint4*)&lh[px][j * 8];
    *(uint4*)(ol + ((size_t)j * totpx + px0 + px) * 8) = *(const uint4*)&ll[px][j * 8];
  }
}

// ------- h1: fused BN+LReLU + split + NCHW->NHWC transpose -------
__global__ __launch_bounds__(256) void bn_t_split_k(
    const float* __restrict__ h1, const float* __restrict__ stats,
    ushort* __restrict__ xh, ushort* __restrict__ xl)
{
  const int icb = blockIdx.x, y = blockIdx.y, b = blockIdx.z;
  __shared__ uint tl[128][33];
  const int t = threadIdx.x;
  for (int e = t; e < 4096; e += 256) {
    int ic = e >> 7, x = e & 127;
    int c = icb * 32 + ic;
    float v = h1[(((size_t)b * 128 + c) * 128 + y) * 128 + x];
    float a = fmaf(v, stats[256 + c], stats[384 + c]);
    a = fmaxf(a, 0.1f * a);
    ushort hi = f2bf(a);
    ushort lo = f2bf(a - bf2f(hi));
    tl[x][ic] = (uint)hi | ((uint)lo << 16);
  }
  __syncthreads();
  for (int e = t; e < 4096; e += 256) {
    int x = e >> 5, ic = e & 31;
    uint v = tl[x][ic];
    size_t o = (((size_t)b * 128 + y) * 128 + x) * 128 + icb * 32 + ic;
    xh[o] = (ushort)(v & 0xffffu);
    xl[o] = (ushort)(v >> 16);
  }
}

// ------- conv2 weights: [oc][ic][3][3] f32 -> [k][oc][ic] bf16 hi/lo -------
__global__ void wsplit_k(const float* __restrict__ w,
                         ushort* __restrict__ wh, ushort* __restrict__ wl)
{
  int i = blockIdx.x * 256 + threadIdx.x;
  if (i >= 256 * 128 * 9) return;
  int k = i % 9; int r = i / 9; int ic = r & 127; int oc = r >> 7;
  float v = w[i];
  ushort hi = f2bf(v);
  ushort lo = f2bf(v - bf2f(hi));
  size_t d = ((size_t)k * 256 + oc) * 128 + ic;
  wh[d] = hi; wl[d] = lo;
}

// ------- conv3/4/5 weights: [oc][ic][4][4] -> [ky][IC/8][oc][kx*8+ici] -------
__global__ void wsplit2_k(const float* __restrict__ w,
                          ushort* __restrict__ wh, ushort* __restrict__ wl,
                          int OC, int IC, int n)
{
  int i = blockIdx.x * 256 + threadIdx.x;
  if (i >= n) return;
  int kx = i & 3, ky = (i >> 2) & 3;
  int ic = (i >> 4) % IC, oc = (i >> 4) / IC;
  float v = w[i];
  ushort hi = f2bf(v);
  ushort lo = f2bf(v - bf2f(hi));
  size_t d = (((size_t)ky * (IC >> 3) + (ic >> 3)) * OC + oc) * 32 + kx * 8 + (ic & 7);
  wh[d] = hi; wl[d] = lo;
}

// ------- conv2 via MFMA (bf16x3), out: blocked bf16 hi/lo pre-BN -------
__global__ __launch_bounds__(256, 2) void conv2_mfma_k(
    const ushort* __restrict__ xh, const ushort* __restrict__ xl,
    const ushort* __restrict__ wph, const ushort* __restrict__ wpl,
    ushort* __restrict__ x3h, ushort* __restrict__ x3l)
{
  const int ocT = blockIdx.x;
  const int y0  = blockIdx.y * 2;
  const int b   = blockIdx.z;

  __shared__ ushort xs[2][2][132][32];
  __shared__ ushort wsm[2][2][128][32];

  const int t  = threadIdx.x;
  const int w  = t >> 6;
  const int l  = t & 63;
  const int rsel = w >> 1;
  const int xb   = (w & 1) * 64;
  const int lr = l & 15;
  const int kg = l >> 4;

  f32x4 acc[8][4];
#pragma unroll
  for (int i = 0; i < 8; ++i)
#pragma unroll
    for (int j = 0; j < 4; ++j) acc[i][j] = (f32x4){0.f, 0.f, 0.f, 0.f};

  for (int ky = 0; ky < 3; ++ky) {
    const int gy0 = y0 + ky - 1;
    for (int ic32 = 0; ic32 < 4; ++ic32) {
      __syncthreads();
      for (int e = t; e < 1040; e += 256) {
        int r   = e / 520;
        int q   = e - r * 520;
        int xi  = q >> 2;
        int icg = q & 3;
        int gy = gy0 + r, gx = xi - 1;
        uint4 vh = {0, 0, 0, 0}, vl = {0, 0, 0, 0};
        if ((unsigned)gy < 128u && (unsigned)gx < 128u) {
          size_t gi = (((size_t)b * 128 + gy) * 128 + gx) * 128 + ic32 * 32 + icg * 8;
          vh = *(const uint4*)(xh + gi);
          vl = *(const uint4*)(xl + gi);
        }
        *(uint4*)&xs[0][r][xi][icg * 8] = vh;
        *(uint4*)&xs[1][r][xi][icg * 8] = vl;
      }
      {
        const int kk = ky * 3;
        for (int e = t; e < 512; e += 256) {
          int oc = e >> 2, icg = e & 3;
          size_t gi = (((size_t)kk * 256 + ocT * 128 + oc) * 128) + ic32 * 32 + icg * 8;
          *(uint4*)&wsm[0][0][oc][icg * 8] = *(const uint4*)(wph + gi);
          *(uint4*)&wsm[0][1][oc][icg * 8] = *(const uint4*)(wpl + gi);
        }
      }
      __syncthreads();

      for (int kx = 0; kx < 3; ++kx) {
        if (kx) __syncthreads();
        if (kx < 2) {
          const int kk = ky * 3 + kx + 1;
          const int buf = (kx + 1) & 1;
          for (int e = t; e < 512; e += 256) {
            int oc = e >> 2, icg = e & 3;
            size_t gi = (((size_t)kk * 256 + ocT * 128 + oc) * 128) + ic32 * 32 + icg * 8;
            *(uint4*)&wsm[buf][0][oc][icg * 8] = *(const uint4*)(wph + gi);
            *(uint4*)&wsm[buf][1][oc][icg * 8] = *(const uint4*)(wpl + gi);
          }
        }
        const int buf = kx & 1;
        bf16x8 awh[8], awl[8], xbh[4], xbl[4];
#pragma unroll
        for (int of = 0; of < 8; ++of) {
          awh[of] = *(const bf16x8*)&wsm[buf][0][of * 16 + lr][kg * 8];
          awl[of] = *(const bf16x8*)&wsm[buf][1][of * 16 + lr][kg * 8];
        }
#pragma unroll
        for (int pf = 0; pf < 4; ++pf) {
          int xi = xb + pf * 16 + lr + kx;
          xbh[pf] = *(const bf16x8*)&xs[0][rsel][xi][kg * 8];
          xbl[pf] = *(const bf16x8*)&xs[1][rsel][xi][kg * 8];
        }
#pragma unroll
        for (int of = 0; of < 8; ++of) {
#pragma unroll
          for (int pf = 0; pf < 4; ++pf) {
            acc[of][pf] = __builtin_amdgcn_mfma_f32_16x16x32_bf16(awh[of], xbh[pf], acc[of][pf], 0, 0, 0);
            acc[of][pf] = __builtin_amdgcn_mfma_f32_16x16x32_bf16(awh[of], xbl[pf], acc[of][pf], 0, 0, 0);
            acc[of][pf] = __builtin_amdgcn_mfma_f32_16x16x32_bf16(awl[of], xbh[pf], acc[of][pf], 0, 0, 0);
          }
        }
      }
    }
  }

  // epilogue: write blocked bf16 hi/lo [oc/8][(b*128+y)*128+x][8]
  const int yy = y0 + rsel;
#pragma unroll
  for (int of = 0; of < 8; ++of) {
#pragma unroll
    for (int pf = 0; pf < 4; ++pf) {
      int oc = ocT * 128 + of * 16 + kg * 4;
      int x  = xb + pf * 16 + lr;
      size_t pxg = ((size_t)b * 128 + yy) * 128 + x;
      size_t base = ((size_t)(oc >> 3) * 131072 + pxg) * 8 + (oc & 7);
      f32x4 a = acc[of][pf];
      ushort h0 = f2bf(a[0]); ushort l0 = f2bf(a[0] - bf2f(h0));
      ushort h1 = f2bf(a[1]); ushort l1 = f2bf(a[1] - bf2f(h1));
      ushort h2 = f2bf(a[2]); ushort l2 = f2bf(a[2] - bf2f(h2));
      ushort h3 = f2bf(a[3]); ushort l3 = f2bf(a[3] - bf2f(h3));
      uint2 uh = {(uint)h0 | ((uint)h1 << 16), (uint)h2 | ((uint)h3 << 16)};
      uint2 ul = {(uint)l0 | ((uint)l1 << 16), (uint)l2 | ((uint)l3 << 16)};
      *(uint2*)(x3h + base) = uh;
      *(uint2*)(x3l + base) = ul;
    }
  }
}

// ------- conv3/4/5 via MFMA: 4x4 s2 p1, K=(4kx x 8ic) per MFMA -------
template<int IC, int OC, int OH, int OW, int WPX>
__global__ __launch_bounds__(256, 2) void convs_mfma_k(
    const ushort* __restrict__ xh, const ushort* __restrict__ xl,  // [IC/8][8*IH*IW][8]
    const ushort* __restrict__ wh, const ushort* __restrict__ wl,  // [4][IC/8][OC][32]
    float* __restrict__ y)                                          // [8][OH][OW][OC]
{
  constexpr int IH  = 2 * OH, IW = 2 * OW;
  constexpr int NCH = IC / 8;
  constexpr int PFX = OW / 16;
  constexpr int RW  = 4 / WPX;

  const int y0 = blockIdx.x * 4;
  const int b  = blockIdx.y;

  __shared__ ushort xs[2][4][2][OW + 2][8];
  __shared__ ushort wsm[2][OC][32];

  const int t = threadIdx.x;
  const int w = t >> 6, l = t & 63;
  const int wo = w / WPX, wp = w % WPX;
  const int lr = l & 15, kg = l >> 4;
  const int oc0w = wo * 64;
  const int rb = wp * RW;

  f32x4 acc[4][4];
#pragma unroll
  for (int i = 0; i < 4; ++i)
#pragma unroll
    for (int j = 0; j < 4; ++j) acc[i][j] = (f32x4){0.f, 0.f, 0.f, 0.f};

  for (int ky = 0; ky < 4; ++ky) {
    for (int ch = 0; ch < NCH; ++ch) {
      __syncthreads();
      // stage X: 4 rows x (IW+2) x' positions, parity-split, hi+lo
      for (int e = t; e < 4 * (IW + 2); e += 256) {
        int r  = e / (IW + 2);
        int xi = e % (IW + 2);
        int xp = xi - 1;
        int iy = 2 * (y0 + r) + ky - 1;
        uint4 vh = {0, 0, 0, 0}, vl = {0, 0, 0, 0};
        if ((unsigned)iy < (unsigned)IH && (unsigned)xp < (unsigned)IW) {
          size_t gi = ((((size_t)ch * 8 + b) * IH + iy) * IW + xp) * 8;
          vh = *(const uint4*)(xh + gi);
          vl = *(const uint4*)(xl + gi);
        }
        int par = xp & 1;
        int idx = (xp + 1) >> 1;
        *(uint4*)&xs[0][r][par][idx][0] = vh;
        *(uint4*)&xs[1][r][par][idx][0] = vl;
      }
      // stage W: [OC][32] hi+lo
      for (int e = t; e < OC * 4; e += 256) {
        size_t gi = (((size_t)ky * NCH + ch) * OC) * 32 + (size_t)e * 8;
        *(uint4*)((ushort*)wsm[0] + e * 8) = *(const uint4*)(wh + gi);
        *(uint4*)((ushort*)wsm[1] + e * 8) = *(const uint4*)(wl + gi);
      }
      __syncthreads();

      bf16x8 ah[4], al[4], bh[4], bl[4];
#pragma unroll
      for (int of = 0; of < 4; ++of) {
        ah[of] = *(const bf16x8*)&wsm[0][oc0w + of * 16 + lr][kg * 8];
        al[of] = *(const bf16x8*)&wsm[1][oc0w + of * 16 + lr][kg * 8];
      }
      const int par = 1 - (kg & 1);
      const int xoff = kg >> 1;
#pragma unroll
      for (int pf = 0; pf < 4; ++pf) {
        int row = rb + pf / PFX;
        int x   = (pf % PFX) * 16 + lr;
        bh[pf] = *(const bf16x8*)&xs[0][row][par][x + xoff][0];
        bl[pf] = *(const bf16x8*)&xs[1][row][par][x + xoff][0];
      }
#pragma unroll
      for (int of = 0; of < 4; ++of) {
#pragma unroll
        for (int pf = 0; pf < 4; ++pf) {
          acc[of][pf] = __builtin_amdgcn_mfma_f32_16x16x32_bf16(ah[of], bh[pf], acc[of][pf], 0, 0, 0);
          acc[of][pf] = __builtin_amdgcn_mfma_f32_16x16x32_bf16(ah[of], bl[pf], acc[of][pf], 0, 0, 0);
          acc[of][pf] = __builtin_amdgcn_mfma_f32_16x16x32_bf16(al[of], bh[pf], acc[of][pf], 0, 0, 0);
        }
      }
    }
  }

  // epilogue: NHWC fp32
#pragma unroll
  for (int of = 0; of < 4; ++of) {
#pragma unroll
    for (int pf = 0; pf < 4; ++pf) {
      int row = rb + pf / PFX;
      int x   = (pf % PFX) * 16 + lr;
      int oc  = oc0w + of * 16 + kg * 4;
      float* p = y + (((size_t)b * OH + y0 + row) * OW + x) * OC + oc;
      f32x4 a = acc[of][pf];
      float4 v = {a[0], a[1], a[2], a[3]};
      *(float4*)p = v;
    }
  }
}

// ---------------- capsule rearrange (h5 NHWC + BN inline) ----------------
__global__ void caps_k(const float* __restrict__ h5, const float* __restrict__ stats,
                       float* __restrict__ caps)
{
  int e = blockIdx.x * 256 + threadIdx.x;
  if (e >= NB * NCAP * 8) return;
  int ii = e & 7;
  int n  = (e >> 3) & 511;
  int jb = e >> 12;
  int j = jb >> 3, b = jb & 7;
  int i = n >> 7, k = (n >> 5) & 3, ch = ((n & 31) << 3) | ii;
  int hh = (i << 2) | (j >> 2);
  int ww = ((j & 3) << 2) | k;
  float v = h5[(((size_t)b * 16 + hh) * 16 + ww) * 256 + ch];
  float a = fmaf(v, stats[512 + ch], stats[768 + ch]);
  a = fmaxf(a, 0.1f * a);
  caps[e] = a;
}

// ---------------- priors ----------------
__global__ __launch_bounds__(256) void priors_k(
    const float* __restrict__ caps, const float* __restrict__ rw,
    float* __restrict__ priors)
{
  const int n = blockIdx.x;
  __shared__ float lrw[NCLS * 8 * NO];
  __shared__ float lc[NB * 8];
  const int t = threadIdx.x;
  for (int e = t; e < NCLS * 8 * NO; e += 256)
    lrw[e] = rw[(size_t)n * NCLS * 8 * NO + e];
  for (int e = t; e < NB * 8; e += 256) {
    int b = e >> 3, ii = e & 7;
    lc[e] = caps[((size_t)b * NCAP + n) * 8 + ii];
  }
  __syncthreads();

  int p[4], kk[4], oo[4];
#pragma unroll
  for (int q = 0; q < 4; ++q) {
    p[q]  = t + q * 256;
    kk[q] = (p[q] < KO) ? p[q] / NO : 0;
    oo[q] = (p[q] < KO) ? p[q] % NO : 0;
  }
  for (int b = 0; b < NB; ++b) {
    const float* cb = &lc[b * 8];
    float c0 = cb[0], c1 = cb[1], c2 = cb[2], c3 = cb[3];
    float c4 = cb[4], c5 = cb[5], c6 = cb[6], c7 = cb[7];
    float* pout = priors + ((size_t)b * NCAP + n) * KO;
#pragma unroll
    for (int q = 0; q < 4; ++q) {
      if (p[q] < KO) {
        const float* wv = &lrw[kk[q] * (8 * NO) + oo[q]];
        float a = c0 * wv[0];
        a = fmaf(c1, wv[21],  a);
        a = fmaf(c2, wv[42],  a);
        a = fmaf(c3, wv[63],  a);
        a = fmaf(c4, wv[84],  a);
        a = fmaf(c5, wv[105], a);
        a = fmaf(c6, wv[126], a);
        a = fmaf(c7, wv[147], a);
        pout[p[q]] = a;
      }
    }
  }
}

// ---------------- routing ----------------
__global__ __launch_bounds__(256) void route_s_partial(
    const float* __restrict__ priors, const float* __restrict__ probs,
    float* __restrict__ s, int uniform)
{
  const int b  = blockIdx.x >> 3;
  const int ns = blockIdx.x & 7;
  const int t  = threadIdx.x;
  const int p0 = t, p1 = t + 256, p2 = t + 512, p3 = t + 768;
  const int k0 = p0 / NO, k1 = p1 / NO, k2 = p2 / NO;
  const int k3 = (p3 < KO) ? p3 / NO : 0;
  float a0 = 0.f, a1 = 0.f, a2 = 0.f, a3 = 0.f;
  const float* pb  = priors + ((size_t)b * NCAP + ns * 64) * KO;
  const float* prb = probs + ((size_t)b * NCAP + ns * 64) * NCLS;
#pragma unroll 2
  for (int n = 0; n < 64; ++n) {
    const float* pn = pb + (size_t)n * KO;
    if (uniform) {
      a0 += pn[p0]; a1 += pn[p1]; a2 += pn[p2];
      if (p3 < KO) a3 += pn[p3];
    } else {
      const float* pr = prb + n * NCLS;
      a0 = fmaf(pr[k0], pn[p0], a0);
      a1 = fmaf(pr[k1], pn[p1], a1);
      a2 = fmaf(pr[k2], pn[p2], a2);
      if (p3 < KO) a3 = fmaf(pr[k3], pn[p3], a3);
    }
  }
  const float sc = uniform ? (1.f / 43.f) : 1.f;
  atomicAdd(&s[b * KO + p0], a0 * sc);
  atomicAdd(&s[b * KO + p1], a1 * sc);
  atomicAdd(&s[b * KO + p2], a2 * sc);
  if (p3 < KO) atomicAdd(&s[b * KO + p3], a3 * sc);
}

__global__ void squash_k(const float* __restrict__ s, float* __restrict__ souts)
{
  int i = blockIdx.x * 256 + threadIdx.x;
  if (i >= NB * NCLS) return;
  int b = i / NCLS, k = i % NCLS;
  const float* sv = s + b * KO + k * NO;
  float sn = 0.f;
#pragma unroll
  for (int o = 0; o < NO; ++o) sn += sv[o] * sv[o];
  float f = sqrtf(sn) / (1.f + sn);
  float* ov = souts + b * KO + k * NO;
#pragma unroll
  for (int o = 0; o < NO; ++o) ov[o] = sv[o] * f;
}

__global__ __launch_bounds__(256) void logits_k(
    const float* __restrict__ priors, const float* __restrict__ souts,
    float* __restrict__ logits, int accum)
{
  int i = blockIdx.x * 256 + threadIdx.x;
  if (i >= NB * NCAP * NCLS) return;
  int k  = i % NCLS;
  int bn = i / NCLS;
  int b  = bn >> 9;
  const float* pv = priors + (size_t)bn * KO + k * NO;
  const float* ov = souts + b * KO + k * NO;
  float d = 0.f;
#pragma unroll
  for (int o = 0; o < NO; ++o) d = fmaf(pv[o], ov[o], d);
  logits[i] = (accum ? logits[i] : 0.f) + d;
}

__global__ __launch_bounds__(256) void probs_k(
    const float* __restrict__ logits, float* __restrict__ probs)
{
  int bn = blockIdx.x * 256 + threadIdx.x;
  if (bn >= NB * NCAP) return;
  const float* lg = logits + (size_t)bn * NCLS;
  float e[NCLS];
  float mx = -1e30f;
#pragma unroll
  for (int k = 0; k < NCLS; ++k) { e[k] = lg[k]; mx = fmaxf(mx, e[k]); }
  float sm = 0.f;
#pragma unroll
  for (int k = 0; k < NCLS; ++k) { e[k] = expf(e[k] - mx); sm += e[k]; }
  float inv = 1.f / sm;
  float* pb = probs + (size_t)bn * NCLS;
#pragma unroll
  for (int k = 0; k < NCLS; ++k) pb[k] = e[k] * inv;
}

__global__ void out_k(const float* __restrict__ souts, float* __restrict__ out)
{
  int i = blockIdx.x * 256 + threadIdx.x;
  if (i >= 8 * 16 * NCLS * NO) return;
  int o = i % NO;
  int r = i / NO;
  int k = r % NCLS; r /= NCLS;
  int g1 = r & 3; r >>= 2;
  int g0 = r & 3;
  int b  = r >> 2;
  int j  = g0 * 4 + g1;
  int jb = j * 8 + b;
  out[i] = souts[jb * KO + k * NO + o];
}

// ---------------- launcher ----------------
extern "C" void kernel_launch(void* const* d_in, const int* in_sizes, int n_in,
                              void* d_out, int out_size, void* d_ws, size_t ws_size,
                              hipStream_t stream)
{
  const float* x   = (const float*)d_in[0];
  const float* c1w = (const float*)d_in[1];
  const float* g1  = (const float*)d_in[3];  const float* b1  = (const float*)d_in[4];
  const float* c2w = (const float*)d_in[5];
  const float* g2  = (const float*)d_in[7];  const float* b2  = (const float*)d_in[8];
  const float* c3w = (const float*)d_in[9];
  const float* g3  = (const float*)d_in[11]; const float* b3  = (const float*)d_in[12];
  const float* c4w = (const float*)d_in[13];
  const float* g4  = (const float*)d_in[15]; const float* b4  = (const float*)d_in[16];
  const float* c5w = (const float*)d_in[17];
  const float* g5  = (const float*)d_in[19]; const float* b5  = (const float*)d_in[20];
  const float* rw  = (const float*)d_in[21];

  float* ws  = (float*)d_ws;
  float* out = (float*)d_out;

  ushort* xth = (ushort*)(ws + F_XTH);
  ushort* xtl = (ushort*)(ws + F_XTL);
  ushort* wph = (ushort*)(ws + F_WPH);
  ushort* wpl = (ushort*)(ws + F_WPL);
  ushort* w3h = (ushort*)(ws + F_W3H);
  ushort* w3l = (ushort*)(ws + F_W3L);
  ushort* w4h = (ushort*)(ws + F_W4H);
  ushort* w4l = (ushort*)(ws + F_W4L);
  ushort* w5h = (ushort*)(ws + F_W5H);
  ushort* w5l = (ushort*)(ws + F_W5L);
  ushort* x3h = (ushort*)(ws + F_X3H);
  ushort* x3l = (ushort*)(ws + F_X3L);
  ushort* x4h = (ushort*)(ws + F_X4H);
  ushort* x4l = (ushort*)(ws + F_X4L);
  ushort* x5h = (ushort*)(ws + F_X5H);
  ushort* x5l = (ushort*)(ws + F_X5L);
  float* h1     = ws + F_H1;
  float* h3     = ws + F_H3;
  float* h4     = ws + F_H4;
  float* h5     = ws + F_H5;
  float* caps   = ws + F_CAPS;
  float* priors = ws + F_PRI;
  float* logits = ws + F_LOG;
  float* probs  = ws + F_PRB;
  float* sbuf   = ws + F_S;
  float* souts  = ws + F_OUTS;
  float* stats  = ws + F_STAT;

  // ---- weight preps ----
  wsplit_k<<<(256 * 128 * 9 + 255) / 256, 256, 0, stream>>>(c2w, wph, wpl);
  wsplit2_k<<<(64 * 256 * 16 + 255) / 256, 256, 0, stream>>>(c3w, w3h, w3l, 64, 256, 64 * 256 * 16);
  wsplit2_k<<<(128 * 64 * 16 + 255) / 256, 256, 0, stream>>>(c4w, w4h, w4l, 128, 64, 128 * 64 * 16);
  wsplit2_k<<<(256 * 128 * 16 + 255) / 256, 256, 0, stream>>>(c5w, w5h, w5l, 256, 128, 256 * 128 * 16);

  // ---- conv1 (fp32 direct) + BN + split/transpose ----
  conv_k<3, 1, 3, 10, 18><<<dim3(8, 16, 8 * 4), 256, 0, stream>>>(
      x, c1w, h1, 3, 128, 128, 128, 128, 128);
  hipMemsetAsync(stats, 0, 2 * 128 * sizeof(float), stream);
  bn_stats_k<<<128 * 16, 256, 0, stream>>>(h1, stats, 128, 14, 16, 131072);
  bn_fin_k<<<1, 256, 0, stream>>>(stats, g1, b1, 128, 1.f / 131072.f);
  bn_t_split_k<<<dim3(4, 128, 8), 256, 0, stream>>>(h1, stats, xth, xtl);

  // ---- conv2 (MFMA) -> blocked bf16 pre-BN; BN in-place ----
  conv2_mfma_k<<<dim3(2, 64, 8), 256, 0, stream>>>(xth, xtl, wph, wpl, x3h, x3l);
  hipMemsetAsync(stats, 0, 2 * 256 * sizeof(float), stream);
  bn_stats_blocked_k<<<32 * 4, 256, 0, stream>>>(x3h, x3l, stats, 32, 131072, 4);
  bn_fin_k<<<1, 256, 0, stream>>>(stats, g2, b2, 256, 1.f / 131072.f);
  bn_apply_blocked_k<<<2048, 256, 0, stream>>>(x3h, x3l, stats, 256, 17, (size_t)32 * 131072);

  // ---- conv3 (MFMA) ----
  convs_mfma_k<256, 64, 64, 64, 4><<<dim3(16, 8), 256, 0, stream>>>(x3h, x3l, w3h, w3l, h3);
  hipMemsetAsync(stats, 0, 2 * 64 * sizeof(float), stream);
  bn_stats_nhwc_k<<<64, 256, 0, stream>>>(h3, stats, 63, 6, 32768);
  bn_fin_k<<<1, 256, 0, stream>>>(stats, g3, b3, 64, 1.f / 32768.f);
  split_blocked_k<64><<<2048, 256, 0, stream>>>(h3, stats, x4h, x4l, 32768);

  // ---- conv4 (MFMA) ----
  convs_mfma_k<64, 128, 32, 32, 2><<<dim3(8, 8), 256, 0, stream>>>(x4h, x4l, w4h, w4l, h4);
  hipMemsetAsync(stats, 0, 2 * 128 * sizeof(float), stream);
  bn_stats_nhwc_k<<<32, 256, 0, stream>>>(h4, stats, 127, 7, 8192);
  bn_fin_k<<<1, 256, 0, stream>>>(stats, g4, b4, 128, 1.f / 8192.f);
  split_blocked_k<128><<<512, 256, 0, stream>>>(h4, stats, x5h, x5l, 8192);

  // ---- conv5 (MFMA) ----
  convs_mfma_k<128, 256, 16, 16, 1><<<dim3(4, 8), 256, 0, stream>>>(x5h, x5l, w5h, w5l, h5);
  hipMemsetAsync(stats, 0, 2 * 256 * sizeof(float), stream);
  bn_stats_nhwc_k<<<8, 256, 0, stream>>>(h5, stats, 255, 8, 2048);
  bn_fin_k<<<1, 256, 0, stream>>>(stats, g5, b5, 256, 1.f / 2048.f);

  // ---- capsules ----
  caps_k<<<2048, 256, 0, stream>>>(h5, stats, caps);
  priors_k<<<512, 256, 0, stream>>>(caps, rw, priors);

  // ---- routing: 3 iterations ----
  hipMemsetAsync(sbuf, 0, NB * KO * sizeof(float), stream);
  route_s_partial<<<NB * 8, 256, 0, stream>>>(priors, probs, sbuf, 1);
  squash_k<<<(NB * NCLS + 255) / 256, 256, 0, stream>>>(sbuf, souts);
  logits_k<<<(NB * NCAP * NCLS + 255) / 256, 256, 0, stream>>>(priors, souts, logits, 0);
  probs_k<<<(NB * NCAP + 255) / 256, 256, 0, stream>>>(logits, probs);
  hipMemsetAsync(sbuf, 0, NB * KO * sizeof(float), stream);
  route_s_partial<<<NB * 8, 256, 0, stream>>>(priors, probs, sbuf, 0);
  squash_k<<<(NB * NCLS + 255) / 256, 256, 0, stream>>>(sbuf, souts);
  logits_k<<<(NB * NCAP * NCLS + 255) / 256, 256, 0, stream>>>(priors, souts, logits, 1);
  probs_k<<<(NB * NCAP + 255) / 256, 256, 0, stream>>>(logits, probs);
  hipMemsetAsync(sbuf, 0, NB * KO * sizeof(float), stream);
  route_s_partial<<<NB * 8, 256, 0, stream>>>(priors, probs, sbuf, 0);
  squash_k<<<(NB * NCLS + 255) / 256, 256, 0, stream>>>(sbuf, souts);

  // ---- final scatter ----
  out_k<<<(8 * 16 * NCLS * NO + 255) / 256, 256, 0, stream>>>(souts, out);
}

// Round 4
// 979.846 us; speedup vs baseline: 2.7826x; 1.3234x over previous
//
#include <hip/hip_runtime.h>
#include <math.h>

typedef unsigned int   uint;
typedef unsigned short ushort;
using bf16x8 = __attribute__((ext_vector_type(8))) __bf16;
using f32x4  = __attribute__((ext_vector_type(4))) float;

constexpr int NB   = 128;
constexpr int NCAP = 512;
constexpr int NCLS = 43;
constexpr int NO   = 21;
constexpr int KO   = NCLS * NO; // 903

// ---- workspace layout (float offsets) ----
constexpr size_t F_XTH  = 0;          // h1 split hi; later reused for conv partials
constexpr size_t F_XTL  = 8388608;
constexpr size_t F_PART = 0;          // conv3/4/5 K-split partials (<= 8.4M floats)
constexpr size_t F_STAT = 16777216;   // 1,024
constexpr size_t F_WPH  = 16778240;   // conv2 w hi (147,456)
constexpr size_t F_WPL  = 16925696;
constexpr size_t F_W3H  = 17073152;
constexpr size_t F_W3L  = 17204224;
constexpr size_t F_W4H  = 17335296;
constexpr size_t F_W4L  = 17400832;
constexpr size_t F_W5H  = 17466368;
constexpr size_t F_W5L  = 17728512;
constexpr size_t F_H1   = 17990656;   // h1 raw fp32 NCHW — dead before X3H written
constexpr size_t F_X3H  = 17990656;   // conv2 out hi, blocked [32][131072][8] bf16
constexpr size_t F_X3L  = 34767872;   // ends 51,545,088
constexpr size_t F_H3   = 51545088;   // h3 NHWC fp32 (2,097,152)
constexpr size_t F_X4H  = 53642240;
constexpr size_t F_X4L  = 54690816;
constexpr size_t F_H4   = 55739392;
constexpr size_t F_X5H  = 56787968;
constexpr size_t F_X5L  = 57312256;
constexpr size_t F_H5   = 57836544;   // (524,288)
// routing phase:
constexpr size_t F_PRI  = 0;          // 59,179,008
constexpr size_t F_CAPS = 59179008;   // 524,288
constexpr size_t F_LOG  = 59703296;   // 2,818,048
constexpr size_t F_S    = 65339392;   // 115,584
constexpr size_t F_OUTS = 65454976;   // 115,584

__device__ inline ushort f2bf(float x) {
  uint u = __float_as_uint(x);
  uint r = (u + 0x7fffu + ((u >> 16) & 1u)) >> 16;  // RNE
  return (ushort)r;
}
__device__ inline float bf2f(ushort h) { return __uint_as_float(((uint)h) << 16); }

// ---------------- conv1: fp32 direct (3->128, 3x3, s1, p1) -----------------
template<int KS, int STRIDE, int ICC, int IHT, int IWT>
__global__ __launch_bounds__(256) void conv_k(
    const float* __restrict__ in, const float* __restrict__ w,
    float* __restrict__ out, int IC, int OC, int IH, int IW, int OH, int OW)
{
  constexpr int BOC = 32;
  const int noc = OC >> 5;
  const int bz  = blockIdx.z;
  const int ocb = bz % noc;
  const int b   = bz / noc;
  const int tx0 = blockIdx.x * 16;
  const int ty0 = blockIdx.y * 8;
  const int oc0 = ocb * BOC;

  __shared__ float lin[ICC][IHT][IWT];
  __shared__ float lw[ICC][KS * KS][BOC];

  const int t  = threadIdx.x;
  const int pq = t & 3;
  const int ty = (t >> 2) & 7;
  const int oq = t >> 5;

  float acc[4][4];
#pragma unroll
  for (int m = 0; m < 4; ++m)
#pragma unroll
    for (int j = 0; j < 4; ++j) acc[m][j] = 0.f;

  const int gx0 = tx0 * STRIDE - 1;
  const int gy0 = ty0 * STRIDE - 1;
  const int nch = IC / ICC;

  for (int ch = 0; ch < nch; ++ch) {
    const int ic0 = ch * ICC;
    __syncthreads();
    for (int e = t; e < ICC * IHT * IWT; e += 256) {
      int ic = e / (IHT * IWT);
      int rr = e % (IHT * IWT);
      int ey = rr / IWT, ex = rr % IWT;
      int gy = gy0 + ey, gx = gx0 + ex;
      float v = 0.f;
      if ((unsigned)gy < (unsigned)IH && (unsigned)gx < (unsigned)IW)
        v = in[((size_t)(b * IC + ic0 + ic) * IH + gy) * IW + gx];
      lin[ic][ey][ex] = v;
    }
    for (int e = t; e < ICC * KS * KS * BOC; e += 256) {
      int ocl = e & (BOC - 1);
      int rr  = e >> 5;
      int kk  = rr % (KS * KS);
      int ic  = rr / (KS * KS);
      lw[ic][kk][ocl] = w[((size_t)(oc0 + ocl) * IC + ic0 + ic) * (KS * KS) + kk];
    }
    __syncthreads();

    for (int ic = 0; ic < ICC; ++ic) {
#pragma unroll
      for (int ky = 0; ky < KS; ++ky) {
#pragma unroll
        for (int kx = 0; kx < KS; ++kx) {
          float xv[4];
#pragma unroll
          for (int j = 0; j < 4; ++j)
            xv[j] = lin[ic][ty * STRIDE + ky][(pq * 4 + j) * STRIDE + kx];
          const float4 w4 = *(const float4*)&lw[ic][ky * KS + kx][oq * 4];
#pragma unroll
          for (int j = 0; j < 4; ++j) {
            acc[0][j] = fmaf(w4.x, xv[j], acc[0][j]);
            acc[1][j] = fmaf(w4.y, xv[j], acc[1][j]);
            acc[2][j] = fmaf(w4.z, xv[j], acc[2][j]);
            acc[3][j] = fmaf(w4.w, xv[j], acc[3][j]);
          }
        }
      }
    }
  }

  const int oy = ty0 + ty;
#pragma unroll
  for (int m = 0; m < 4; ++m) {
    int oc = oc0 + oq * 4 + m;
    float* op = out + ((size_t)(b * OC + oc) * OH + oy) * OW + tx0 + pq * 4;
#pragma unroll
    for (int j = 0; j < 4; ++j) op[j] = acc[m][j];
  }
}

// ---------------- BN stats ----------------
__global__ __launch_bounds__(256) void bn_stats_k(
    const float* __restrict__ x, float* __restrict__ stats,
    int C, int sh, int split, int nelem)
{
  const int c = blockIdx.x / split;
  const int s = blockIdx.x % split;
  const int HW = 1 << sh;
  float sum = 0.f, sq = 0.f;
  for (int i = s * 256 + threadIdx.x; i < nelem; i += split * 256) {
    int b = i >> sh, r = i & (HW - 1);
    float v = x[((size_t)(b * C + c) << sh) + r];
    sum += v; sq += v * v;
  }
#pragma unroll
  for (int off = 32; off > 0; off >>= 1) {
    sum += __shfl_down(sum, off);
    sq  += __shfl_down(sq, off);
  }
  __shared__ float ls[4], lq[4];
  int wid = threadIdx.x >> 6, lane = threadIdx.x & 63;
  if (lane == 0) { ls[wid] = sum; lq[wid] = sq; }
  __syncthreads();
  if (threadIdx.x == 0) {
    atomicAdd(&stats[c], ls[0] + ls[1] + ls[2] + ls[3]);
    atomicAdd(&stats[C + c], lq[0] + lq[1] + lq[2] + lq[3]);
  }
}

__global__ __launch_bounds__(256) void bn_stats_nhwc_k(
    const float* __restrict__ x, float* __restrict__ stats,
    int cmask, int lg2c, int totpx)
{
  int g = blockIdx.x * 256 + threadIdx.x;
  int c = g & cmask;
  int p0 = g >> lg2c;
  int stride = (gridDim.x * 256) >> lg2c;
  float s = 0.f, q = 0.f;
  for (int p = p0; p < totpx; p += stride) {
    float v = x[((size_t)p << lg2c) | c];
    s += v; q += v * v;
  }
  atomicAdd(&stats[c], s);
  atomicAdd(&stats[cmask + 1 + c], q);
}

__global__ __launch_bounds__(256) void bn_stats_blocked_k(
    const ushort* __restrict__ xh, const ushort* __restrict__ xl,
    float* __restrict__ stats, int nj, int totpx, int slices)
{
  const int j  = blockIdx.x % nj;
  const int sl = blockIdx.x / nj;
  float s[8] = {0,0,0,0,0,0,0,0}, q[8] = {0,0,0,0,0,0,0,0};
  const ushort* ph = xh + (size_t)j * totpx * 8;
  const ushort* pl = xl + (size_t)j * totpx * 8;
  for (int p = sl * 256 + threadIdx.x; p < totpx; p += slices * 256) {
    uint4 vh = *(const uint4*)(ph + (size_t)p * 8);
    uint4 vl = *(const uint4*)(pl + (size_t)p * 8);
    uint hw[4] = {vh.x, vh.y, vh.z, vh.w};
    uint lw[4] = {vl.x, vl.y, vl.z, vl.w};
#pragma unroll
    for (int m = 0; m < 4; ++m) {
      float v0 = __uint_as_float(hw[m] << 16) + __uint_as_float(lw[m] << 16);
      float v1 = __uint_as_float(hw[m] & 0xffff0000u) + __uint_as_float(lw[m] & 0xffff0000u);
      s[2*m] += v0; q[2*m] += v0 * v0;
      s[2*m+1] += v1; q[2*m+1] += v1 * v1;
    }
  }
#pragma unroll
  for (int off = 32; off > 0; off >>= 1)
#pragma unroll
    for (int k = 0; k < 8; ++k) {
      s[k] += __shfl_down(s[k], off);
      q[k] += __shfl_down(q[k], off);
    }
  __shared__ float red[4][16];
  int wid = threadIdx.x >> 6, lane = threadIdx.x & 63;
  if (lane == 0) {
#pragma unroll
    for (int k = 0; k < 8; ++k) { red[wid][k] = s[k]; red[wid][8 + k] = q[k]; }
  }
  __syncthreads();
  if (threadIdx.x < 16) {
    float a = red[0][threadIdx.x] + red[1][threadIdx.x] + red[2][threadIdx.x] + red[3][threadIdx.x];
    int C = nj * 8;
    int c = j * 8 + (threadIdx.x & 7);
    atomicAdd(&stats[(threadIdx.x >> 3) * C + c], a);
  }
}

__global__ void bn_fin_k(float* __restrict__ stats, const float* __restrict__ g,
                         const float* __restrict__ bt, int C, float inv_n)
{
  int c = threadIdx.x;
  if (c < C) {
    float m  = stats[c] * inv_n;
    float v  = stats[C + c] * inv_n - m * m;
    float rs = rsqrtf(v + 1e-5f);
    float sc = g[c] * rs;
    stats[2 * C + c] = sc;
    stats[3 * C + c] = bt[c] - m * sc;
  }
}

__global__ __launch_bounds__(256) void bn_apply_blocked_k(
    ushort* __restrict__ xh, ushort* __restrict__ xl,
    const float* __restrict__ stats, int C, int lg2tot, size_t total)
{
  size_t stride = (size_t)gridDim.x * 256;
  for (size_t i = (size_t)blockIdx.x * 256 + threadIdx.x; i < total; i += stride) {
    int j = (int)(i >> lg2tot);
    uint4 vh = *(const uint4*)(xh + i * 8);
    uint4 vl = *(const uint4*)(xl + i * 8);
    int c0 = j * 8;
    float4 sc0 = *(const float4*)&stats[2 * C + c0];
    float4 sc1 = *(const float4*)&stats[2 * C + c0 + 4];
    float4 sf0 = *(const float4*)&stats[3 * C + c0];
    float4 sf1 = *(const float4*)&stats[3 * C + c0 + 4];
    float scv[8] = {sc0.x, sc0.y, sc0.z, sc0.w, sc1.x, sc1.y, sc1.z, sc1.w};
    float sfv[8] = {sf0.x, sf0.y, sf0.z, sf0.w, sf1.x, sf1.y, sf1.z, sf1.w};
    uint hw[4] = {vh.x, vh.y, vh.z, vh.w};
    uint lw[4] = {vl.x, vl.y, vl.z, vl.w};
    uint oh[4], ol[4];
#pragma unroll
    for (int m = 0; m < 4; ++m) {
      float v0 = __uint_as_float(hw[m] << 16) + __uint_as_float(lw[m] << 16);
      float v1 = __uint_as_float(hw[m] & 0xffff0000u) + __uint_as_float(lw[m] & 0xffff0000u);
      float a0 = fmaf(v0, scv[2*m], sfv[2*m]);     a0 = fmaxf(a0, 0.1f * a0);
      float a1 = fmaf(v1, scv[2*m+1], sfv[2*m+1]); a1 = fmaxf(a1, 0.1f * a1);
      ushort h0 = f2bf(a0); ushort l0 = f2bf(a0 - bf2f(h0));
      ushort h1 = f2bf(a1); ushort l1 = f2bf(a1 - bf2f(h1));
      oh[m] = (uint)h0 | ((uint)h1 << 16);
      ol[m] = (uint)l0 | ((uint)l1 << 16);
    }
    uint4 rh = {oh[0], oh[1], oh[2], oh[3]};
    uint4 rl = {ol[0], ol[1], ol[2], ol[3]};
    *(uint4*)(xh + i * 8) = rh;
    *(uint4*)(xl + i * 8) = rl;
  }
}

template<int C>
__global__ __launch_bounds__(256) void split_blocked_k(
    const float* __restrict__ h, const float* __restrict__ stats,
    ushort* __restrict__ oh, ushort* __restrict__ ol, int totpx)
{
  __shared__ ushort lh[16][C + 8], ll[16][C + 8];
  const int px0 = blockIdx.x * 16;
  const int t = threadIdx.x;
  for (int e = t; e < 16 * C / 4; e += 256) {
    int px = e / (C / 4);
    int c0 = (e % (C / 4)) * 4;
    float4 v  = *(const float4*)(h + (size_t)(px0 + px) * C + c0);
    float4 sc = *(const float4*)&stats[2 * C + c0];
    float4 sf = *(const float4*)&stats[3 * C + c0];
    float a0 = fmaf(v.x, sc.x, sf.x); a0 = fmaxf(a0, 0.1f * a0);
    float a1 = fmaf(v.y, sc.y, sf.y); a1 = fmaxf(a1, 0.1f * a1);
    float a2 = fmaf(v.z, sc.z, sf.z); a2 = fmaxf(a2, 0.1f * a2);
    float a3 = fmaf(v.w, sc.w, sf.w); a3 = fmaxf(a3, 0.1f * a3);
    ushort h0 = f2bf(a0), h1 = f2bf(a1), h2v = f2bf(a2), h3v = f2bf(a3);
    lh[px][c0]   = h0;  ll[px][c0]   = f2bf(a0 - bf2f(h0));
    lh[px][c0+1] = h1;  ll[px][c0+1] = f2bf(a1 - bf2f(h1));
    lh[px][c0+2] = h2v; ll[px][c0+2] = f2bf(a2 - bf2f(h2v));
    lh[px][c0+3] = h3v; ll[px][c0+3] = f2bf(a3 - bf2f(h3v));
  }
  __syncthreads();
  for (int e = t; e < 16 * (C / 8); e += 256) {
    int j = e >> 4, px = e & 15;
    *(uint4*)(oh + ((size_t)j * totpx + px0 + px) * 8) = *(const uint4*)&lh[px][j * 8];
    *(uint4*)(ol + ((size_t)j * totpx + px0 + px) * 8) = *(const uint4*)&ll[px][j * 8];
  }
}

__global__ __launch_bounds__(256) void bn_t_split_k(
    const float* __restrict__ h1, const float* __restrict__ stats,
    ushort* __restrict__ xh, ushort* __restrict__ xl)
{
  const int icb = blockIdx.x, y = blockIdx.y, b = blockIdx.z;
  __shared__ uint tl[128][33];
  const int t = threadIdx.x;
  for (int e = t; e < 4096; e += 256) {
    int ic = e >> 7, x = e & 127;
    int c = icb * 32 + ic;
    float v = h1[(((size_t)b * 128 + c) * 128 + y) * 128 + x];
    float a = fmaf(v, stats[256 + c], stats[384 + c]);
    a = fmaxf(a, 0.1f * a);
    ushort hi = f2bf(a);
    ushort lo = f2bf(a - bf2f(hi));
    tl[x][ic] = (uint)hi | ((uint)lo << 16);
  }
  __syncthreads();
  for (int e = t; e < 4096; e += 256) {
    int x = e >> 5, ic = e & 31;
    uint v = tl[x][ic];
    size_t o = (((size_t)b * 128 + y) * 128 + x) * 128 + icb * 32 + ic;
    xh[o] = (ushort)(v & 0xffffu);
    xl[o] = (ushort)(v >> 16);
  }
}

__global__ void wsplit_k(const float* __restrict__ w,
                         ushort* __restrict__ wh, ushort* __restrict__ wl)
{
  int i = blockIdx.x * 256 + threadIdx.x;
  if (i >= 256 * 128 * 9) return;
  int k = i % 9; int r = i / 9; int ic = r & 127; int oc = r >> 7;
  float v = w[i];
  ushort hi = f2bf(v);
  ushort lo = f2bf(v - bf2f(hi));
  size_t d = ((size_t)k * 256 + oc) * 128 + ic;
  wh[d] = hi; wl[d] = lo;
}

__global__ void wsplit2_k(const float* __restrict__ w,
                          ushort* __restrict__ wh, ushort* __restrict__ wl,
                          int OC, int IC, int n)
{
  int i = blockIdx.x * 256 + threadIdx.x;
  if (i >= n) return;
  int kx = i & 3, ky = (i >> 2) & 3;
  int ic = (i >> 4) % IC, oc = (i >> 4) / IC;
  float v = w[i];
  ushort hi = f2bf(v);
  ushort lo = f2bf(v - bf2f(hi));
  size_t d = (((size_t)ky * (IC >> 3) + (ic >> 3)) * OC + oc) * 32 + kx * 8 + (ic & 7);
  wh[d] = hi; wl[d] = lo;
}

// ------- conv2 via MFMA (bf16x3), out: blocked bf16 hi/lo pre-BN -------
__global__ __launch_bounds__(256, 2) void conv2_mfma_k(
    const ushort* __restrict__ xh, const ushort* __restrict__ xl,
    const ushort* __restrict__ wph, const ushort* __restrict__ wpl,
    ushort* __restrict__ x3h, ushort* __restrict__ x3l)
{
  const int ocT = blockIdx.x;
  const int y0  = blockIdx.y * 2;
  const int b   = blockIdx.z;

  __shared__ ushort xs[2][2][132][32];
  __shared__ ushort wsm[2][2][128][32];

  const int t  = threadIdx.x;
  const int w  = t >> 6;
  const int l  = t & 63;
  const int rsel = w >> 1;
  const int xb   = (w & 1) * 64;
  const int lr = l & 15;
  const int kg = l >> 4;

  f32x4 acc[8][4];
#pragma unroll
  for (int i = 0; i < 8; ++i)
#pragma unroll
    for (int j = 0; j < 4; ++j) acc[i][j] = (f32x4){0.f, 0.f, 0.f, 0.f};

  for (int ky = 0; ky < 3; ++ky) {
    const int gy0 = y0 + ky - 1;
    for (int ic32 = 0; ic32 < 4; ++ic32) {
      __syncthreads();
      for (int e = t; e < 1040; e += 256) {
        int r   = e / 520;
        int q   = e - r * 520;
        int xi  = q >> 2;
        int icg = q & 3;
        int gy = gy0 + r, gx = xi - 1;
        uint4 vh = {0, 0, 0, 0}, vl = {0, 0, 0, 0};
        if ((unsigned)gy < 128u && (unsigned)gx < 128u) {
          size_t gi = (((size_t)b * 128 + gy) * 128 + gx) * 128 + ic32 * 32 + icg * 8;
          vh = *(const uint4*)(xh + gi);
          vl = *(const uint4*)(xl + gi);
        }
        *(uint4*)&xs[0][r][xi][icg * 8] = vh;
        *(uint4*)&xs[1][r][xi][icg * 8] = vl;
      }
      {
        const int kk = ky * 3;
        for (int e = t; e < 512; e += 256) {
          int oc = e >> 2, icg = e & 3;
          size_t gi = (((size_t)kk * 256 + ocT * 128 + oc) * 128) + ic32 * 32 + icg * 8;
          *(uint4*)&wsm[0][0][oc][icg * 8] = *(const uint4*)(wph + gi);
          *(uint4*)&wsm[0][1][oc][icg * 8] = *(const uint4*)(wpl + gi);
        }
      }
      __syncthreads();

      for (int kx = 0; kx < 3; ++kx) {
        if (kx) __syncthreads();
        if (kx < 2) {
          const int kk = ky * 3 + kx + 1;
          const int buf = (kx + 1) & 1;
          for (int e = t; e < 512; e += 256) {
            int oc = e >> 2, icg = e & 3;
            size_t gi = (((size_t)kk * 256 + ocT * 128 + oc) * 128) + ic32 * 32 + icg * 8;
            *(uint4*)&wsm[buf][0][oc][icg * 8] = *(const uint4*)(wph + gi);
            *(uint4*)&wsm[buf][1][oc][icg * 8] = *(const uint4*)(wpl + gi);
          }
        }
        const int buf = kx & 1;
        bf16x8 awh[8], awl[8], xbh[4], xbl[4];
#pragma unroll
        for (int of = 0; of < 8; ++of) {
          awh[of] = *(const bf16x8*)&wsm[buf][0][of * 16 + lr][kg * 8];
          awl[of] = *(const bf16x8*)&wsm[buf][1][of * 16 + lr][kg * 8];
        }
#pragma unroll
        for (int pf = 0; pf < 4; ++pf) {
          int xi = xb + pf * 16 + lr + kx;
          xbh[pf] = *(const bf16x8*)&xs[0][rsel][xi][kg * 8];
          xbl[pf] = *(const bf16x8*)&xs[1][rsel][xi][kg * 8];
        }
#pragma unroll
        for (int of = 0; of < 8; ++of) {
#pragma unroll
          for (int pf = 0; pf < 4; ++pf) {
            acc[of][pf] = __builtin_amdgcn_mfma_f32_16x16x32_bf16(awh[of], xbh[pf], acc[of][pf], 0, 0, 0);
            acc[of][pf] = __builtin_amdgcn_mfma_f32_16x16x32_bf16(awh[of], xbl[pf], acc[of][pf], 0, 0, 0);
            acc[of][pf] = __builtin_amdgcn_mfma_f32_16x16x32_bf16(awl[of], xbh[pf], acc[of][pf], 0, 0, 0);
          }
        }
      }
    }
  }

  const int yy = y0 + rsel;
#pragma unroll
  for (int of = 0; of < 8; ++of) {
#pragma unroll
    for (int pf = 0; pf < 4; ++pf) {
      int oc = ocT * 128 + of * 16 + kg * 4;
      int x  = xb + pf * 16 + lr;
      size_t pxg = ((size_t)b * 128 + yy) * 128 + x;
      size_t base = ((size_t)(oc >> 3) * 131072 + pxg) * 8 + (oc & 7);
      f32x4 a = acc[of][pf];
      ushort h0 = f2bf(a[0]); ushort l0 = f2bf(a[0] - bf2f(h0));
      ushort h1 = f2bf(a[1]); ushort l1 = f2bf(a[1] - bf2f(h1));
      ushort h2 = f2bf(a[2]); ushort l2 = f2bf(a[2] - bf2f(h2));
      ushort h3 = f2bf(a[3]); ushort l3 = f2bf(a[3] - bf2f(h3));
      uint2 uh = {(uint)h0 | ((uint)h1 << 16), (uint)h2 | ((uint)h3 << 16)};
      uint2 ul = {(uint)l0 | ((uint)l1 << 16), (uint)l2 | ((uint)l3 << 16)};
      *(uint2*)(x3h + base) = uh;
      *(uint2*)(x3l + base) = ul;
    }
  }
}

// ------- conv3/4/5 via MFMA, K-split over (ky, ch-group) into partials -------
// grid (OH/4, 8b, 4*CS); partial z = blockIdx.z
template<int IC, int OC, int OH, int OW, int WPX, int CS>
__global__ __launch_bounds__(256, 2) void convs_mfma_k(
    const ushort* __restrict__ xh, const ushort* __restrict__ xl,  // [IC/8][8*IH*IW][8]
    const ushort* __restrict__ wh, const ushort* __restrict__ wl,  // [4][IC/8][OC][32]
    float* __restrict__ part)                                       // [4*CS][8][OH][OW][OC]
{
  constexpr int IH  = 2 * OH, IW = 2 * OW;
  constexpr int NCH = IC / 8;
  constexpr int NCHB = NCH / CS;
  constexpr int PFX = OW / 16;
  constexpr int RW  = 4 / WPX;

  const int y0 = blockIdx.x * 4;
  const int b  = blockIdx.y;
  const int zi = blockIdx.z;
  const int ky = zi & 3;
  const int cs = zi >> 2;

  __shared__ ushort xs[2][4][2][OW + 2][8];
  __shared__ ushort wsm[2][OC][32];

  const int t = threadIdx.x;
  const int w = t >> 6, l = t & 63;
  const int wo = w / WPX, wp = w % WPX;
  const int lr = l & 15, kg = l >> 4;
  const int oc0w = wo * 64;
  const int rb = wp * RW;

  f32x4 acc[4][4];
#pragma unroll
  for (int i = 0; i < 4; ++i)
#pragma unroll
    for (int j = 0; j < 4; ++j) acc[i][j] = (f32x4){0.f, 0.f, 0.f, 0.f};

  for (int cc = 0; cc < NCHB; ++cc) {
    const int ch = cs * NCHB + cc;
    __syncthreads();
    for (int e = t; e < 4 * (IW + 2); e += 256) {
      int r  = e / (IW + 2);
      int xi = e % (IW + 2);
      int xp = xi - 1;
      int iy = 2 * (y0 + r) + ky - 1;
      uint4 vh = {0, 0, 0, 0}, vl = {0, 0, 0, 0};
      if ((unsigned)iy < (unsigned)IH && (unsigned)xp < (unsigned)IW) {
        size_t gi = ((((size_t)ch * 8 + b) * IH + iy) * IW + xp) * 8;
        vh = *(const uint4*)(xh + gi);
        vl = *(const uint4*)(xl + gi);
      }
      int par = xp & 1;
      int idx = (xp + 1) >> 1;
      *(uint4*)&xs[0][r][par][idx][0] = vh;
      *(uint4*)&xs[1][r][par][idx][0] = vl;
    }
    for (int e = t; e < OC * 4; e += 256) {
      size_t gi = (((size_t)ky * NCH + ch) * OC) * 32 + (size_t)e * 8;
      *(uint4*)((ushort*)wsm[0] + e * 8) = *(const uint4*)(wh + gi);
      *(uint4*)((ushort*)wsm[1] + e * 8) = *(const uint4*)(wl + gi);
    }
    __syncthreads();

    bf16x8 ah[4], al[4], bh[4], bl[4];
#pragma unroll
    for (int of = 0; of < 4; ++of) {
      ah[of] = *(const bf16x8*)&wsm[0][oc0w + of * 16 + lr][kg * 8];
      al[of] = *(const bf16x8*)&wsm[1][oc0w + of * 16 + lr][kg * 8];
    }
    const int par = 1 - (kg & 1);
    const int xoff = kg >> 1;
#pragma unroll
    for (int pf = 0; pf < 4; ++pf) {
      int row = rb + pf / PFX;
      int x   = (pf % PFX) * 16 + lr;
      bh[pf] = *(const bf16x8*)&xs[0][row][par][x + xoff][0];
      bl[pf] = *(const bf16x8*)&xs[1][row][par][x + xoff][0];
    }
#pragma unroll
    for (int of = 0; of < 4; ++of) {
#pragma unroll
      for (int pf = 0; pf < 4; ++pf) {
        acc[of][pf] = __builtin_amdgcn_mfma_f32_16x16x32_bf16(ah[of], bh[pf], acc[of][pf], 0, 0, 0);
        acc[of][pf] = __builtin_amdgcn_mfma_f32_16x16x32_bf16(ah[of], bl[pf], acc[of][pf], 0, 0, 0);
        acc[of][pf] = __builtin_amdgcn_mfma_f32_16x16x32_bf16(al[of], bh[pf], acc[of][pf], 0, 0, 0);
      }
    }
  }

  float* yp = part + (size_t)zi * (8 * OH * OW * OC);
#pragma unroll
  for (int of = 0; of < 4; ++of) {
#pragma unroll
    for (int pf = 0; pf < 4; ++pf) {
      int row = rb + pf / PFX;
      int x   = (pf % PFX) * 16 + lr;
      int oc  = oc0w + of * 16 + kg * 4;
      float* p = yp + (((size_t)b * OH + y0 + row) * OW + x) * OC + oc;
      f32x4 a = acc[of][pf];
      float4 v = {a[0], a[1], a[2], a[3]};
      *(float4*)p = v;
    }
  }
}

// ------- reduce partials -> h (float4) -------
__global__ __launch_bounds__(256) void reduce_k(
    const float* __restrict__ part, float* __restrict__ h,
    int n4, int nparts)
{
  int i = blockIdx.x * 256 + threadIdx.x;
  if (i >= n4) return;
  float4 a = ((const float4*)part)[i];
  for (int z = 1; z < nparts; ++z) {
    float4 b = ((const float4*)part)[(size_t)z * n4 + i];
    a.x += b.x; a.y += b.y; a.z += b.z; a.w += b.w;
  }
  ((float4*)h)[i] = a;
}

// ---------------- capsule rearrange (h5 NHWC + BN inline) ----------------
__global__ void caps_k(const float* __restrict__ h5, const float* __restrict__ stats,
                       float* __restrict__ caps)
{
  int e = blockIdx.x * 256 + threadIdx.x;
  if (e >= NB * NCAP * 8) return;
  int ii = e & 7;
  int n  = (e >> 3) & 511;
  int jb = e >> 12;
  int j = jb >> 3, b = jb & 7;
  int i = n >> 7, k = (n >> 5) & 3, ch = ((n & 31) << 3) | ii;
  int hh = (i << 2) | (j >> 2);
  int ww = ((j & 3) << 2) | k;
  float v = h5[(((size_t)b * 16 + hh) * 16 + ww) * 256 + ch];
  float a = fmaf(v, stats[512 + ch], stats[768 + ch]);
  a = fmaxf(a, 0.1f * a);
  caps[e] = a;
}

// ---------------- priors ----------------
__global__ __launch_bounds__(256) void priors_k(
    const float* __restrict__ caps, const float* __restrict__ rw,
    float* __restrict__ priors)
{
  const int n = blockIdx.x;
  __shared__ float lrw[NCLS * 8 * NO];
  __shared__ float lc[NB * 8];
  const int t = threadIdx.x;
  for (int e = t; e < NCLS * 8 * NO; e += 256)
    lrw[e] = rw[(size_t)n * NCLS * 8 * NO + e];
  for (int e = t; e < NB * 8; e += 256) {
    int b = e >> 3, ii = e & 7;
    lc[e] = caps[((size_t)b * NCAP + n) * 8 + ii];
  }
  __syncthreads();

  int p[4], kk[4], oo[4];
#pragma unroll
  for (int q = 0; q < 4; ++q) {
    p[q]  = t + q * 256;
    kk[q] = (p[q] < KO) ? p[q] / NO : 0;
    oo[q] = (p[q] < KO) ? p[q] % NO : 0;
  }
  for (int b = 0; b < NB; ++b) {
    const float* cb = &lc[b * 8];
    float c0 = cb[0], c1 = cb[1], c2 = cb[2], c3 = cb[3];
    float c4 = cb[4], c5 = cb[5], c6 = cb[6], c7 = cb[7];
    float* pout = priors + ((size_t)b * NCAP + n) * KO;
#pragma unroll
    for (int q = 0; q < 4; ++q) {
      if (p[q] < KO) {
        const float* wv = &lrw[kk[q] * (8 * NO) + oo[q]];
        float a = c0 * wv[0];
        a = fmaf(c1, wv[21],  a);
        a = fmaf(c2, wv[42],  a);
        a = fmaf(c3, wv[63],  a);
        a = fmaf(c4, wv[84],  a);
        a = fmaf(c5, wv[105], a);
        a = fmaf(c6, wv[126], a);
        a = fmaf(c7, wv[147], a);
        pout[p[q]] = a;
      }
    }
  }
}

// ---------------- routing ----------------
// iter 0: uniform probs
__global__ __launch_bounds__(256) void route_s_partial(
    const float* __restrict__ priors, float* __restrict__ s)
{
  const int b  = blockIdx.x >> 3;
  const int ns = blockIdx.x & 7;
  const int t  = threadIdx.x;
  const int p0 = t, p1 = t + 256, p2 = t + 512, p3 = t + 768;
  float a0 = 0.f, a1 = 0.f, a2 = 0.f, a3 = 0.f;
  const float* pb = priors + ((size_t)b * NCAP + ns * 64) * KO;
#pragma unroll 2
  for (int n = 0; n < 64; ++n) {
    const float* pn = pb + (size_t)n * KO;
    a0 += pn[p0]; a1 += pn[p1]; a2 += pn[p2];
    if (p3 < KO) a3 += pn[p3];
  }
  const float sc = 1.f / 43.f;
  atomicAdd(&s[b * KO + p0], a0 * sc);
  atomicAdd(&s[b * KO + p1], a1 * sc);
  atomicAdd(&s[b * KO + p2], a2 * sc);
  if (p3 < KO) atomicAdd(&s[b * KO + p3], a3 * sc);
}

// fused: logits += priors . souts; probs = softmax; s += probs * priors
// one read of priors per iteration. grid = NB*8, block 256; block = (b, 64 n's)
__global__ __launch_bounds__(256) void route_iter_k(
    const float* __restrict__ priors, const float* __restrict__ souts,
    float* __restrict__ logits, float* __restrict__ s,
    int readPrev, int writeL)
{
  const int b  = blockIdx.x >> 3;
  const int ns = blockIdx.x & 7;
  const int t  = threadIdx.x;

  __shared__ float so_l[KO];
  __shared__ float sacc[KO];
  __shared__ float prow[KO];
  __shared__ float pk[NCLS];

  const int e0 = t, e1 = t + 256, e2 = t + 512, e3 = t + 768;
  const int k0 = e0 / NO, k1 = e1 / NO, k2 = e2 / NO;
  const int k3 = (e3 < KO) ? e3 / NO : 0;

  for (int e = t; e < KO; e += 256) {
    so_l[e] = souts[b * KO + e];
    sacc[e] = 0.f;
  }
  __syncthreads();

  for (int nn = 0; nn < 64; ++nn) {
    const int n = ns * 64 + nn;
    const float* pr = priors + ((size_t)b * NCAP + n) * KO;
    float v0 = pr[e0], v1 = pr[e1], v2 = pr[e2];
    float v3 = (e3 < KO) ? pr[e3] : 0.f;
    prow[e0] = v0; prow[e1] = v1; prow[e2] = v2;
    if (e3 < KO) prow[e3] = v3;
    __syncthreads();

    if (t < 64) {
      float L = -1e30f;
      if (t < NCLS) {
        float d = 0.f;
        const float* pp = &prow[t * NO];
        const float* ss = &so_l[t * NO];
#pragma unroll
        for (int o = 0; o < NO; ++o) d = fmaf(pp[o], ss[o], d);
        size_t lidx = ((size_t)(b * NCAP + n)) * NCLS + t;
        L = (readPrev ? logits[lidx] : 0.f) + d;
        if (writeL) logits[lidx] = L;
      }
      float m = L;
#pragma unroll
      for (int off = 32; off > 0; off >>= 1) m = fmaxf(m, __shfl_xor(m, off));
      float ex = (t < NCLS) ? __expf(L - m) : 0.f;
      float sm = ex;
#pragma unroll
      for (int off = 32; off > 0; off >>= 1) sm += __shfl_xor(sm, off);
      if (t < NCLS) pk[t] = ex / sm;
    }
    __syncthreads();

    sacc[e0] += pk[k0] * v0;
    sacc[e1] += pk[k1] * v1;
    sacc[e2] += pk[k2] * v2;
    if (e3 < KO) sacc[e3] += pk[k3] * v3;
  }
  __syncthreads();
  for (int e = t; e < KO; e += 256)
    atomicAdd(&s[b * KO + e], sacc[e]);
}

__global__ void squash_k(const float* __restrict__ s, float* __restrict__ souts)
{
  int i = blockIdx.x * 256 + threadIdx.x;
  if (i >= NB * NCLS) return;
  int b = i / NCLS, k = i % NCLS;
  const float* sv = s + b * KO + k * NO;
  float sn = 0.f;
#pragma unroll
  for (int o = 0; o < NO; ++o) sn += sv[o] * sv[o];
  float f = sqrtf(sn) / (1.f + sn);
  float* ov = souts + b * KO + k * NO;
#pragma unroll
  for (int o = 0; o < NO; ++o) ov[o] = sv[o] * f;
}

__global__ void out_k(const float* __restrict__ souts, float* __restrict__ out)
{
  int i = blockIdx.x * 256 + threadIdx.x;
  if (i >= 8 * 16 * NCLS * NO) return;
  int o = i % NO;
  int r = i / NO;
  int k = r % NCLS; r /= NCLS;
  int g1 = r & 3; r >>= 2;
  int g0 = r & 3;
  int b  = r >> 2;
  int j  = g0 * 4 + g1;
  int jb = j * 8 + b;
  out[i] = souts[jb * KO + k * NO + o];
}

// ---------------- launcher ----------------
extern "C" void kernel_launch(void* const* d_in, const int* in_sizes, int n_in,
                              void* d_out, int out_size, void* d_ws, size_t ws_size,
                              hipStream_t stream)
{
  const float* x   = (const float*)d_in[0];
  const float* c1w = (const float*)d_in[1];
  const float* g1  = (const float*)d_in[3];  const float* b1  = (const float*)d_in[4];
  const float* c2w = (const float*)d_in[5];
  const float* g2  = (const float*)d_in[7];  const float* b2  = (const float*)d_in[8];
  const float* c3w = (const float*)d_in[9];
  const float* g3  = (const float*)d_in[11]; const float* b3  = (const float*)d_in[12];
  const float* c4w = (const float*)d_in[13];
  const float* g4  = (const float*)d_in[15]; const float* b4  = (const float*)d_in[16];
  const float* c5w = (const float*)d_in[17];
  const float* g5  = (const float*)d_in[19]; const float* b5  = (const float*)d_in[20];
  const float* rw  = (const float*)d_in[21];

  float* ws  = (float*)d_ws;
  float* out = (float*)d_out;

  ushort* xth = (ushort*)(ws + F_XTH);
  ushort* xtl = (ushort*)(ws + F_XTL);
  ushort* wph = (ushort*)(ws + F_WPH);
  ushort* wpl = (ushort*)(ws + F_WPL);
  ushort* w3h = (ushort*)(ws + F_W3H);
  ushort* w3l = (ushort*)(ws + F_W3L);
  ushort* w4h = (ushort*)(ws + F_W4H);
  ushort* w4l = (ushort*)(ws + F_W4L);
  ushort* w5h = (ushort*)(ws + F_W5H);
  ushort* w5l = (ushort*)(ws + F_W5L);
  ushort* x3h = (ushort*)(ws + F_X3H);
  ushort* x3l = (ushort*)(ws + F_X3L);
  ushort* x4h = (ushort*)(ws + F_X4H);
  ushort* x4l = (ushort*)(ws + F_X4L);
  ushort* x5h = (ushort*)(ws + F_X5H);
  ushort* x5l = (ushort*)(ws + F_X5L);
  float* part   = ws + F_PART;
  float* h1     = ws + F_H1;
  float* h3     = ws + F_H3;
  float* h4     = ws + F_H4;
  float* h5     = ws + F_H5;
  float* caps   = ws + F_CAPS;
  float* priors = ws + F_PRI;
  float* logits = ws + F_LOG;
  float* sbuf   = ws + F_S;
  float* souts  = ws + F_OUTS;
  float* stats  = ws + F_STAT;

  // ---- weight preps ----
  wsplit_k<<<(256 * 128 * 9 + 255) / 256, 256, 0, stream>>>(c2w, wph, wpl);
  wsplit2_k<<<(64 * 256 * 16 + 255) / 256, 256, 0, stream>>>(c3w, w3h, w3l, 64, 256, 64 * 256 * 16);
  wsplit2_k<<<(128 * 64 * 16 + 255) / 256, 256, 0, stream>>>(c4w, w4h, w4l, 128, 64, 128 * 64 * 16);
  wsplit2_k<<<(256 * 128 * 16 + 255) / 256, 256, 0, stream>>>(c5w, w5h, w5l, 256, 128, 256 * 128 * 16);

  // ---- conv1 (fp32 direct) + BN + split/transpose ----
  conv_k<3, 1, 3, 10, 18><<<dim3(8, 16, 8 * 4), 256, 0, stream>>>(
      x, c1w, h1, 3, 128, 128, 128, 128, 128);
  hipMemsetAsync(stats, 0, 2 * 128 * sizeof(float), stream);
  bn_stats_k<<<128 * 16, 256, 0, stream>>>(h1, stats, 128, 14, 16, 131072);
  bn_fin_k<<<1, 256, 0, stream>>>(stats, g1, b1, 128, 1.f / 131072.f);
  bn_t_split_k<<<dim3(4, 128, 8), 256, 0, stream>>>(h1, stats, xth, xtl);

  // ---- conv2 (MFMA) -> blocked bf16 pre-BN; BN in-place ----
  conv2_mfma_k<<<dim3(2, 64, 8), 256, 0, stream>>>(xth, xtl, wph, wpl, x3h, x3l);
  hipMemsetAsync(stats, 0, 2 * 256 * sizeof(float), stream);
  bn_stats_blocked_k<<<32 * 4, 256, 0, stream>>>(x3h, x3l, stats, 32, 131072, 4);
  bn_fin_k<<<1, 256, 0, stream>>>(stats, g2, b2, 256, 1.f / 131072.f);
  bn_apply_blocked_k<<<2048, 256, 0, stream>>>(x3h, x3l, stats, 256, 17, (size_t)32 * 131072);

  // ---- conv3 (MFMA, ky-split x4 -> 512 blocks) ----
  convs_mfma_k<256, 64, 64, 64, 4, 1><<<dim3(16, 8, 4), 256, 0, stream>>>(x3h, x3l, w3h, w3l, part);
  reduce_k<<<(524288 + 255) / 256, 256, 0, stream>>>(part, h3, 524288, 4);
  hipMemsetAsync(stats, 0, 2 * 64 * sizeof(float), stream);
  bn_stats_nhwc_k<<<64, 256, 0, stream>>>(h3, stats, 63, 6, 32768);
  bn_fin_k<<<1, 256, 0, stream>>>(stats, g3, b3, 64, 1.f / 32768.f);
  split_blocked_k<64><<<2048, 256, 0, stream>>>(h3, stats, x4h, x4l, 32768);

  // ---- conv4 (MFMA, (ky x ch/2)-split x8 -> 512 blocks) ----
  convs_mfma_k<64, 128, 32, 32, 2, 2><<<dim3(8, 8, 8), 256, 0, stream>>>(x4h, x4l, w4h, w4l, part);
  reduce_k<<<(262144 + 255) / 256, 256, 0, stream>>>(part, h4, 262144, 8);
  hipMemsetAsync(stats, 0, 2 * 128 * sizeof(float), stream);
  bn_stats_nhwc_k<<<32, 256, 0, stream>>>(h4, stats, 127, 7, 8192);
  bn_fin_k<<<1, 256, 0, stream>>>(stats, g4, b4, 128, 1.f / 8192.f);
  split_blocked_k<128><<<512, 256, 0, stream>>>(h4, stats, x5h, x5l, 8192);

  // ---- conv5 (MFMA, (ky x ch/2)-split x8 -> 256 blocks) ----
  convs_mfma_k<128, 256, 16, 16, 1, 2><<<dim3(4, 8, 8), 256, 0, stream>>>(x5h, x5l, w5h, w5l, part);
  reduce_k<<<(131072 + 255) / 256, 256, 0, stream>>>(part, h5, 131072, 8);
  hipMemsetAsync(stats, 0, 2 * 256 * sizeof(float), stream);
  bn_stats_nhwc_k<<<8, 256, 0, stream>>>(h5, stats, 255, 8, 2048);
  bn_fin_k<<<1, 256, 0, stream>>>(stats, g5, b5, 256, 1.f / 2048.f);

  // ---- capsules ----
  caps_k<<<2048, 256, 0, stream>>>(h5, stats, caps);
  priors_k<<<512, 256, 0, stream>>>(caps, rw, priors);

  // ---- routing: 3 iterations (iters 1,2 fused logits+softmax+s) ----
  hipMemsetAsync(sbuf, 0, NB * KO * sizeof(float), stream);
  route_s_partial<<<NB * 8, 256, 0, stream>>>(priors, sbuf);
  squash_k<<<(NB * NCLS + 255) / 256, 256, 0, stream>>>(sbuf, souts);

  hipMemsetAsync(sbuf, 0, NB * KO * sizeof(float), stream);
  route_iter_k<<<NB * 8, 256, 0, stream>>>(priors, souts, logits, sbuf, 0, 1);
  squash_k<<<(NB * NCLS + 255) / 256, 256, 0, stream>>>(sbuf, souts);

  hipMemsetAsync(sbuf, 0, NB * KO * sizeof(float), stream);
  route_iter_k<<<NB * 8, 256, 0, stream>>>(priors, souts, logits, sbuf, 1, 0);
  squash_k<<<(NB * NCLS + 255) / 256, 256, 0, stream>>>(sbuf, souts);

  // ---- final scatter ----
  out_k<<<(8 * 16 * NCLS * NO + 255) / 256, 256, 0, stream>>>(souts, out);
}

// Round 5
// 758.934 us; speedup vs baseline: 3.5925x; 1.2911x over previous
//
#include <hip/hip_runtime.h>
#include <math.h>

typedef unsigned int   uint;
typedef unsigned short ushort;
using bf16x8 = __attribute__((ext_vector_type(8))) __bf16;
using f32x4  = __attribute__((ext_vector_type(4))) float;

constexpr int NB   = 128;
constexpr int NCAP = 512;
constexpr int NCLS = 43;
constexpr int NO   = 21;
constexpr int KO   = NCLS * NO; // 903

// ---- workspace layout (float offsets) ----
constexpr size_t F_X1H  = 0;          // conv1 out hi, blocked [16][131072][8] bf16 (8,388,608 f32)
constexpr size_t F_X1L  = 8388608;
constexpr size_t F_PART = 0;          // conv3/4/5 K-split partials (reuses x1 region; x1 dead)
constexpr size_t F_STAT = 16777216;   // 1,024
constexpr size_t F_WPH  = 16778240;   // conv2 w (147,456)
constexpr size_t F_WPL  = 16925696;
constexpr size_t F_W3H  = 17073152;
constexpr size_t F_W3L  = 17204224;
constexpr size_t F_W4H  = 17335296;
constexpr size_t F_W4L  = 17400832;
constexpr size_t F_W5H  = 17466368;
constexpr size_t F_W5L  = 17728512;
constexpr size_t F_X3H  = 17990656;   // conv2 out hi, blocked [32][131072][8] bf16
constexpr size_t F_X3L  = 34767872;   // ends 51,545,088
constexpr size_t F_H3   = 51545088;   // h3 NHWC fp32 (2,097,152)
constexpr size_t F_X4H  = 53642240;
constexpr size_t F_X4L  = 54690816;
constexpr size_t F_H4   = 55739392;
constexpr size_t F_X5H  = 56787968;
constexpr size_t F_X5L  = 57312256;
constexpr size_t F_H5   = 57836544;   // (524,288)
// routing phase:
constexpr size_t F_PRI  = 0;          // 59,179,008
constexpr size_t F_CAPS = 59179008;   // 524,288
constexpr size_t F_LOG  = 59703296;   // 2,818,048
constexpr size_t F_S    = 65339392;   // 115,584
constexpr size_t F_OUTS = 65454976;   // 115,584

__device__ inline ushort f2bf(float x) {
  uint u = __float_as_uint(x);
  uint r = (u + 0x7fffu + ((u >> 16) & 1u)) >> 16;  // RNE
  return (ushort)r;
}
__device__ inline float bf2f(ushort h) { return __uint_as_float(((uint)h) << 16); }

// ---------------- conv1: fp32 direct, writes blocked pre-BN bf16 hi/lo ----
__global__ __launch_bounds__(256) void conv1_k(
    const float* __restrict__ in, const float* __restrict__ w,
    ushort* __restrict__ oh, ushort* __restrict__ ol)
{
  constexpr int KS = 3, ICC = 3, IHT = 10, IWT = 18;
  const int ocb = blockIdx.z & 3;
  const int b   = blockIdx.z >> 2;
  const int tx0 = blockIdx.x * 16;
  const int ty0 = blockIdx.y * 8;
  const int oc0 = ocb * 32;

  __shared__ float lin[ICC][IHT][IWT];
  __shared__ float lw[ICC][KS * KS][32];

  const int t  = threadIdx.x;
  const int pq = t & 3;
  const int ty = (t >> 2) & 7;
  const int oq = t >> 5;

  float acc[4][4];
#pragma unroll
  for (int m = 0; m < 4; ++m)
#pragma unroll
    for (int j = 0; j < 4; ++j) acc[m][j] = 0.f;

  const int gx0 = tx0 - 1;
  const int gy0 = ty0 - 1;

  for (int e = t; e < ICC * IHT * IWT; e += 256) {
    int ic = e / (IHT * IWT);
    int rr = e % (IHT * IWT);
    int ey = rr / IWT, ex = rr % IWT;
    int gy = gy0 + ey, gx = gx0 + ex;
    float v = 0.f;
    if ((unsigned)gy < 128u && (unsigned)gx < 128u)
      v = in[((size_t)(b * 3 + ic) * 128 + gy) * 128 + gx];
    lin[ic][ey][ex] = v;
  }
  for (int e = t; e < ICC * 9 * 32; e += 256) {
    int ocl = e & 31;
    int rr  = e >> 5;
    int kk  = rr % 9;
    int ic  = rr / 9;
    lw[ic][kk][ocl] = w[((size_t)(oc0 + ocl) * 3 + ic) * 9 + kk];
  }
  __syncthreads();

  for (int ic = 0; ic < ICC; ++ic) {
#pragma unroll
    for (int ky = 0; ky < KS; ++ky) {
#pragma unroll
      for (int kx = 0; kx < KS; ++kx) {
        float xv[4];
#pragma unroll
        for (int j = 0; j < 4; ++j)
          xv[j] = lin[ic][ty + ky][pq * 4 + j + kx];
        const float4 w4 = *(const float4*)&lw[ic][ky * KS + kx][oq * 4];
#pragma unroll
        for (int j = 0; j < 4; ++j) {
          acc[0][j] = fmaf(w4.x, xv[j], acc[0][j]);
          acc[1][j] = fmaf(w4.y, xv[j], acc[1][j]);
          acc[2][j] = fmaf(w4.z, xv[j], acc[2][j]);
          acc[3][j] = fmaf(w4.w, xv[j], acc[3][j]);
        }
      }
    }
  }

  const int oy = ty0 + ty;
  const int oc0q = oc0 + oq * 4;
  const size_t icb = oc0q >> 3;
  const int off = oc0q & 7;
#pragma unroll
  for (int j = 0; j < 4; ++j) {
    int px = tx0 + pq * 4 + j;
    size_t pxg = ((size_t)b * 128 + oy) * 128 + px;
    size_t addr = (icb * 131072 + pxg) * 8 + off;
    ushort h0 = f2bf(acc[0][j]); ushort l0 = f2bf(acc[0][j] - bf2f(h0));
    ushort h1 = f2bf(acc[1][j]); ushort l1 = f2bf(acc[1][j] - bf2f(h1));
    ushort h2 = f2bf(acc[2][j]); ushort l2 = f2bf(acc[2][j] - bf2f(h2));
    ushort h3 = f2bf(acc[3][j]); ushort l3 = f2bf(acc[3][j] - bf2f(h3));
    uint2 uh; uh.x = (uint)h0 | ((uint)h1 << 16); uh.y = (uint)h2 | ((uint)h3 << 16);
    uint2 ul; ul.x = (uint)l0 | ((uint)l1 << 16); ul.y = (uint)l2 | ((uint)l3 << 16);
    *(uint2*)(oh + addr) = uh;
    *(uint2*)(ol + addr) = ul;
  }
}

// ---------------- BN stats: blocked bf16 hi/lo ----------------
__global__ __launch_bounds__(256) void bn_stats_blocked_k(
    const ushort* __restrict__ xh, const ushort* __restrict__ xl,
    float* __restrict__ stats, int nj, int totpx, int slices)
{
  const int j  = blockIdx.x % nj;
  const int sl = blockIdx.x / nj;
  float s[8] = {0,0,0,0,0,0,0,0}, q[8] = {0,0,0,0,0,0,0,0};
  const ushort* ph = xh + (size_t)j * totpx * 8;
  const ushort* pl = xl + (size_t)j * totpx * 8;
  for (int p = sl * 256 + threadIdx.x; p < totpx; p += slices * 256) {
    uint4 vh = *(const uint4*)(ph + (size_t)p * 8);
    uint4 vl = *(const uint4*)(pl + (size_t)p * 8);
    uint hw[4] = {vh.x, vh.y, vh.z, vh.w};
    uint lw[4] = {vl.x, vl.y, vl.z, vl.w};
#pragma unroll
    for (int m = 0; m < 4; ++m) {
      float v0 = __uint_as_float(hw[m] << 16) + __uint_as_float(lw[m] << 16);
      float v1 = __uint_as_float(hw[m] & 0xffff0000u) + __uint_as_float(lw[m] & 0xffff0000u);
      s[2*m] += v0; q[2*m] += v0 * v0;
      s[2*m+1] += v1; q[2*m+1] += v1 * v1;
    }
  }
#pragma unroll
  for (int off = 32; off > 0; off >>= 1)
#pragma unroll
    for (int k = 0; k < 8; ++k) {
      s[k] += __shfl_down(s[k], off);
      q[k] += __shfl_down(q[k], off);
    }
  __shared__ float red[4][16];
  int wid = threadIdx.x >> 6, lane = threadIdx.x & 63;
  if (lane == 0) {
#pragma unroll
    for (int k = 0; k < 8; ++k) { red[wid][k] = s[k]; red[wid][8 + k] = q[k]; }
  }
  __syncthreads();
  if (threadIdx.x < 16) {
    float a = red[0][threadIdx.x] + red[1][threadIdx.x] + red[2][threadIdx.x] + red[3][threadIdx.x];
    int C = nj * 8;
    int c = j * 8 + (threadIdx.x & 7);
    atomicAdd(&stats[(threadIdx.x >> 3) * C + c], a);
  }
}

__global__ __launch_bounds__(256) void bn_stats_nhwc_k(
    const float* __restrict__ x, float* __restrict__ stats,
    int cmask, int lg2c, int totpx)
{
  int g = blockIdx.x * 256 + threadIdx.x;
  int c = g & cmask;
  int p0 = g >> lg2c;
  int stride = (gridDim.x * 256) >> lg2c;
  float s = 0.f, q = 0.f;
  for (int p = p0; p < totpx; p += stride) {
    float v = x[((size_t)p << lg2c) | c];
    s += v; q += v * v;
  }
  atomicAdd(&stats[c], s);
  atomicAdd(&stats[cmask + 1 + c], q);
}

// ---- BN+LReLU+split fp32 NHWC -> blocked bf16 hi/lo (inline fin) ----
template<int C>
__global__ __launch_bounds__(256) void split_blocked_k(
    const float* __restrict__ h, const float* __restrict__ stats,
    const float* __restrict__ g, const float* __restrict__ bt, float inv_n,
    ushort* __restrict__ oh, ushort* __restrict__ ol, int totpx)
{
  __shared__ ushort lh[16][C + 8], ll[16][C + 8];
  __shared__ float scs[C], sfs[C];
  const int px0 = blockIdx.x * 16;
  const int t = threadIdx.x;
  if (t < C) {
    float m = stats[t] * inv_n;
    float v = stats[C + t] * inv_n - m * m;
    float rs = rsqrtf(v + 1e-5f);
    float sc = g[t] * rs;
    scs[t] = sc; sfs[t] = bt[t] - m * sc;
  }
  __syncthreads();
  for (int e = t; e < 16 * C / 4; e += 256) {
    int px = e / (C / 4);
    int c0 = (e % (C / 4)) * 4;
    float4 v  = *(const float4*)(h + (size_t)(px0 + px) * C + c0);
    float a0 = fmaf(v.x, scs[c0],   sfs[c0]);   a0 = fmaxf(a0, 0.1f * a0);
    float a1 = fmaf(v.y, scs[c0+1], sfs[c0+1]); a1 = fmaxf(a1, 0.1f * a1);
    float a2 = fmaf(v.z, scs[c0+2], sfs[c0+2]); a2 = fmaxf(a2, 0.1f * a2);
    float a3 = fmaf(v.w, scs[c0+3], sfs[c0+3]); a3 = fmaxf(a3, 0.1f * a3);
    ushort h0 = f2bf(a0), h1 = f2bf(a1), h2v = f2bf(a2), h3v = f2bf(a3);
    lh[px][c0]   = h0;  ll[px][c0]   = f2bf(a0 - bf2f(h0));
    lh[px][c0+1] = h1;  ll[px][c0+1] = f2bf(a1 - bf2f(h1));
    lh[px][c0+2] = h2v; ll[px][c0+2] = f2bf(a2 - bf2f(h2v));
    lh[px][c0+3] = h3v; ll[px][c0+3] = f2bf(a3 - bf2f(h3v));
  }
  __syncthreads();
  for (int e = t; e < 16 * (C / 8); e += 256) {
    int j = e >> 4, px = e & 15;
    *(uint4*)(oh + ((size_t)j * totpx + px0 + px) * 8) = *(const uint4*)&lh[px][j * 8];
    *(uint4*)(ol + ((size_t)j * totpx + px0 + px) * 8) = *(const uint4*)&ll[px][j * 8];
  }
}

// ------- all weight splits merged -------
__global__ void wsplit_all_k(
    const float* __restrict__ c2w, const float* __restrict__ c3w,
    const float* __restrict__ c4w, const float* __restrict__ c5w,
    ushort* __restrict__ wph, ushort* __restrict__ wpl,
    ushort* __restrict__ w3h, ushort* __restrict__ w3l,
    ushort* __restrict__ w4h, ushort* __restrict__ w4l,
    ushort* __restrict__ w5h, ushort* __restrict__ w5l)
{
  int i = blockIdx.x * 256 + threadIdx.x;
  if (i < 294912) {
    // conv2: [oc][ic][3][3] -> [k][oc][ic]
    int k = i % 9; int r = i / 9; int ic = r & 127; int oc = r >> 7;
    float v = c2w[i];
    ushort hi = f2bf(v), lo = f2bf(v - bf2f(hi));
    size_t d = ((size_t)k * 256 + oc) * 128 + ic;
    wph[d] = hi; wpl[d] = lo;
    return;
  }
  i -= 294912;
  const float* w; ushort *wh, *wl; int OC, IC, n;
  if (i < 262144)      { w = c3w; wh = w3h; wl = w3l; OC = 64;  IC = 256; n = i; }
  else if (i < 393216) { w = c4w; wh = w4h; wl = w4l; OC = 128; IC = 64;  n = i - 262144; }
  else if (i < 917504) { w = c5w; wh = w5h; wl = w5l; OC = 256; IC = 128; n = i - 393216; }
  else return;
  int kx = n & 3, ky = (n >> 2) & 3;
  int ic = (n >> 4) % IC, oc = (n >> 4) / IC;
  float v = w[n];
  ushort hi = f2bf(v), lo = f2bf(v - bf2f(hi));
  size_t d = (((size_t)ky * (IC >> 3) + (ic >> 3)) * OC + oc) * 32 + kx * 8 + (ic & 7);
  wh[d] = hi; wl[d] = lo;
}

// ------- conv2 via MFMA (bf16x3), BN of x1 fused in staging, XCD swizzle ----
__global__ __launch_bounds__(256, 2) void conv2_mfma_k(
    const ushort* __restrict__ x1h, const ushort* __restrict__ x1l,
    const ushort* __restrict__ wph, const ushort* __restrict__ wpl,
    const float* __restrict__ stats, const float* __restrict__ g1,
    const float* __restrict__ b1,
    ushort* __restrict__ x3h, ushort* __restrict__ x3l)
{
  const int bid = blockIdx.x;
  const int wid = (bid & 7) * 128 + (bid >> 3);
  const int ocT = wid & 1;
  const int y0  = ((wid >> 1) & 63) * 2;
  const int b   = wid >> 7;

  __shared__ ushort xs[2][2][132][32];
  __shared__ ushort wsm[2][2][128][32];
  __shared__ float scs[128], sfs[128];

  const int t  = threadIdx.x;
  if (t < 128) {
    float m = stats[t] * (1.f / 131072.f);
    float v = stats[128 + t] * (1.f / 131072.f) - m * m;
    float rs = rsqrtf(v + 1e-5f);
    float sc = g1[t] * rs;
    scs[t] = sc; sfs[t] = b1[t] - m * sc;
  }

  const int w  = t >> 6;
  const int l  = t & 63;
  const int rsel = w >> 1;
  const int xb   = (w & 1) * 64;
  const int lr = l & 15;
  const int kg = l >> 4;

  f32x4 acc[8][4];
#pragma unroll
  for (int i = 0; i < 8; ++i)
#pragma unroll
    for (int j = 0; j < 4; ++j) acc[i][j] = (f32x4){0.f, 0.f, 0.f, 0.f};

  for (int ky = 0; ky < 3; ++ky) {
    const int gy0 = y0 + ky - 1;
    for (int ic32 = 0; ic32 < 4; ++ic32) {
      __syncthreads();
      // stage X with BN+LReLU fused (xi fastest for coalescing)
      for (int e = t; e < 1040; e += 256) {
        int r   = e / 520;
        int q   = e - r * 520;
        int icg = q / 130;
        int xi  = q - icg * 130;
        int gy = gy0 + r, gx = xi - 1;
        uint4 rh = {0, 0, 0, 0}, rl = {0, 0, 0, 0};
        if ((unsigned)gy < 128u && (unsigned)gx < 128u) {
          int jb = ic32 * 4 + icg;
          size_t gi = ((size_t)jb * 131072 + ((size_t)b * 128 + gy) * 128 + gx) * 8;
          uint4 vh = *(const uint4*)(x1h + gi);
          uint4 vl = *(const uint4*)(x1l + gi);
          int c0 = jb * 8;
          uint hw[4] = {vh.x, vh.y, vh.z, vh.w};
          uint lw[4] = {vl.x, vl.y, vl.z, vl.w};
          uint ohv[4], olv[4];
#pragma unroll
          for (int m = 0; m < 4; ++m) {
            float f0 = __uint_as_float(hw[m] << 16) + __uint_as_float(lw[m] << 16);
            float f1 = __uint_as_float(hw[m] & 0xffff0000u) + __uint_as_float(lw[m] & 0xffff0000u);
            float a0 = fmaf(f0, scs[c0 + 2*m],   sfs[c0 + 2*m]);   a0 = fmaxf(a0, 0.1f * a0);
            float a1 = fmaf(f1, scs[c0 + 2*m+1], sfs[c0 + 2*m+1]); a1 = fmaxf(a1, 0.1f * a1);
            ushort h0 = f2bf(a0), l0 = f2bf(a0 - bf2f(h0));
            ushort h1 = f2bf(a1), l1 = f2bf(a1 - bf2f(h1));
            ohv[m] = (uint)h0 | ((uint)h1 << 16);
            olv[m] = (uint)l0 | ((uint)l1 << 16);
          }
          rh.x = ohv[0]; rh.y = ohv[1]; rh.z = ohv[2]; rh.w = ohv[3];
          rl.x = olv[0]; rl.y = olv[1]; rl.z = olv[2]; rl.w = olv[3];
        }
        *(uint4*)&xs[0][r][xi][icg * 8] = rh;
        *(uint4*)&xs[1][r][xi][icg * 8] = rl;
      }
      {
        const int kk = ky * 3;
        for (int e = t; e < 512; e += 256) {
          int oc = e >> 2, icg = e & 3;
          size_t gi = (((size_t)kk * 256 + ocT * 128 + oc) * 128) + ic32 * 32 + icg * 8;
          *(uint4*)&wsm[0][0][oc][icg * 8] = *(const uint4*)(wph + gi);
          *(uint4*)&wsm[0][1][oc][icg * 8] = *(const uint4*)(wpl + gi);
        }
      }
      __syncthreads();

      for (int kx = 0; kx < 3; ++kx) {
        if (kx) __syncthreads();
        if (kx < 2) {
          const int kk = ky * 3 + kx + 1;
          const int buf = (kx + 1) & 1;
          for (int e = t; e < 512; e += 256) {
            int oc = e >> 2, icg = e & 3;
            size_t gi = (((size_t)kk * 256 + ocT * 128 + oc) * 128) + ic32 * 32 + icg * 8;
            *(uint4*)&wsm[buf][0][oc][icg * 8] = *(const uint4*)(wph + gi);
            *(uint4*)&wsm[buf][1][oc][icg * 8] = *(const uint4*)(wpl + gi);
          }
        }
        const int buf = kx & 1;
        bf16x8 awh[8], awl[8], xbh[4], xbl[4];
#pragma unroll
        for (int of = 0; of < 8; ++of) {
          awh[of] = *(const bf16x8*)&wsm[buf][0][of * 16 + lr][kg * 8];
          awl[of] = *(const bf16x8*)&wsm[buf][1][of * 16 + lr][kg * 8];
        }
#pragma unroll
        for (int pf = 0; pf < 4; ++pf) {
          int xi = xb + pf * 16 + lr + kx;
          xbh[pf] = *(const bf16x8*)&xs[0][rsel][xi][kg * 8];
          xbl[pf] = *(const bf16x8*)&xs[1][rsel][xi][kg * 8];
        }
#pragma unroll
        for (int of = 0; of < 8; ++of) {
#pragma unroll
          for (int pf = 0; pf < 4; ++pf) {
            acc[of][pf] = __builtin_amdgcn_mfma_f32_16x16x32_bf16(awh[of], xbh[pf], acc[of][pf], 0, 0, 0);
            acc[of][pf] = __builtin_amdgcn_mfma_f32_16x16x32_bf16(awh[of], xbl[pf], acc[of][pf], 0, 0, 0);
            acc[of][pf] = __builtin_amdgcn_mfma_f32_16x16x32_bf16(awl[of], xbh[pf], acc[of][pf], 0, 0, 0);
          }
        }
      }
    }
  }

  const int yy = y0 + rsel;
#pragma unroll
  for (int of = 0; of < 8; ++of) {
#pragma unroll
    for (int pf = 0; pf < 4; ++pf) {
      int oc = ocT * 128 + of * 16 + kg * 4;
      int x  = xb + pf * 16 + lr;
      size_t pxg = ((size_t)b * 128 + yy) * 128 + x;
      size_t base = ((size_t)(oc >> 3) * 131072 + pxg) * 8 + (oc & 7);
      f32x4 a = acc[of][pf];
      ushort h0 = f2bf(a[0]); ushort l0 = f2bf(a[0] - bf2f(h0));
      ushort h1 = f2bf(a[1]); ushort l1 = f2bf(a[1] - bf2f(h1));
      ushort h2 = f2bf(a[2]); ushort l2 = f2bf(a[2] - bf2f(h2));
      ushort h3 = f2bf(a[3]); ushort l3 = f2bf(a[3] - bf2f(h3));
      uint2 uh; uh.x = (uint)h0 | ((uint)h1 << 16); uh.y = (uint)h2 | ((uint)h3 << 16);
      uint2 ul; ul.x = (uint)l0 | ((uint)l1 << 16); ul.y = (uint)l2 | ((uint)l3 << 16);
      *(uint2*)(x3h + base) = uh;
      *(uint2*)(x3l + base) = ul;
    }
  }
}

// ------- conv3/4/5 via MFMA, K-split, optional BN fusion, XCD swizzle -------
template<int IC, int OC, int OH, int OW, int WPX, int CS, bool FBN>
__global__ __launch_bounds__(256, 2) void convs_mfma_k(
    const ushort* __restrict__ xh, const ushort* __restrict__ xl,
    const ushort* __restrict__ wh, const ushort* __restrict__ wl,
    const float* __restrict__ stats, const float* __restrict__ gg,
    const float* __restrict__ bb, float inv_n,
    float* __restrict__ part)
{
  constexpr int IH  = 2 * OH, IW = 2 * OW;
  constexpr int NCH = IC / 8;
  constexpr int NCHB = NCH / CS;
  constexpr int PFX = OW / 16;
  constexpr int RW  = 4 / WPX;
  constexpr int NZ = 4 * CS;
  constexpr int NX = OH / 4;
  constexpr int SBN = FBN ? IC : 1;

  const int bid = blockIdx.x;
  const int wid = (bid & 7) * (NZ * NX) + (bid >> 3);
  const int zi = wid % NZ;
  const int y0 = ((wid / NZ) % NX) * 4;
  const int b  = wid / (NZ * NX);
  const int ky = zi & 3;
  const int cs = zi >> 2;

  __shared__ ushort xs[2][4][2][OW + 2][8];
  __shared__ ushort wsm[2][OC][32];
  __shared__ float scs[SBN], sfs[SBN];

  const int t = threadIdx.x;
  if (FBN) {
    for (int c = t; c < IC; c += 256) {
      float m = stats[c] * inv_n;
      float v = stats[IC + c] * inv_n - m * m;
      float rs = rsqrtf(v + 1e-5f);
      float sc = gg[c] * rs;
      scs[c] = sc; sfs[c] = bb[c] - m * sc;
    }
  }

  const int w = t >> 6, l = t & 63;
  const int wo = w / WPX, wp = w % WPX;
  const int lr = l & 15, kg = l >> 4;
  const int oc0w = wo * 64;
  const int rb = wp * RW;

  f32x4 acc[4][4];
#pragma unroll
  for (int i = 0; i < 4; ++i)
#pragma unroll
    for (int j = 0; j < 4; ++j) acc[i][j] = (f32x4){0.f, 0.f, 0.f, 0.f};

  for (int cc = 0; cc < NCHB; ++cc) {
    const int ch = cs * NCHB + cc;
    __syncthreads();
    for (int e = t; e < 4 * (IW + 2); e += 256) {
      int r  = e / (IW + 2);
      int xi = e % (IW + 2);
      int xp = xi - 1;
      int iy = 2 * (y0 + r) + ky - 1;
      uint4 rh = {0, 0, 0, 0}, rl = {0, 0, 0, 0};
      if ((unsigned)iy < (unsigned)IH && (unsigned)xp < (unsigned)IW) {
        size_t gi = ((((size_t)ch * 8 + b) * IH + iy) * IW + xp) * 8;
        uint4 vh = *(const uint4*)(xh + gi);
        uint4 vl = *(const uint4*)(xl + gi);
        if (FBN) {
          int c0 = ch * 8;
          uint hw[4] = {vh.x, vh.y, vh.z, vh.w};
          uint lw[4] = {vl.x, vl.y, vl.z, vl.w};
          uint ohv[4], olv[4];
#pragma unroll
          for (int m = 0; m < 4; ++m) {
            float f0 = __uint_as_float(hw[m] << 16) + __uint_as_float(lw[m] << 16);
            float f1 = __uint_as_float(hw[m] & 0xffff0000u) + __uint_as_float(lw[m] & 0xffff0000u);
            float a0 = fmaf(f0, scs[c0 + 2*m],   sfs[c0 + 2*m]);   a0 = fmaxf(a0, 0.1f * a0);
            float a1 = fmaf(f1, scs[c0 + 2*m+1], sfs[c0 + 2*m+1]); a1 = fmaxf(a1, 0.1f * a1);
            ushort h0 = f2bf(a0), l0 = f2bf(a0 - bf2f(h0));
            ushort h1 = f2bf(a1), l1 = f2bf(a1 - bf2f(h1));
            ohv[m] = (uint)h0 | ((uint)h1 << 16);
            olv[m] = (uint)l0 | ((uint)l1 << 16);
          }
          rh.x = ohv[0]; rh.y = ohv[1]; rh.z = ohv[2]; rh.w = ohv[3];
          rl.x = olv[0]; rl.y = olv[1]; rl.z = olv[2]; rl.w = olv[3];
        } else {
          rh = vh; rl = vl;
        }
      }
      int par = xp & 1;
      int idx = (xp + 1) >> 1;
      *(uint4*)&xs[0][r][par][idx][0] = rh;
      *(uint4*)&xs[1][r][par][idx][0] = rl;
    }
    for (int e = t; e < OC * 4; e += 256) {
      size_t gi = (((size_t)ky * NCH + ch) * OC) * 32 + (size_t)e * 8;
      *(uint4*)((ushort*)wsm[0] + e * 8) = *(const uint4*)(wh + gi);
      *(uint4*)((ushort*)wsm[1] + e * 8) = *(const uint4*)(wl + gi);
    }
    __syncthreads();

    bf16x8 ah[4], al[4], bh[4], bl[4];
#pragma unroll
    for (int of = 0; of < 4; ++of) {
      ah[of] = *(const bf16x8*)&wsm[0][oc0w + of * 16 + lr][kg * 8];
      al[of] = *(const bf16x8*)&wsm[1][oc0w + of * 16 + lr][kg * 8];
    }
    const int par = 1 - (kg & 1);
    const int xoff = kg >> 1;
#pragma unroll
    for (int pf = 0; pf < 4; ++pf) {
      int row = rb + pf / PFX;
      int x   = (pf % PFX) * 16 + lr;
      bh[pf] = *(const bf16x8*)&xs[0][row][par][x + xoff][0];
      bl[pf] = *(const bf16x8*)&xs[1][row][par][x + xoff][0];
    }
#pragma unroll
    for (int of = 0; of < 4; ++of) {
#pragma unroll
      for (int pf = 0; pf < 4; ++pf) {
        acc[of][pf] = __builtin_amdgcn_mfma_f32_16x16x32_bf16(ah[of], bh[pf], acc[of][pf], 0, 0, 0);
        acc[of][pf] = __builtin_amdgcn_mfma_f32_16x16x32_bf16(ah[of], bl[pf], acc[of][pf], 0, 0, 0);
        acc[of][pf] = __builtin_amdgcn_mfma_f32_16x16x32_bf16(al[of], bh[pf], acc[of][pf], 0, 0, 0);
      }
    }
  }

  float* yp = part + (size_t)zi * (8 * OH * OW * OC);
#pragma unroll
  for (int of = 0; of < 4; ++of) {
#pragma unroll
    for (int pf = 0; pf < 4; ++pf) {
      int row = rb + pf / PFX;
      int x   = (pf % PFX) * 16 + lr;
      int oc  = oc0w + of * 16 + kg * 4;
      float* p = yp + (((size_t)b * OH + y0 + row) * OW + x) * OC + oc;
      f32x4 a = acc[of][pf];
      float4 v = {a[0], a[1], a[2], a[3]};
      *(float4*)p = v;
    }
  }
}

// ------- reduce partials -> h (float4) -------
__global__ __launch_bounds__(256) void reduce_k(
    const float* __restrict__ part, float* __restrict__ h,
    int n4, int nparts)
{
  int i = blockIdx.x * 256 + threadIdx.x;
  if (i >= n4) return;
  float4 a = ((const float4*)part)[i];
  for (int z = 1; z < nparts; ++z) {
    float4 b = ((const float4*)part)[(size_t)z * n4 + i];
    a.x += b.x; a.y += b.y; a.z += b.z; a.w += b.w;
  }
  ((float4*)h)[i] = a;
}

// ---------------- capsule rearrange (h5 NHWC, BN inline, fin inline) -------
__global__ void caps_k(const float* __restrict__ h5, const float* __restrict__ stats,
                       const float* __restrict__ g5, const float* __restrict__ b5,
                       float* __restrict__ caps)
{
  int e = blockIdx.x * 256 + threadIdx.x;
  if (e >= NB * NCAP * 8) return;
  int ii = e & 7;
  int n  = (e >> 3) & 511;
  int jb = e >> 12;
  int j = jb >> 3, b = jb & 7;
  int i = n >> 7, k = (n >> 5) & 3, ch = ((n & 31) << 3) | ii;
  int hh = (i << 2) | (j >> 2);
  int ww = ((j & 3) << 2) | k;
  float m  = stats[ch] * (1.f / 2048.f);
  float vv = stats[256 + ch] * (1.f / 2048.f) - m * m;
  float rs = rsqrtf(vv + 1e-5f);
  float sc = g5[ch] * rs;
  float sf = b5[ch] - m * sc;
  float v = h5[(((size_t)b * 16 + hh) * 16 + ww) * 256 + ch];
  float a = fmaf(v, sc, sf);
  a = fmaxf(a, 0.1f * a);
  caps[e] = a;
}

// ---------------- priors ----------------
__global__ __launch_bounds__(256) void priors_k(
    const float* __restrict__ caps, const float* __restrict__ rw,
    float* __restrict__ priors)
{
  const int n = blockIdx.x;
  __shared__ float lrw[NCLS * 8 * NO];
  __shared__ float lc[NB * 8];
  const int t = threadIdx.x;
  for (int e = t; e < NCLS * 8 * NO; e += 256)
    lrw[e] = rw[(size_t)n * NCLS * 8 * NO + e];
  for (int e = t; e < NB * 8; e += 256) {
    int b = e >> 3, ii = e & 7;
    lc[e] = caps[((size_t)b * NCAP + n) * 8 + ii];
  }
  __syncthreads();

  int p[4], kk[4], oo[4];
#pragma unroll
  for (int q = 0; q < 4; ++q) {
    p[q]  = t + q * 256;
    kk[q] = (p[q] < KO) ? p[q] / NO : 0;
    oo[q] = (p[q] < KO) ? p[q] % NO : 0;
  }
  for (int b = 0; b < NB; ++b) {
    const float* cb = &lc[b * 8];
    float c0 = cb[0], c1 = cb[1], c2 = cb[2], c3 = cb[3];
    float c4 = cb[4], c5 = cb[5], c6 = cb[6], c7 = cb[7];
    float* pout = priors + ((size_t)b * NCAP + n) * KO;
#pragma unroll
    for (int q = 0; q < 4; ++q) {
      if (p[q] < KO) {
        const float* wv = &lrw[kk[q] * (8 * NO) + oo[q]];
        float a = c0 * wv[0];
        a = fmaf(c1, wv[21],  a);
        a = fmaf(c2, wv[42],  a);
        a = fmaf(c3, wv[63],  a);
        a = fmaf(c4, wv[84],  a);
        a = fmaf(c5, wv[105], a);
        a = fmaf(c6, wv[126], a);
        a = fmaf(c7, wv[147], a);
        pout[p[q]] = a;
      }
    }
  }
}

// ---------------- routing ----------------
__global__ __launch_bounds__(256) void route_s_partial(
    const float* __restrict__ priors, float* __restrict__ s)
{
  const int b  = blockIdx.x >> 3;
  const int ns = blockIdx.x & 7;
  const int t  = threadIdx.x;
  const int p0 = t, p1 = t + 256, p2 = t + 512, p3 = t + 768;
  float a0 = 0.f, a1 = 0.f, a2 = 0.f, a3 = 0.f;
  const float* pb = priors + ((size_t)b * NCAP + ns * 64) * KO;
#pragma unroll 2
  for (int n = 0; n < 64; ++n) {
    const float* pn = pb + (size_t)n * KO;
    a0 += pn[p0]; a1 += pn[p1]; a2 += pn[p2];
    if (p3 < KO) a3 += pn[p3];
  }
  const float sc = 1.f / 43.f;
  atomicAdd(&s[b * KO + p0], a0 * sc);
  atomicAdd(&s[b * KO + p1], a1 * sc);
  atomicAdd(&s[b * KO + p2], a2 * sc);
  if (p3 < KO) atomicAdd(&s[b * KO + p3], a3 * sc);
}

// fused logits+softmax+s, wave-parallel over n (4 n's per block iteration)
__global__ __launch_bounds__(256) void route_iter_k(
    const float* __restrict__ priors, const float* __restrict__ souts,
    float* __restrict__ logits, float* __restrict__ s,
    int readPrev, int writeL)
{
  const int b  = blockIdx.x >> 3;
  const int ns = blockIdx.x & 7;
  const int t  = threadIdx.x;
  const int w  = t >> 6;
  const int lane = t & 63;

  __shared__ float so_l[KO];
  __shared__ float sacc[4][KO];
  __shared__ float prow[4][KO];
  __shared__ float pk[4][NCLS];

  for (int e = t; e < KO; e += 256) so_l[e] = souts[b * KO + e];
  for (int e = lane; e < KO; e += 64) sacc[w][e] = 0.f;

  int kq[15];
#pragma unroll
  for (int q = 0; q < 15; ++q) {
    int e = lane + q * 64;
    kq[q] = (e < KO) ? e / NO : 0;
  }
  __syncthreads();

  for (int nn = 0; nn < 16; ++nn) {
    const int n = ns * 64 + w * 16 + nn;
    const float* pr = priors + ((size_t)(b * NCAP + n)) * KO;
    float v[15];
#pragma unroll
    for (int q = 0; q < 15; ++q) {
      int e = lane + q * 64;
      if (e < KO) { v[q] = pr[e]; prow[w][e] = v[q]; }
      else v[q] = 0.f;
    }
    __syncthreads();

    float L = -1e30f;
    if (lane < NCLS) {
      float d = 0.f;
      const float* pp = &prow[w][lane * NO];
      const float* ss = &so_l[lane * NO];
#pragma unroll
      for (int o = 0; o < NO; ++o) d = fmaf(pp[o], ss[o], d);
      size_t lidx = ((size_t)(b * NCAP + n)) * NCLS + lane;
      L = (readPrev ? logits[lidx] : 0.f) + d;
      if (writeL) logits[lidx] = L;
    }
    float m = L;
#pragma unroll
    for (int off = 32; off > 0; off >>= 1) m = fmaxf(m, __shfl_xor(m, off));
    float ex = (lane < NCLS) ? __expf(L - m) : 0.f;
    float sm = ex;
#pragma unroll
    for (int off = 32; off > 0; off >>= 1) sm += __shfl_xor(sm, off);
    if (lane < NCLS) pk[w][lane] = ex / sm;
    __syncthreads();

#pragma unroll
    for (int q = 0; q < 15; ++q) {
      int e = lane + q * 64;
      if (e < KO) sacc[w][e] += pk[w][kq[q]] * v[q];
    }
  }
  __syncthreads();
  for (int e = t; e < KO; e += 256)
    atomicAdd(&s[b * KO + e], sacc[0][e] + sacc[1][e] + sacc[2][e] + sacc[3][e]);
}

__global__ void squash_k(const float* __restrict__ s, float* __restrict__ souts)
{
  int i = blockIdx.x * 256 + threadIdx.x;
  if (i >= NB * NCLS) return;
  int b = i / NCLS, k = i % NCLS;
  const float* sv = s + b * KO + k * NO;
  float sn = 0.f;
#pragma unroll
  for (int o = 0; o < NO; ++o) sn += sv[o] * sv[o];
  float f = sqrtf(sn) / (1.f + sn);
  float* ov = souts + b * KO + k * NO;
#pragma unroll
  for (int o = 0; o < NO; ++o) ov[o] = sv[o] * f;
}

__global__ void out_k(const float* __restrict__ souts, float* __restrict__ out)
{
  int i = blockIdx.x * 256 + threadIdx.x;
  if (i >= 8 * 16 * NCLS * NO) return;
  int o = i % NO;
  int r = i / NO;
  int k = r % NCLS; r /= NCLS;
  int g1 = r & 3; r >>= 2;
  int g0 = r & 3;
  int b  = r >> 2;
  int j  = g0 * 4 + g1;
  int jb = j * 8 + b;
  out[i] = souts[jb * KO + k * NO + o];
}

// ---------------- launcher ----------------
extern "C" void kernel_launch(void* const* d_in, const int* in_sizes, int n_in,
                              void* d_out, int out_size, void* d_ws, size_t ws_size,
                              hipStream_t stream)
{
  const float* x   = (const float*)d_in[0];
  const float* c1w = (const float*)d_in[1];
  const float* g1  = (const float*)d_in[3];  const float* b1  = (const float*)d_in[4];
  const float* c2w = (const float*)d_in[5];
  const float* g2  = (const float*)d_in[7];  const float* b2  = (const float*)d_in[8];
  const float* c3w = (const float*)d_in[9];
  const float* g3  = (const float*)d_in[11]; const float* b3  = (const float*)d_in[12];
  const float* c4w = (const float*)d_in[13];
  const float* g4  = (const float*)d_in[15]; const float* b4  = (const float*)d_in[16];
  const float* c5w = (const float*)d_in[17];
  const float* g5  = (const float*)d_in[19]; const float* b5  = (const float*)d_in[20];
  const float* rw  = (const float*)d_in[21];

  float* ws  = (float*)d_ws;
  float* out = (float*)d_out;

  ushort* x1h = (ushort*)(ws + F_X1H);
  ushort* x1l = (ushort*)(ws + F_X1L);
  ushort* wph = (ushort*)(ws + F_WPH);
  ushort* wpl = (ushort*)(ws + F_WPL);
  ushort* w3h = (ushort*)(ws + F_W3H);
  ushort* w3l = (ushort*)(ws + F_W3L);
  ushort* w4h = (ushort*)(ws + F_W4H);
  ushort* w4l = (ushort*)(ws + F_W4L);
  ushort* w5h = (ushort*)(ws + F_W5H);
  ushort* w5l = (ushort*)(ws + F_W5L);
  ushort* x3h = (ushort*)(ws + F_X3H);
  ushort* x3l = (ushort*)(ws + F_X3L);
  ushort* x4h = (ushort*)(ws + F_X4H);
  ushort* x4l = (ushort*)(ws + F_X4L);
  ushort* x5h = (ushort*)(ws + F_X5H);
  ushort* x5l = (ushort*)(ws + F_X5L);
  float* part   = ws + F_PART;
  float* h3     = ws + F_H3;
  float* h4     = ws + F_H4;
  float* h5     = ws + F_H5;
  float* caps   = ws + F_CAPS;
  float* priors = ws + F_PRI;
  float* logits = ws + F_LOG;
  float* sbuf   = ws + F_S;
  float* souts  = ws + F_OUTS;
  float* stats  = ws + F_STAT;

  // ---- weight preps (merged) ----
  wsplit_all_k<<<(1212416 + 255) / 256, 256, 0, stream>>>(
      c2w, c3w, c4w, c5w, wph, wpl, w3h, w3l, w4h, w4l, w5h, w5l);

  // ---- conv1 -> blocked pre-BN bf16 hi/lo; stats ----
  conv1_k<<<dim3(8, 16, 32), 256, 0, stream>>>(x, c1w, x1h, x1l);
  hipMemsetAsync(stats, 0, 2 * 128 * sizeof(float), stream);
  bn_stats_blocked_k<<<16 * 16, 256, 0, stream>>>(x1h, x1l, stats, 16, 131072, 16);

  // ---- conv2 (MFMA, BN of x1 fused, XCD swizzle) -> blocked pre-BN; stats ----
  conv2_mfma_k<<<1024, 256, 0, stream>>>(x1h, x1l, wph, wpl, stats, g1, b1, x3h, x3l);
  hipMemsetAsync(stats, 0, 2 * 256 * sizeof(float), stream);
  bn_stats_blocked_k<<<32 * 8, 256, 0, stream>>>(x3h, x3l, stats, 32, 131072, 8);

  // ---- conv3 (MFMA, ky-split x4, BN of x3 fused) ----
  convs_mfma_k<256, 64, 64, 64, 4, 1, true><<<512, 256, 0, stream>>>(
      x3h, x3l, w3h, w3l, stats, g2, b2, 1.f / 131072.f, part);
  reduce_k<<<(524288 + 255) / 256, 256, 0, stream>>>(part, h3, 524288, 4);
  hipMemsetAsync(stats, 0, 2 * 64 * sizeof(float), stream);
  bn_stats_nhwc_k<<<256, 256, 0, stream>>>(h3, stats, 63, 6, 32768);
  split_blocked_k<64><<<2048, 256, 0, stream>>>(h3, stats, g3, b3, 1.f / 32768.f, x4h, x4l, 32768);

  // ---- conv4 (MFMA, (ky x ch/2)-split x8) ----
  convs_mfma_k<64, 128, 32, 32, 2, 2, false><<<512, 256, 0, stream>>>(
      x4h, x4l, w4h, w4l, stats, g4, b4, 0.f, part);
  reduce_k<<<(262144 + 255) / 256, 256, 0, stream>>>(part, h4, 262144, 8);
  hipMemsetAsync(stats, 0, 2 * 128 * sizeof(float), stream);
  bn_stats_nhwc_k<<<128, 256, 0, stream>>>(h4, stats, 127, 7, 8192);
  split_blocked_k<128><<<512, 256, 0, stream>>>(h4, stats, g4, b4, 1.f / 8192.f, x5h, x5l, 8192);

  // ---- conv5 (MFMA, (ky x ch/2)-split x8) ----
  convs_mfma_k<128, 256, 16, 16, 1, 2, false><<<256, 256, 0, stream>>>(
      x5h, x5l, w5h, w5l, stats, g5, b5, 0.f, part);
  reduce_k<<<(131072 + 255) / 256, 256, 0, stream>>>(part, h5, 131072, 8);
  hipMemsetAsync(stats, 0, 2 * 256 * sizeof(float), stream);
  bn_stats_nhwc_k<<<64, 256, 0, stream>>>(h5, stats, 255, 8, 2048);

  // ---- capsules ----
  caps_k<<<2048, 256, 0, stream>>>(h5, stats, g5, b5, caps);
  priors_k<<<512, 256, 0, stream>>>(caps, rw, priors);

  // ---- routing: 3 iterations ----
  hipMemsetAsync(sbuf, 0, NB * KO * sizeof(float), stream);
  route_s_partial<<<NB * 8, 256, 0, stream>>>(priors, sbuf);
  squash_k<<<(NB * NCLS + 255) / 256, 256, 0, stream>>>(sbuf, souts);

  hipMemsetAsync(sbuf, 0, NB * KO * sizeof(float), stream);
  route_iter_k<<<NB * 8, 256, 0, stream>>>(priors, souts, logits, sbuf, 0, 1);
  squash_k<<<(NB * NCLS + 255) / 256, 256, 0, stream>>>(sbuf, souts);

  hipMemsetAsync(sbuf, 0, NB * KO * sizeof(float), stream);
  route_iter_k<<<NB * 8, 256, 0, stream>>>(priors, souts, logits, sbuf, 1, 0);
  squash_k<<<(NB * NCLS + 255) / 256, 256, 0, stream>>>(sbuf, souts);

  // ---- final scatter ----
  out_k<<<(8 * 16 * NCLS * NO + 255) / 256, 256, 0, stream>>>(souts, out);
}

// Round 6
// 749.217 us; speedup vs baseline: 3.6391x; 1.0130x over previous
//
#include <hip/hip_runtime.h>
#include <math.h>

typedef unsigned int   uint;
typedef unsigned short ushort;
using bf16x8 = __attribute__((ext_vector_type(8))) __bf16;
using f32x4  = __attribute__((ext_vector_type(4))) float;

constexpr int NB   = 128;
constexpr int NCAP = 512;
constexpr int NCLS = 43;
constexpr int NO   = 21;
constexpr int KO   = NCLS * NO; // 903

// ---- workspace layout (float offsets) ----
constexpr size_t F_X1H  = 0;          // conv1 out hi, blocked [16][131072][8] bf16
constexpr size_t F_X1L  = 8388608;
constexpr size_t F_PART = 0;          // conv3/4/5 K-split partials (x1 dead)
constexpr size_t F_STAT = 16777216;   // 1,024
constexpr size_t F_WPH  = 16778240;   // conv2 w (147,456)
constexpr size_t F_WPL  = 16925696;
constexpr size_t F_W3H  = 17073152;
constexpr size_t F_W3L  = 17204224;
constexpr size_t F_W4H  = 17335296;
constexpr size_t F_W4L  = 17400832;
constexpr size_t F_W5H  = 17466368;
constexpr size_t F_W5L  = 17728512;
constexpr size_t F_X3H  = 17990656;   // conv2 out hi, blocked [32][131072][8] bf16
constexpr size_t F_X3L  = 34767872;   // ends 51,545,088
constexpr size_t F_H3   = 51545088;   // h3 NHWC fp32 (2,097,152)
constexpr size_t F_X4H  = 53642240;
constexpr size_t F_X4L  = 54690816;
constexpr size_t F_H4   = 55739392;
constexpr size_t F_X5H  = 56787968;
constexpr size_t F_X5L  = 57312256;
constexpr size_t F_H5   = 57836544;   // (524,288)
// routing phase:
constexpr size_t F_PRI  = 0;          // bf16 priors: 59,179,008 ushorts (29.6M f32 slots)
constexpr size_t F_CAPS = 59179008;   // 524,288
constexpr size_t F_LOG  = 59703296;   // 2,818,048
constexpr size_t F_S    = 65339392;   // 115,584
constexpr size_t F_OUTS = 65454976;   // 115,584

__device__ inline ushort f2bf(float x) {
  uint u = __float_as_uint(x);
  uint r = (u + 0x7fffu + ((u >> 16) & 1u)) >> 16;  // RNE
  return (ushort)r;
}
__device__ inline float bf2f(ushort h) { return __uint_as_float(((uint)h) << 16); }

// ---------------- conv1: fp32 direct, writes blocked pre-BN bf16 hi/lo ----
__global__ __launch_bounds__(256) void conv1_k(
    const float* __restrict__ in, const float* __restrict__ w,
    ushort* __restrict__ oh, ushort* __restrict__ ol)
{
  constexpr int KS = 3, ICC = 3, IHT = 10, IWT = 18;
  const int ocb = blockIdx.z & 3;
  const int b   = blockIdx.z >> 2;
  const int tx0 = blockIdx.x * 16;
  const int ty0 = blockIdx.y * 8;
  const int oc0 = ocb * 32;

  __shared__ float lin[ICC][IHT][IWT];
  __shared__ float lw[ICC][KS * KS][32];

  const int t  = threadIdx.x;
  const int pq = t & 3;
  const int ty = (t >> 2) & 7;
  const int oq = t >> 5;

  float acc[4][4];
#pragma unroll
  for (int m = 0; m < 4; ++m)
#pragma unroll
    for (int j = 0; j < 4; ++j) acc[m][j] = 0.f;

  const int gx0 = tx0 - 1;
  const int gy0 = ty0 - 1;

  for (int e = t; e < ICC * IHT * IWT; e += 256) {
    int ic = e / (IHT * IWT);
    int rr = e % (IHT * IWT);
    int ey = rr / IWT, ex = rr % IWT;
    int gy = gy0 + ey, gx = gx0 + ex;
    float v = 0.f;
    if ((unsigned)gy < 128u && (unsigned)gx < 128u)
      v = in[((size_t)(b * 3 + ic) * 128 + gy) * 128 + gx];
    lin[ic][ey][ex] = v;
  }
  for (int e = t; e < ICC * 9 * 32; e += 256) {
    int ocl = e & 31;
    int rr  = e >> 5;
    int kk  = rr % 9;
    int ic  = rr / 9;
    lw[ic][kk][ocl] = w[((size_t)(oc0 + ocl) * 3 + ic) * 9 + kk];
  }
  __syncthreads();

  for (int ic = 0; ic < ICC; ++ic) {
#pragma unroll
    for (int ky = 0; ky < KS; ++ky) {
#pragma unroll
      for (int kx = 0; kx < KS; ++kx) {
        float xv[4];
#pragma unroll
        for (int j = 0; j < 4; ++j)
          xv[j] = lin[ic][ty + ky][pq * 4 + j + kx];
        const float4 w4 = *(const float4*)&lw[ic][ky * KS + kx][oq * 4];
#pragma unroll
        for (int j = 0; j < 4; ++j) {
          acc[0][j] = fmaf(w4.x, xv[j], acc[0][j]);
          acc[1][j] = fmaf(w4.y, xv[j], acc[1][j]);
          acc[2][j] = fmaf(w4.z, xv[j], acc[2][j]);
          acc[3][j] = fmaf(w4.w, xv[j], acc[3][j]);
        }
      }
    }
  }

  const int oy = ty0 + ty;
  const int oc0q = oc0 + oq * 4;
  const size_t icb = oc0q >> 3;
  const int off = oc0q & 7;
#pragma unroll
  for (int j = 0; j < 4; ++j) {
    int px = tx0 + pq * 4 + j;
    size_t pxg = ((size_t)b * 128 + oy) * 128 + px;
    size_t addr = (icb * 131072 + pxg) * 8 + off;
    ushort h0 = f2bf(acc[0][j]); ushort l0 = f2bf(acc[0][j] - bf2f(h0));
    ushort h1 = f2bf(acc[1][j]); ushort l1 = f2bf(acc[1][j] - bf2f(h1));
    ushort h2 = f2bf(acc[2][j]); ushort l2 = f2bf(acc[2][j] - bf2f(h2));
    ushort h3 = f2bf(acc[3][j]); ushort l3 = f2bf(acc[3][j] - bf2f(h3));
    uint2 uh; uh.x = (uint)h0 | ((uint)h1 << 16); uh.y = (uint)h2 | ((uint)h3 << 16);
    uint2 ul; ul.x = (uint)l0 | ((uint)l1 << 16); ul.y = (uint)l2 | ((uint)l3 << 16);
    *(uint2*)(oh + addr) = uh;
    *(uint2*)(ol + addr) = ul;
  }
}

// ---------------- BN stats: blocked bf16 hi/lo ----------------
__global__ __launch_bounds__(256) void bn_stats_blocked_k(
    const ushort* __restrict__ xh, const ushort* __restrict__ xl,
    float* __restrict__ stats, int nj, int totpx, int slices)
{
  const int j  = blockIdx.x % nj;
  const int sl = blockIdx.x / nj;
  float s[8] = {0,0,0,0,0,0,0,0}, q[8] = {0,0,0,0,0,0,0,0};
  const ushort* ph = xh + (size_t)j * totpx * 8;
  const ushort* pl = xl + (size_t)j * totpx * 8;
  for (int p = sl * 256 + threadIdx.x; p < totpx; p += slices * 256) {
    uint4 vh = *(const uint4*)(ph + (size_t)p * 8);
    uint4 vl = *(const uint4*)(pl + (size_t)p * 8);
    uint hw[4] = {vh.x, vh.y, vh.z, vh.w};
    uint lw[4] = {vl.x, vl.y, vl.z, vl.w};
#pragma unroll
    for (int m = 0; m < 4; ++m) {
      float v0 = __uint_as_float(hw[m] << 16) + __uint_as_float(lw[m] << 16);
      float v1 = __uint_as_float(hw[m] & 0xffff0000u) + __uint_as_float(lw[m] & 0xffff0000u);
      s[2*m] += v0; q[2*m] += v0 * v0;
      s[2*m+1] += v1; q[2*m+1] += v1 * v1;
    }
  }
#pragma unroll
  for (int off = 32; off > 0; off >>= 1)
#pragma unroll
    for (int k = 0; k < 8; ++k) {
      s[k] += __shfl_down(s[k], off);
      q[k] += __shfl_down(q[k], off);
    }
  __shared__ float red[4][16];
  int wid = threadIdx.x >> 6, lane = threadIdx.x & 63;
  if (lane == 0) {
#pragma unroll
    for (int k = 0; k < 8; ++k) { red[wid][k] = s[k]; red[wid][8 + k] = q[k]; }
  }
  __syncthreads();
  if (threadIdx.x < 16) {
    float a = red[0][threadIdx.x] + red[1][threadIdx.x] + red[2][threadIdx.x] + red[3][threadIdx.x];
    int C = nj * 8;
    int c = j * 8 + (threadIdx.x & 7);
    atomicAdd(&stats[(threadIdx.x >> 3) * C + c], a);
  }
}

__global__ __launch_bounds__(256) void bn_stats_nhwc_k(
    const float* __restrict__ x, float* __restrict__ stats,
    int cmask, int lg2c, int totpx)
{
  int g = blockIdx.x * 256 + threadIdx.x;
  int c = g & cmask;
  int p0 = g >> lg2c;
  int stride = (gridDim.x * 256) >> lg2c;
  float s = 0.f, q = 0.f;
  for (int p = p0; p < totpx; p += stride) {
    float v = x[((size_t)p << lg2c) | c];
    s += v; q += v * v;
  }
  atomicAdd(&stats[c], s);
  atomicAdd(&stats[cmask + 1 + c], q);
}

// ---- BN+LReLU+split fp32 NHWC -> blocked bf16 hi/lo (inline fin) ----
template<int C>
__global__ __launch_bounds__(256) void split_blocked_k(
    const float* __restrict__ h, const float* __restrict__ stats,
    const float* __restrict__ g, const float* __restrict__ bt, float inv_n,
    ushort* __restrict__ oh, ushort* __restrict__ ol, int totpx)
{
  __shared__ ushort lh[16][C + 8], ll[16][C + 8];
  __shared__ float scs[C], sfs[C];
  const int px0 = blockIdx.x * 16;
  const int t = threadIdx.x;
  if (t < C) {
    float m = stats[t] * inv_n;
    float v = stats[C + t] * inv_n - m * m;
    float rs = rsqrtf(v + 1e-5f);
    float sc = g[t] * rs;
    scs[t] = sc; sfs[t] = bt[t] - m * sc;
  }
  __syncthreads();
  for (int e = t; e < 16 * C / 4; e += 256) {
    int px = e / (C / 4);
    int c0 = (e % (C / 4)) * 4;
    float4 v  = *(const float4*)(h + (size_t)(px0 + px) * C + c0);
    float a0 = fmaf(v.x, scs[c0],   sfs[c0]);   a0 = fmaxf(a0, 0.1f * a0);
    float a1 = fmaf(v.y, scs[c0+1], sfs[c0+1]); a1 = fmaxf(a1, 0.1f * a1);
    float a2 = fmaf(v.z, scs[c0+2], sfs[c0+2]); a2 = fmaxf(a2, 0.1f * a2);
    float a3 = fmaf(v.w, scs[c0+3], sfs[c0+3]); a3 = fmaxf(a3, 0.1f * a3);
    ushort h0 = f2bf(a0), h1 = f2bf(a1), h2v = f2bf(a2), h3v = f2bf(a3);
    lh[px][c0]   = h0;  ll[px][c0]   = f2bf(a0 - bf2f(h0));
    lh[px][c0+1] = h1;  ll[px][c0+1] = f2bf(a1 - bf2f(h1));
    lh[px][c0+2] = h2v; ll[px][c0+2] = f2bf(a2 - bf2f(h2v));
    lh[px][c0+3] = h3v; ll[px][c0+3] = f2bf(a3 - bf2f(h3v));
  }
  __syncthreads();
  for (int e = t; e < 16 * (C / 8); e += 256) {
    int j = e >> 4, px = e & 15;
    *(uint4*)(oh + ((size_t)j * totpx + px0 + px) * 8) = *(const uint4*)&lh[px][j * 8];
    *(uint4*)(ol + ((size_t)j * totpx + px0 + px) * 8) = *(const uint4*)&ll[px][j * 8];
  }
}

// ------- all weight splits merged -------
__global__ void wsplit_all_k(
    const float* __restrict__ c2w, const float* __restrict__ c3w,
    const float* __restrict__ c4w, const float* __restrict__ c5w,
    ushort* __restrict__ wph, ushort* __restrict__ wpl,
    ushort* __restrict__ w3h, ushort* __restrict__ w3l,
    ushort* __restrict__ w4h, ushort* __restrict__ w4l,
    ushort* __restrict__ w5h, ushort* __restrict__ w5l)
{
  int i = blockIdx.x * 256 + threadIdx.x;
  if (i < 294912) {
    int k = i % 9; int r = i / 9; int ic = r & 127; int oc = r >> 7;
    float v = c2w[i];
    ushort hi = f2bf(v), lo = f2bf(v - bf2f(hi));
    size_t d = ((size_t)k * 256 + oc) * 128 + ic;
    wph[d] = hi; wpl[d] = lo;
    return;
  }
  i -= 294912;
  const float* w; ushort *wh, *wl; int OC, IC, n;
  if (i < 262144)      { w = c3w; wh = w3h; wl = w3l; OC = 64;  IC = 256; n = i; }
  else if (i < 393216) { w = c4w; wh = w4h; wl = w4l; OC = 128; IC = 64;  n = i - 262144; }
  else if (i < 917504) { w = c5w; wh = w5h; wl = w5l; OC = 256; IC = 128; n = i - 393216; }
  else return;
  int kx = n & 3, ky = (n >> 2) & 3;
  int ic = (n >> 4) % IC, oc = (n >> 4) / IC;
  float v = w[n];
  ushort hi = f2bf(v), lo = f2bf(v - bf2f(hi));
  size_t d = (((size_t)ky * (IC >> 3) + (ic >> 3)) * OC + oc) * 32 + kx * 8 + (ic & 7);
  wh[d] = hi; wl[d] = lo;
}

// ------- conv2 via MFMA (bf16x3), 1 row x 128 px x 256 oc per block -------
// BN of x1 fused in staging; XCD swizzle; bank-conflict-free LDS layouts.
__global__ __launch_bounds__(256, 2) void conv2_mfma_k(
    const ushort* __restrict__ x1h, const ushort* __restrict__ x1l,
    const ushort* __restrict__ wph, const ushort* __restrict__ wpl,
    const float* __restrict__ stats, const float* __restrict__ g1,
    const float* __restrict__ b1,
    ushort* __restrict__ x3h, ushort* __restrict__ x3l)
{
  const int bid = blockIdx.x;                 // 1024 blocks
  const int wid = (bid & 7) * 128 + (bid >> 3);
  const int y0  = wid & 127;
  const int b   = wid >> 7;

  __shared__ ushort xs[2][4][132][8];   // [hl][icg][xi][ic8] : 16,896 B
  __shared__ ushort wsm[2][4][256][8];  // [hl][icg][oc][ic8] : 32,768 B
  __shared__ float scs[128], sfs[128];

  const int t = threadIdx.x;
  if (t < 128) {
    float m = stats[t] * (1.f / 131072.f);
    float v = stats[128 + t] * (1.f / 131072.f) - m * m;
    float rs = rsqrtf(v + 1e-5f);
    float sc = g1[t] * rs;
    scs[t] = sc; sfs[t] = b1[t] - m * sc;
  }

  const int w  = t >> 6;
  const int l  = t & 63;
  const int xhf = w & 1;        // x half (64 px)
  const int ohf = w >> 1;       // oc half (128 oc)
  const int lr = l & 15;
  const int kg = l >> 4;

  f32x4 acc[8][4];
#pragma unroll
  for (int i = 0; i < 8; ++i)
#pragma unroll
    for (int j = 0; j < 4; ++j) acc[i][j] = (f32x4){0.f, 0.f, 0.f, 0.f};

  for (int ky = 0; ky < 3; ++ky) {
    const int gy = y0 + ky - 1;
    const bool rowok = (unsigned)gy < 128u;
    for (int ic32 = 0; ic32 < 4; ++ic32) {
      __syncthreads();
      // stage X: 130 xi x 4 icg, BN+LReLU fused
      for (int e = t; e < 520; e += 256) {
        int icg = e / 130;
        int xi  = e - icg * 130;
        int gx = xi - 1;
        uint4 rh = {0, 0, 0, 0}, rl = {0, 0, 0, 0};
        if (rowok && (unsigned)gx < 128u) {
          int jb = ic32 * 4 + icg;
          size_t gi = ((size_t)jb * 131072 + ((size_t)b * 128 + gy) * 128 + gx) * 8;
          uint4 vh = *(const uint4*)(x1h + gi);
          uint4 vl = *(const uint4*)(x1l + gi);
          int c0 = jb * 8;
          uint hw[4] = {vh.x, vh.y, vh.z, vh.w};
          uint lw[4] = {vl.x, vl.y, vl.z, vl.w};
          uint ohv[4], olv[4];
#pragma unroll
          for (int m = 0; m < 4; ++m) {
            float f0 = __uint_as_float(hw[m] << 16) + __uint_as_float(lw[m] << 16);
            float f1 = __uint_as_float(hw[m] & 0xffff0000u) + __uint_as_float(lw[m] & 0xffff0000u);
            float a0 = fmaf(f0, scs[c0 + 2*m],   sfs[c0 + 2*m]);   a0 = fmaxf(a0, 0.1f * a0);
            float a1 = fmaf(f1, scs[c0 + 2*m+1], sfs[c0 + 2*m+1]); a1 = fmaxf(a1, 0.1f * a1);
            ushort h0 = f2bf(a0), l0 = f2bf(a0 - bf2f(h0));
            ushort h1 = f2bf(a1), l1 = f2bf(a1 - bf2f(h1));
            ohv[m] = (uint)h0 | ((uint)h1 << 16);
            olv[m] = (uint)l0 | ((uint)l1 << 16);
          }
          rh.x = ohv[0]; rh.y = ohv[1]; rh.z = ohv[2]; rh.w = ohv[3];
          rl.x = olv[0]; rl.y = olv[1]; rl.z = olv[2]; rl.w = olv[3];
        }
        *(uint4*)&xs[0][icg][xi][0] = rh;
        *(uint4*)&xs[1][icg][xi][0] = rl;
      }

      for (int kx = 0; kx < 3; ++kx) {
        __syncthreads();   // prev MFMA reads done (and X staged, first iter)
        {
          const int kk = ky * 3 + kx;
          for (int e = t; e < 1024; e += 256) {
            int oc = e >> 2, icg = e & 3;
            size_t gi = (((size_t)kk * 256 + oc) * 128) + ic32 * 32 + icg * 8;
            *(uint4*)&wsm[0][icg][oc][0] = *(const uint4*)(wph + gi);
            *(uint4*)&wsm[1][icg][oc][0] = *(const uint4*)(wpl + gi);
          }
        }
        __syncthreads();

        bf16x8 awh[8], awl[8], xbh[4], xbl[4];
#pragma unroll
        for (int of = 0; of < 8; ++of) {
          awh[of] = *(const bf16x8*)&wsm[0][kg][ohf * 128 + of * 16 + lr][0];
          awl[of] = *(const bf16x8*)&wsm[1][kg][ohf * 128 + of * 16 + lr][0];
        }
#pragma unroll
        for (int pf = 0; pf < 4; ++pf) {
          int xi = xhf * 64 + pf * 16 + lr + kx;
          xbh[pf] = *(const bf16x8*)&xs[0][kg][xi][0];
          xbl[pf] = *(const bf16x8*)&xs[1][kg][xi][0];
        }
#pragma unroll
        for (int of = 0; of < 8; ++of) {
#pragma unroll
          for (int pf = 0; pf < 4; ++pf) {
            acc[of][pf] = __builtin_amdgcn_mfma_f32_16x16x32_bf16(awh[of], xbh[pf], acc[of][pf], 0, 0, 0);
            acc[of][pf] = __builtin_amdgcn_mfma_f32_16x16x32_bf16(awh[of], xbl[pf], acc[of][pf], 0, 0, 0);
            acc[of][pf] = __builtin_amdgcn_mfma_f32_16x16x32_bf16(awl[of], xbh[pf], acc[of][pf], 0, 0, 0);
          }
        }
      }
    }
  }

  // epilogue: blocked bf16 hi/lo [oc/8][(b*128+y)*128+x][8]
#pragma unroll
  for (int of = 0; of < 8; ++of) {
#pragma unroll
    for (int pf = 0; pf < 4; ++pf) {
      int oc = ohf * 128 + of * 16 + kg * 4;
      int x  = xhf * 64 + pf * 16 + lr;
      size_t pxg = ((size_t)b * 128 + y0) * 128 + x;
      size_t base = ((size_t)(oc >> 3) * 131072 + pxg) * 8 + (oc & 7);
      f32x4 a = acc[of][pf];
      ushort h0 = f2bf(a[0]); ushort l0 = f2bf(a[0] - bf2f(h0));
      ushort h1 = f2bf(a[1]); ushort l1 = f2bf(a[1] - bf2f(h1));
      ushort h2 = f2bf(a[2]); ushort l2 = f2bf(a[2] - bf2f(h2));
      ushort h3 = f2bf(a[3]); ushort l3 = f2bf(a[3] - bf2f(h3));
      uint2 uh; uh.x = (uint)h0 | ((uint)h1 << 16); uh.y = (uint)h2 | ((uint)h3 << 16);
      uint2 ul; ul.x = (uint)l0 | ((uint)l1 << 16); ul.y = (uint)l2 | ((uint)l3 << 16);
      *(uint2*)(x3h + base) = uh;
      *(uint2*)(x3l + base) = ul;
    }
  }
}

// ------- conv3/4/5 via MFMA, K-split, optional BN fusion, XCD swizzle -------
template<int IC, int OC, int OH, int OW, int WPX, int CS, bool FBN>
__global__ __launch_bounds__(256, 2) void convs_mfma_k(
    const ushort* __restrict__ xh, const ushort* __restrict__ xl,
    const ushort* __restrict__ wh, const ushort* __restrict__ wl,
    const float* __restrict__ stats, const float* __restrict__ gg,
    const float* __restrict__ bb, float inv_n,
    float* __restrict__ part)
{
  constexpr int IH  = 2 * OH, IW = 2 * OW;
  constexpr int NCH = IC / 8;
  constexpr int NCHB = NCH / CS;
  constexpr int PFX = OW / 16;
  constexpr int RW  = 4 / WPX;
  constexpr int NZ = 4 * CS;
  constexpr int NX = OH / 4;
  constexpr int SBN = FBN ? IC : 1;

  const int bid = blockIdx.x;
  const int wid = (bid & 7) * (NZ * NX) + (bid >> 3);
  const int zi = wid % NZ;
  const int y0 = ((wid / NZ) % NX) * 4;
  const int b  = wid / (NZ * NX);
  const int ky = zi & 3;
  const int cs = zi >> 2;

  __shared__ ushort xs[2][4][2][OW + 2][8];
  __shared__ ushort wsm[2][4][OC][8];   // [hl][kxg][oc][ic8] — conflict-free reads
  __shared__ float scs[SBN], sfs[SBN];

  const int t = threadIdx.x;
  if (FBN) {
    for (int c = t; c < IC; c += 256) {
      float m = stats[c] * inv_n;
      float v = stats[IC + c] * inv_n - m * m;
      float rs = rsqrtf(v + 1e-5f);
      float sc = gg[c] * rs;
      scs[c] = sc; sfs[c] = bb[c] - m * sc;
    }
  }

  const int w = t >> 6, l = t & 63;
  const int wo = w / WPX, wp = w % WPX;
  const int lr = l & 15, kg = l >> 4;
  const int oc0w = wo * 64;
  const int rb = wp * RW;

  f32x4 acc[4][4];
#pragma unroll
  for (int i = 0; i < 4; ++i)
#pragma unroll
    for (int j = 0; j < 4; ++j) acc[i][j] = (f32x4){0.f, 0.f, 0.f, 0.f};

  for (int cc = 0; cc < NCHB; ++cc) {
    const int ch = cs * NCHB + cc;
    __syncthreads();
    for (int e = t; e < 4 * (IW + 2); e += 256) {
      int r  = e / (IW + 2);
      int xi = e % (IW + 2);
      int xp = xi - 1;
      int iy = 2 * (y0 + r) + ky - 1;
      uint4 rh = {0, 0, 0, 0}, rl = {0, 0, 0, 0};
      if ((unsigned)iy < (unsigned)IH && (unsigned)xp < (unsigned)IW) {
        size_t gi = ((((size_t)ch * 8 + b) * IH + iy) * IW + xp) * 8;
        uint4 vh = *(const uint4*)(xh + gi);
        uint4 vl = *(const uint4*)(xl + gi);
        if (FBN) {
          int c0 = ch * 8;
          uint hw[4] = {vh.x, vh.y, vh.z, vh.w};
          uint lw[4] = {vl.x, vl.y, vl.z, vl.w};
          uint ohv[4], olv[4];
#pragma unroll
          for (int m = 0; m < 4; ++m) {
            float f0 = __uint_as_float(hw[m] << 16) + __uint_as_float(lw[m] << 16);
            float f1 = __uint_as_float(hw[m] & 0xffff0000u) + __uint_as_float(lw[m] & 0xffff0000u);
            float a0 = fmaf(f0, scs[c0 + 2*m],   sfs[c0 + 2*m]);   a0 = fmaxf(a0, 0.1f * a0);
            float a1 = fmaf(f1, scs[c0 + 2*m+1], sfs[c0 + 2*m+1]); a1 = fmaxf(a1, 0.1f * a1);
            ushort h0 = f2bf(a0), l0 = f2bf(a0 - bf2f(h0));
            ushort h1 = f2bf(a1), l1 = f2bf(a1 - bf2f(h1));
            ohv[m] = (uint)h0 | ((uint)h1 << 16);
            olv[m] = (uint)l0 | ((uint)l1 << 16);
          }
          rh.x = ohv[0]; rh.y = ohv[1]; rh.z = ohv[2]; rh.w = ohv[3];
          rl.x = olv[0]; rl.y = olv[1]; rl.z = olv[2]; rl.w = olv[3];
        } else {
          rh = vh; rl = vl;
        }
      }
      int par = xp & 1;
      int idx = (xp + 1) >> 1;
      *(uint4*)&xs[0][r][par][idx][0] = rh;
      *(uint4*)&xs[1][r][par][idx][0] = rl;
    }
    for (int e = t; e < OC * 4; e += 256) {
      int oc = e >> 2, kxg = e & 3;
      size_t gi = (((size_t)ky * NCH + ch) * OC + oc) * 32 + kxg * 8;
      *(uint4*)&wsm[0][kxg][oc][0] = *(const uint4*)(wh + gi);
      *(uint4*)&wsm[1][kxg][oc][0] = *(const uint4*)(wl + gi);
    }
    __syncthreads();

    bf16x8 ah[4], al[4], bh[4], bl[4];
#pragma unroll
    for (int of = 0; of < 4; ++of) {
      ah[of] = *(const bf16x8*)&wsm[0][kg][oc0w + of * 16 + lr][0];
      al[of] = *(const bf16x8*)&wsm[1][kg][oc0w + of * 16 + lr][0];
    }
    const int par = 1 - (kg & 1);
    const int xoff = kg >> 1;
#pragma unroll
    for (int pf = 0; pf < 4; ++pf) {
      int row = rb + pf / PFX;
      int x   = (pf % PFX) * 16 + lr;
      bh[pf] = *(const bf16x8*)&xs[0][row][par][x + xoff][0];
      bl[pf] = *(const bf16x8*)&xs[1][row][par][x + xoff][0];
    }
#pragma unroll
    for (int of = 0; of < 4; ++of) {
#pragma unroll
      for (int pf = 0; pf < 4; ++pf) {
        acc[of][pf] = __builtin_amdgcn_mfma_f32_16x16x32_bf16(ah[of], bh[pf], acc[of][pf], 0, 0, 0);
        acc[of][pf] = __builtin_amdgcn_mfma_f32_16x16x32_bf16(ah[of], bl[pf], acc[of][pf], 0, 0, 0);
        acc[of][pf] = __builtin_amdgcn_mfma_f32_16x16x32_bf16(al[of], bh[pf], acc[of][pf], 0, 0, 0);
      }
    }
  }

  float* yp = part + (size_t)zi * (8 * OH * OW * OC);
#pragma unroll
  for (int of = 0; of < 4; ++of) {
#pragma unroll
    for (int pf = 0; pf < 4; ++pf) {
      int row = rb + pf / PFX;
      int x   = (pf % PFX) * 16 + lr;
      int oc  = oc0w + of * 16 + kg * 4;
      float* p = yp + (((size_t)b * OH + y0 + row) * OW + x) * OC + oc;
      f32x4 a = acc[of][pf];
      float4 v = {a[0], a[1], a[2], a[3]};
      *(float4*)p = v;
    }
  }
}

// ------- reduce partials -> h (float4) -------
__global__ __launch_bounds__(256) void reduce_k(
    const float* __restrict__ part, float* __restrict__ h,
    int n4, int nparts)
{
  int i = blockIdx.x * 256 + threadIdx.x;
  if (i >= n4) return;
  float4 a = ((const float4*)part)[i];
  for (int z = 1; z < nparts; ++z) {
    float4 b = ((const float4*)part)[(size_t)z * n4 + i];
    a.x += b.x; a.y += b.y; a.z += b.z; a.w += b.w;
  }
  ((float4*)h)[i] = a;
}

// ---------------- capsule rearrange (h5 NHWC, BN inline) ----------------
__global__ void caps_k(const float* __restrict__ h5, const float* __restrict__ stats,
                       const float* __restrict__ g5, const float* __restrict__ b5,
                       float* __restrict__ caps)
{
  int e = blockIdx.x * 256 + threadIdx.x;
  if (e >= NB * NCAP * 8) return;
  int ii = e & 7;
  int n  = (e >> 3) & 511;
  int jb = e >> 12;
  int j = jb >> 3, b = jb & 7;
  int i = n >> 7, k = (n >> 5) & 3, ch = ((n & 31) << 3) | ii;
  int hh = (i << 2) | (j >> 2);
  int ww = ((j & 3) << 2) | k;
  float m  = stats[ch] * (1.f / 2048.f);
  float vv = stats[256 + ch] * (1.f / 2048.f) - m * m;
  float rs = rsqrtf(vv + 1e-5f);
  float sc = g5[ch] * rs;
  float sf = b5[ch] - m * sc;
  float v = h5[(((size_t)b * 16 + hh) * 16 + ww) * 256 + ch];
  float a = fmaf(v, sc, sf);
  a = fmaxf(a, 0.1f * a);
  caps[e] = a;
}

// ---------------- priors (bf16 output) ----------------
__global__ __launch_bounds__(256) void priors_k(
    const float* __restrict__ caps, const float* __restrict__ rw,
    ushort* __restrict__ priors)
{
  const int n = blockIdx.x;
  __shared__ float lrw[NCLS * 8 * NO];
  __shared__ float lc[NB * 8];
  const int t = threadIdx.x;
  for (int e = t; e < NCLS * 8 * NO; e += 256)
    lrw[e] = rw[(size_t)n * NCLS * 8 * NO + e];
  for (int e = t; e < NB * 8; e += 256) {
    int b = e >> 3, ii = e & 7;
    lc[e] = caps[((size_t)b * NCAP + n) * 8 + ii];
  }
  __syncthreads();

  int p[4], kk[4], oo[4];
#pragma unroll
  for (int q = 0; q < 4; ++q) {
    p[q]  = t + q * 256;
    kk[q] = (p[q] < KO) ? p[q] / NO : 0;
    oo[q] = (p[q] < KO) ? p[q] % NO : 0;
  }
  for (int b = 0; b < NB; ++b) {
    const float* cb = &lc[b * 8];
    float c0 = cb[0], c1 = cb[1], c2 = cb[2], c3 = cb[3];
    float c4 = cb[4], c5 = cb[5], c6 = cb[6], c7 = cb[7];
    ushort* pout = priors + ((size_t)b * NCAP + n) * KO;
#pragma unroll
    for (int q = 0; q < 4; ++q) {
      if (p[q] < KO) {
        const float* wv = &lrw[kk[q] * (8 * NO) + oo[q]];
        float a = c0 * wv[0];
        a = fmaf(c1, wv[21],  a);
        a = fmaf(c2, wv[42],  a);
        a = fmaf(c3, wv[63],  a);
        a = fmaf(c4, wv[84],  a);
        a = fmaf(c5, wv[105], a);
        a = fmaf(c6, wv[126], a);
        a = fmaf(c7, wv[147], a);
        pout[p[q]] = f2bf(a);
      }
    }
  }
}

// ---------------- routing ----------------
__global__ __launch_bounds__(256) void route_s_partial(
    const ushort* __restrict__ priors, float* __restrict__ s)
{
  const int b  = blockIdx.x >> 3;
  const int ns = blockIdx.x & 7;
  const int t  = threadIdx.x;
  const int p0 = t, p1 = t + 256, p2 = t + 512, p3 = t + 768;
  float a0 = 0.f, a1 = 0.f, a2 = 0.f, a3 = 0.f;
  const ushort* pb = priors + ((size_t)b * NCAP + ns * 64) * KO;
#pragma unroll 2
  for (int n = 0; n < 64; ++n) {
    const ushort* pn = pb + (size_t)n * KO;
    a0 += bf2f(pn[p0]); a1 += bf2f(pn[p1]); a2 += bf2f(pn[p2]);
    if (p3 < KO) a3 += bf2f(pn[p3]);
  }
  const float sc = 1.f / 43.f;
  atomicAdd(&s[b * KO + p0], a0 * sc);
  atomicAdd(&s[b * KO + p1], a1 * sc);
  atomicAdd(&s[b * KO + p2], a2 * sc);
  if (p3 < KO) atomicAdd(&s[b * KO + p3], a3 * sc);
}

// fused logits+softmax+s, wave-parallel over n
__global__ __launch_bounds__(256) void route_iter_k(
    const ushort* __restrict__ priors, const float* __restrict__ souts,
    float* __restrict__ logits, float* __restrict__ s,
    int readPrev, int writeL)
{
  const int b  = blockIdx.x >> 3;
  const int ns = blockIdx.x & 7;
  const int t  = threadIdx.x;
  const int w  = t >> 6;
  const int lane = t & 63;

  __shared__ float so_l[KO];
  __shared__ float sacc[4][KO];
  __shared__ float prow[4][KO];
  __shared__ float pk[4][NCLS];

  for (int e = t; e < KO; e += 256) so_l[e] = souts[b * KO + e];
  for (int e = lane; e < KO; e += 64) sacc[w][e] = 0.f;

  int kq[15];
#pragma unroll
  for (int q = 0; q < 15; ++q) {
    int e = lane + q * 64;
    kq[q] = (e < KO) ? e / NO : 0;
  }
  __syncthreads();

  for (int nn = 0; nn < 16; ++nn) {
    const int n = ns * 64 + w * 16 + nn;
    const ushort* pr = priors + ((size_t)(b * NCAP + n)) * KO;
    float v[15];
#pragma unroll
    for (int q = 0; q < 15; ++q) {
      int e = lane + q * 64;
      if (e < KO) { v[q] = bf2f(pr[e]); prow[w][e] = v[q]; }
      else v[q] = 0.f;
    }
    __syncthreads();

    float L = -1e30f;
    if (lane < NCLS) {
      float d = 0.f;
      const float* pp = &prow[w][lane * NO];
      const float* ss = &so_l[lane * NO];
#pragma unroll
      for (int o = 0; o < NO; ++o) d = fmaf(pp[o], ss[o], d);
      size_t lidx = ((size_t)(b * NCAP + n)) * NCLS + lane;
      L = (readPrev ? logits[lidx] : 0.f) + d;
      if (writeL) logits[lidx] = L;
    }
    float m = L;
#pragma unroll
    for (int off = 32; off > 0; off >>= 1) m = fmaxf(m, __shfl_xor(m, off));
    float ex = (lane < NCLS) ? __expf(L - m) : 0.f;
    float sm = ex;
#pragma unroll
    for (int off = 32; off > 0; off >>= 1) sm += __shfl_xor(sm, off);
    if (lane < NCLS) pk[w][lane] = ex / sm;
    __syncthreads();

#pragma unroll
    for (int q = 0; q < 15; ++q) {
      int e = lane + q * 64;
      if (e < KO) sacc[w][e] += pk[w][kq[q]] * v[q];
    }
  }
  __syncthreads();
  for (int e = t; e < KO; e += 256)
    atomicAdd(&s[b * KO + e], sacc[0][e] + sacc[1][e] + sacc[2][e] + sacc[3][e]);
}

__global__ void squash_k(const float* __restrict__ s, float* __restrict__ souts)
{
  int i = blockIdx.x * 256 + threadIdx.x;
  if (i >= NB * NCLS) return;
  int b = i / NCLS, k = i % NCLS;
  const float* sv = s + b * KO + k * NO;
  float sn = 0.f;
#pragma unroll
  for (int o = 0; o < NO; ++o) sn += sv[o] * sv[o];
  float f = sqrtf(sn) / (1.f + sn);
  float* ov = souts + b * KO + k * NO;
#pragma unroll
  for (int o = 0; o < NO; ++o) ov[o] = sv[o] * f;
}

__global__ void out_k(const float* __restrict__ souts, float* __restrict__ out)
{
  int i = blockIdx.x * 256 + threadIdx.x;
  if (i >= 8 * 16 * NCLS * NO) return;
  int o = i % NO;
  int r = i / NO;
  int k = r % NCLS; r /= NCLS;
  int g1 = r & 3; r >>= 2;
  int g0 = r & 3;
  int b  = r >> 2;
  int j  = g0 * 4 + g1;
  int jb = j * 8 + b;
  out[i] = souts[jb * KO + k * NO + o];
}

// ---------------- launcher ----------------
extern "C" void kernel_launch(void* const* d_in, const int* in_sizes, int n_in,
                              void* d_out, int out_size, void* d_ws, size_t ws_size,
                              hipStream_t stream)
{
  const float* x   = (const float*)d_in[0];
  const float* c1w = (const float*)d_in[1];
  const float* g1  = (const float*)d_in[3];  const float* b1  = (const float*)d_in[4];
  const float* c2w = (const float*)d_in[5];
  const float* g2  = (const float*)d_in[7];  const float* b2  = (const float*)d_in[8];
  const float* c3w = (const float*)d_in[9];
  const float* g3  = (const float*)d_in[11]; const float* b3  = (const float*)d_in[12];
  const float* c4w = (const float*)d_in[13];
  const float* g4  = (const float*)d_in[15]; const float* b4  = (const float*)d_in[16];
  const float* c5w = (const float*)d_in[17];
  const float* g5  = (const float*)d_in[19]; const float* b5  = (const float*)d_in[20];
  const float* rw  = (const float*)d_in[21];

  float* ws  = (float*)d_ws;
  float* out = (float*)d_out;

  ushort* x1h = (ushort*)(ws + F_X1H);
  ushort* x1l = (ushort*)(ws + F_X1L);
  ushort* wph = (ushort*)(ws + F_WPH);
  ushort* wpl = (ushort*)(ws + F_WPL);
  ushort* w3h = (ushort*)(ws + F_W3H);
  ushort* w3l = (ushort*)(ws + F_W3L);
  ushort* w4h = (ushort*)(ws + F_W4H);
  ushort* w4l = (ushort*)(ws + F_W4L);
  ushort* w5h = (ushort*)(ws + F_W5H);
  ushort* w5l = (ushort*)(ws + F_W5L);
  ushort* x3h = (ushort*)(ws + F_X3H);
  ushort* x3l = (ushort*)(ws + F_X3L);
  ushort* x4h = (ushort*)(ws + F_X4H);
  ushort* x4l = (ushort*)(ws + F_X4L);
  ushort* x5h = (ushort*)(ws + F_X5H);
  ushort* x5l = (ushort*)(ws + F_X5L);
  float* part   = ws + F_PART;
  float* h3     = ws + F_H3;
  float* h4     = ws + F_H4;
  float* h5     = ws + F_H5;
  float* caps   = ws + F_CAPS;
  ushort* priors = (ushort*)(ws + F_PRI);
  float* logits = ws + F_LOG;
  float* sbuf   = ws + F_S;
  float* souts  = ws + F_OUTS;
  float* stats  = ws + F_STAT;

  // ---- weight preps (merged) ----
  wsplit_all_k<<<(1212416 + 255) / 256, 256, 0, stream>>>(
      c2w, c3w, c4w, c5w, wph, wpl, w3h, w3l, w4h, w4l, w5h, w5l);

  // ---- conv1 -> blocked pre-BN bf16 hi/lo; stats ----
  conv1_k<<<dim3(8, 16, 32), 256, 0, stream>>>(x, c1w, x1h, x1l);
  hipMemsetAsync(stats, 0, 2 * 128 * sizeof(float), stream);
  bn_stats_blocked_k<<<16 * 16, 256, 0, stream>>>(x1h, x1l, stats, 16, 131072, 16);

  // ---- conv2 (MFMA, BN fused, 256 oc/block, XCD swizzle) -> pre-BN; stats ----
  conv2_mfma_k<<<1024, 256, 0, stream>>>(x1h, x1l, wph, wpl, stats, g1, b1, x3h, x3l);
  hipMemsetAsync(stats, 0, 2 * 256 * sizeof(float), stream);
  bn_stats_blocked_k<<<32 * 8, 256, 0, stream>>>(x3h, x3l, stats, 32, 131072, 8);

  // ---- conv3 (MFMA, ky-split x4, BN of x3 fused) ----
  convs_mfma_k<256, 64, 64, 64, 4, 1, true><<<512, 256, 0, stream>>>(
      x3h, x3l, w3h, w3l, stats, g2, b2, 1.f / 131072.f, part);
  reduce_k<<<(524288 + 255) / 256, 256, 0, stream>>>(part, h3, 524288, 4);
  hipMemsetAsync(stats, 0, 2 * 64 * sizeof(float), stream);
  bn_stats_nhwc_k<<<256, 256, 0, stream>>>(h3, stats, 63, 6, 32768);
  split_blocked_k<64><<<2048, 256, 0, stream>>>(h3, stats, g3, b3, 1.f / 32768.f, x4h, x4l, 32768);

  // ---- conv4 (MFMA, (ky x ch/2)-split x8) ----
  convs_mfma_k<64, 128, 32, 32, 2, 2, false><<<512, 256, 0, stream>>>(
      x4h, x4l, w4h, w4l, stats, g4, b4, 0.f, part);
  reduce_k<<<(262144 + 255) / 256, 256, 0, stream>>>(part, h4, 262144, 8);
  hipMemsetAsync(stats, 0, 2 * 128 * sizeof(float), stream);
  bn_stats_nhwc_k<<<128, 256, 0, stream>>>(h4, stats, 127, 7, 8192);
  split_blocked_k<128><<<512, 256, 0, stream>>>(h4, stats, g4, b4, 1.f / 8192.f, x5h, x5l, 8192);

  // ---- conv5 (MFMA, (ky x ch/2)-split x8) ----
  convs_mfma_k<128, 256, 16, 16, 1, 2, false><<<256, 256, 0, stream>>>(
      x5h, x5l, w5h, w5l, stats, g5, b5, 0.f, part);
  reduce_k<<<(131072 + 255) / 256, 256, 0, stream>>>(part, h5, 131072, 8);
  hipMemsetAsync(stats, 0, 2 * 256 * sizeof(float), stream);
  bn_stats_nhwc_k<<<64, 256, 0, stream>>>(h5, stats, 255, 8, 2048);

  // ---- capsules ----
  caps_k<<<2048, 256, 0, stream>>>(h5, stats, g5, b5, caps);
  priors_k<<<512, 256, 0, stream>>>(caps, rw, priors);

  // ---- routing: 3 iterations ----
  hipMemsetAsync(sbuf, 0, NB * KO * sizeof(float), stream);
  route_s_partial<<<NB * 8, 256, 0, stream>>>(priors, sbuf);
  squash_k<<<(NB * NCLS + 255) / 256, 256, 0, stream>>>(sbuf, souts);

  hipMemsetAsync(sbuf, 0, NB * KO * sizeof(float), stream);
  route_iter_k<<<NB * 8, 256, 0, stream>>>(priors, souts, logits, sbuf, 0, 1);
  squash_k<<<(NB * NCLS + 255) / 256, 256, 0, stream>>>(sbuf, souts);

  hipMemsetAsync(sbuf, 0, NB * KO * sizeof(float), stream);
  route_iter_k<<<NB * 8, 256, 0, stream>>>(priors, souts, logits, sbuf, 1, 0);
  squash_k<<<(NB * NCLS + 255) / 256, 256, 0, stream>>>(sbuf, souts);

  // ---- final scatter ----
  out_k<<<(8 * 16 * NCLS * NO + 255) / 256, 256, 0, stream>>>(souts, out);
}